// Round 7
// baseline (561.025 us; speedup 1.0000x reference)
//
#include <hip/hip_runtime.h>
#include <math.h>

#define N_NODES 20000
#define N_EDGES 160000
#define DIM_IN  128
#define HIDDEN  96
#define NH      6
#define HD      576      // NH*HIDDEN
#define LDROW   704      // bf16 row stride: Q(576)|S(96)|pad(32) = 11 lines
#define KVF8LD  1152     // fp8 row stride BYTES: K(576)|V(576) = 9 lines
#define NALL    1824     // concat QKVS weight cols
#define NGRAPH  512
#define NCLS    128
#define CHUNK   32       // edges per softmax chunk
#define SLD     104      // bf16 LDS stage row stride (ushorts)
#define BSTR    112      // fp8 LDS stage row stride (bytes, mult of 16)

typedef unsigned short ushort_t;
typedef unsigned char uchar_t;
typedef __attribute__((ext_vector_type(8))) short bf16x8;
typedef __attribute__((ext_vector_type(4))) float f32x4;
typedef __attribute__((ext_vector_type(2))) float f32x2;

static __device__ __forceinline__ ushort_t f2bf(float f) {
    unsigned int u = __float_as_uint(f);
    return (ushort_t)((u + 0x7fffu + ((u >> 16) & 1u)) >> 16);  // RNE
}
static __device__ __forceinline__ float bfs(ushort_t u) { return __uint_as_float((unsigned int)u << 16); }
static __device__ __forceinline__ float bflo(unsigned int u) { return __uint_as_float(u << 16); }
static __device__ __forceinline__ float bfhi(unsigned int u) { return __uint_as_float(u & 0xffff0000u); }

// ---------------------------------------------------------------------------
// Fused prep: x->bf16 cast | edge degree histogram | graph boundaries.
// ---------------------------------------------------------------------------
#define PREP_CVT_BLOCKS 10000   // 20000*128/256
#define PREP_DEG_BLOCKS 625     // 160000/256
#define PREP_GB_BLOCKS  3       // ceil((NGRAPH+1)/256)
__global__ void k_prep(const float* __restrict__ x, ushort_t* __restrict__ xb,
                       const int* __restrict__ edst, int* __restrict__ deg,
                       const int* __restrict__ batch, int* __restrict__ gbound)
{
    int b = blockIdx.x;
    if (b < PREP_CVT_BLOCKS) {
        int i = b * 256 + threadIdx.x;
        if (i < N_NODES * DIM_IN) xb[i] = f2bf(x[i]);
    } else if (b < PREP_CVT_BLOCKS + PREP_DEG_BLOCKS) {
        int e = (b - PREP_CVT_BLOCKS) * 256 + threadIdx.x;
        if (e < N_EDGES) atomicAdd(&deg[edst[e]], 1);
    } else {
        int g = (b - PREP_CVT_BLOCKS - PREP_DEG_BLOCKS) * 256 + threadIdx.x;
        if (g <= NGRAPH) {
            int lo = 0, hi = N_NODES;
            while (lo < hi) {
                int mid = (lo + hi) >> 1;
                if (batch[mid] < g) lo = mid + 1; else hi = mid;
            }
            gbound[g] = lo;
        }
    }
}

// All 5 layers' transposed concat bf16 weights in one launch. grid.y = layer.
__global__ void k_cvt_wT_all(
    const float* __restrict__ Wq1, const float* __restrict__ Wk1,
    const float* __restrict__ Wv1, const float* __restrict__ Ws1,
    const float* __restrict__ Wq_r, const float* __restrict__ Wk_r,
    const float* __restrict__ Wv_r, const float* __restrict__ Ws_r,
    ushort_t* __restrict__ Wb0, ushort_t* __restrict__ Wbr)
{
    const int L = blockIdx.y;
    const int K = (L == 0) ? DIM_IN : HIDDEN;
    int i = blockIdx.x * blockDim.x + threadIdx.x;
    if (i >= K * NALL) return;
    const float *Wq, *Wk, *Wv, *Ws; ushort_t* dst;
    if (L == 0) { Wq = Wq1; Wk = Wk1; Wv = Wv1; Ws = Ws1; dst = Wb0; }
    else {
        int j = L - 1;
        Wq = Wq_r + (size_t)j * HIDDEN * HD; Wk = Wk_r + (size_t)j * HIDDEN * HD;
        Wv = Wv_r + (size_t)j * HIDDEN * HD; Ws = Ws_r + (size_t)j * HIDDEN * HIDDEN;
        dst = Wbr + (size_t)j * HIDDEN * NALL;
    }
    int n = i / K, k = i - n * K;
    float v;
    if (n < 576)       v = Wq[(size_t)k * HD + n];
    else if (n < 1152) v = Wk[(size_t)k * HD + (n - 576)];
    else if (n < 1728) v = Wv[(size_t)k * HD + (n - 1152)];
    else               v = Ws[(size_t)k * HIDDEN + (n - 1728)];
    dst[i] = f2bf(v);
}

// ---------------------------------------------------------------------------
// bf16 MFMA fused QKVS projection (R14 structure — best measured).
// ---------------------------------------------------------------------------
template<int KDIM>
__global__ __launch_bounds__(256) void gemm_qkvs_mfma(
    const ushort_t* __restrict__ A, int M,
    const ushort_t* __restrict__ WbT,
    const float* __restrict__ bq, const float* __restrict__ bk,
    const float* __restrict__ bv, const float* __restrict__ bs,
    ushort_t* __restrict__ kvqs, uchar_t* __restrict__ kvf8)
{
    constexpr int LDB = KDIM + 8;       // padded B stride
    constexpr int K8  = KDIM >> 3;
    __shared__ __align__(16) ushort_t smem[128 * SLD];   // 26.6 KB
    const int t    = threadIdx.x;
    const int lane = t & 63;
    const int w    = t >> 6;
    const int wm   = w & 1, wn = w >> 1;
    const int quad = lane >> 4;
    const int l16  = lane & 15;
    const int m0   = blockIdx.y * 128;
    const int rb   = blockIdx.x;          // 0..18
    const int n0   = rb * 96;

    // cooperative B stage: 96 cols x KDIM, contiguous uint4 copies
    for (int idx = t; idx < 96 * K8; idx += 256) {
        int c = idx / K8, kc = idx - c * K8;
        uint4 v = *(const uint4*)(WbT + (size_t)(n0 + c) * KDIM + kc * 8);
        *(uint4*)(&smem[c * LDB + kc * 8]) = v;
    }

    // direct-global A fragment pointers (row-clamped for OOB M)
    const ushort_t* Arow[4];
    #pragma unroll
    for (int i = 0; i < 4; i++) {
        int row = m0 + wm * 64 + i * 16 + l16;
        row = min(row, M - 1);
        Arow[i] = A + (size_t)row * KDIM + quad * 8;
    }
    __syncthreads();

    f32x4 acc[4][3] = {};
    #pragma unroll
    for (int ks = 0; ks < KDIM; ks += 32) {
        bf16x8 af[4], bfv[3];
        #pragma unroll
        for (int i = 0; i < 4; i++) af[i] = *(const bf16x8*)(Arow[i] + ks);
        #pragma unroll
        for (int j = 0; j < 3; j++)
            bfv[j] = *(const bf16x8*)(&smem[(wn * 48 + j * 16 + l16) * LDB + ks + quad * 8]);
        #pragma unroll
        for (int i = 0; i < 4; i++)
            #pragma unroll
            for (int j = 0; j < 3; j++)
                acc[i][j] = __builtin_amdgcn_mfma_f32_16x16x32_bf16(af[i], bfv[j], acc[i][j], 0, 0, 0);
    }

    // region select (boundaries are multiples of 96)
    int region; const float* biasp;
    if (rb < 6)       { region = 0; biasp = bq; }
    else if (rb < 12) { region = 1; biasp = bk; }
    else if (rb < 18) { region = 2; biasp = bv; }
    else              { region = 3; biasp = bs; }
    const int colbase = (region == 3) ? 0 : (rb - region * 6) * 96;
    float bj[3];
    #pragma unroll
    for (int j = 0; j < 3; j++) bj[j] = biasp[colbase + wn * 48 + j * 16 + l16];

    __syncthreads();   // done reading B from smem; safe to overwrite

    if (region == 1 || region == 2) {
        // ---- K/V: fp8-e4m3 byte stage + cooperative 16B stores ---------
        uchar_t* bstage = (uchar_t*)smem;
        #pragma unroll
        for (int i = 0; i < 4; i++) {
            #pragma unroll
            for (int r = 0; r < 4; r++) {
                int row = wm * 64 + i * 16 + quad * 4 + r;
                #pragma unroll
                for (int j = 0; j < 3; j++) {
                    float v = acc[i][j][r] + bj[j];
                    int pk = __builtin_amdgcn_cvt_pk_fp8_f32(v, v, 0, false);
                    bstage[row * BSTR + wn * 48 + j * 16 + l16] = (uchar_t)(pk & 0xff);
                }
            }
        }
        __syncthreads();
        const int c0 = (rb - 6) * 96;   // 0..1056 spans K|V contiguously
        for (int idx = t; idx < 128 * 6; idx += 256) {
            int r = idx / 6, v4 = idx - r * 6;
            int row = m0 + r;
            if (row < M)
                *(uint4*)(kvf8 + (size_t)row * KVF8LD + c0 + v4 * 16) =
                    *(const uint4*)(bstage + r * BSTR + v4 * 16);
        }
    } else {
        // ---- Q/S: bf16 stage + cooperative 16B stores ------------------
        int dstoff = (region == 0) ? n0 : 576;
        #pragma unroll
        for (int i = 0; i < 4; i++) {
            #pragma unroll
            for (int r = 0; r < 4; r++) {
                int row = wm * 64 + i * 16 + quad * 4 + r;
                #pragma unroll
                for (int j = 0; j < 3; j++)
                    smem[row * SLD + wn * 48 + j * 16 + l16] = f2bf(acc[i][j][r] + bj[j]);
            }
        }
        __syncthreads();
        for (int idx = t; idx < 128 * 12; idx += 256) {
            int r = idx / 12, v = idx - r * 12;
            int row = m0 + r;
            if (row < M)
                *(uint4*)(kvqs + (size_t)row * LDROW + dstoff + v * 8) =
                    *(const uint4*)(&smem[r * SLD + v * 8]);
        }
    }
}

// ---------------------------------------------------------------------------
// CSR construction (scan + scatter; degree done in k_prep)
// ---------------------------------------------------------------------------
__global__ __launch_bounds__(1024) void k_scan(const int* __restrict__ deg,
                                               int* __restrict__ row_ptr,
                                               int* __restrict__ cursor)
{
    __shared__ int part[1024];
    int t = threadIdx.x;
    const int chunk = (N_NODES + 1023) / 1024;  // 20
    int b = t * chunk;
    int s = 0;
    for (int i = 0; i < chunk; i++)
        if (b + i < N_NODES) s += deg[b + i];
    part[t] = s;
    __syncthreads();
    for (int o = 1; o < 1024; o <<= 1) {
        int v = (t >= o) ? part[t - o] : 0;
        __syncthreads();
        part[t] += v;
        __syncthreads();
    }
    int run = part[t] - s;
    for (int i = 0; i < chunk; i++) {
        if (b + i < N_NODES) {
            row_ptr[b + i] = run;
            cursor[b + i]  = run;
            run += deg[b + i];
        }
    }
    if (t == 1023) row_ptr[N_NODES] = part[1023];
}

__global__ void k_scatter(const int* __restrict__ esrc, const int* __restrict__ edst,
                          int* __restrict__ cursor, int* __restrict__ csrc,
                          int* __restrict__ cdst)
{
    int e = blockIdx.x * blockDim.x + threadIdx.x;
    if (e < N_EDGES) {
        int d = edst[e];
        int pos = atomicAdd(&cursor[d], 1);
        csrc[pos] = esrc[e];
        cdst[pos] = d;
    }
}

// ---------------------------------------------------------------------------
// EDGE-PARALLEL logits (SDDMM): alpha[e][h] = (Q[dst[e],h] . K[src[e],h])/sqrt(96)
// No LDS, no barriers — every wave free-runs. Lane map per edge pair:
// sub = which edge, (g 0..5, qr 0..3) = (head, 24-dim quarter); 4-lane shfl
// reduce; lane qr==0 writes. Edges are CSR dst-sorted, so a wave's contiguous
// 16-edge strip spans ~2 dst nodes -> Q reads hit L1/L2.
// ---------------------------------------------------------------------------
#define ELOG_EPW    16                      // edges per wave
#define ELOG_BLOCKS (N_EDGES / (ELOG_EPW * 4))   // 2500 (exact)
__global__ __launch_bounds__(256) void k_edge_logits(
    const ushort_t* __restrict__ kvqs, const uchar_t* __restrict__ kvf8,
    const int* __restrict__ csrc, const int* __restrict__ cdst,
    float* __restrict__ alphag)
{
    const int wid  = (blockIdx.x * 256 + threadIdx.x) >> 6;
    const int lane = threadIdx.x & 63;
    const int sub  = lane >> 5;
    const int h32  = lane & 31;
    const int g    = h32 >> 2;             // 0..7 (6,7 idle)
    const int gg   = (g < 6) ? g : 0;
    const int qr   = h32 & 3;
    const float qa = 0.10206207261596577f; // 1/sqrt(96)

    const int base0 = wid * ELOG_EPW;

    for (int off = 0; off < ELOG_EPW; off += 4) {
        const int base = base0 + off;
        unsigned int kb[2][6];
        unsigned int qb[2][12];
        // issue all loads for 2 edge-pairs before any math
        #pragma unroll
        for (int j = 0; j < 2; j++) {
            int e  = base + 2 * j + sub;
            int ec = min(e, N_EDGES - 1);
            int src = csrc[ec], dst = cdst[ec];
            const uchar_t* kp = kvf8 + (size_t)src * KVF8LD + gg * HIDDEN + qr * 24;
            uint2 a0 = *(const uint2*)(kp);
            uint2 a1 = *(const uint2*)(kp + 8);
            uint2 a2 = *(const uint2*)(kp + 16);
            kb[j][0] = a0.x; kb[j][1] = a0.y; kb[j][2] = a1.x;
            kb[j][3] = a1.y; kb[j][4] = a2.x; kb[j][5] = a2.y;
            const ushort_t* qp = kvqs + (size_t)dst * LDROW + gg * HIDDEN + qr * 24;
            uint4 q0 = *(const uint4*)(qp);
            uint4 q1 = *(const uint4*)(qp + 8);
            uint4 q2 = *(const uint4*)(qp + 16);
            qb[j][0] = q0.x; qb[j][1] = q0.y; qb[j][2]  = q0.z; qb[j][3]  = q0.w;
            qb[j][4] = q1.x; qb[j][5] = q1.y; qb[j][6]  = q1.z; qb[j][7]  = q1.w;
            qb[j][8] = q2.x; qb[j][9] = q2.y; qb[j][10] = q2.z; qb[j][11] = q2.w;
        }
        #pragma unroll
        for (int j = 0; j < 2; j++) {
            int e = base + 2 * j + sub;
            float p = 0.f;
            #pragma unroll
            for (int k2 = 0; k2 < 6; k2++) {
                f32x2 lo = __builtin_amdgcn_cvt_pk_f32_fp8(kb[j][k2], false);
                f32x2 hi = __builtin_amdgcn_cvt_pk_f32_fp8(kb[j][k2], true);
                p += lo[0] * bflo(qb[j][2 * k2])     + lo[1] * bfhi(qb[j][2 * k2])
                   + hi[0] * bflo(qb[j][2 * k2 + 1]) + hi[1] * bfhi(qb[j][2 * k2 + 1]);
            }
            p += __shfl_xor(p, 1, 64);
            p += __shfl_xor(p, 2, 64);
            if (e < N_EDGES && g < 6 && qr == 0)
                alphag[(size_t)e * NH + g] = p * qa;
        }
    }
}

// ---------------------------------------------------------------------------
// NODE-PARALLEL softmax + V aggregation. One wave per node (R2 structure).
// Pass 1 is gone: per chunk, {contiguous alpha load -> softmax -> batched V
// gather}. One random-gather leg instead of two.
// ---------------------------------------------------------------------------
__global__ __launch_bounds__(64) void k_node_agg(
    const ushort_t* __restrict__ kvqs, const uchar_t* __restrict__ kvf8,
    const int* __restrict__ row_ptr, const int* __restrict__ csrc,
    const float* __restrict__ alphag, ushort_t* __restrict__ hb)
{
    const int n    = blockIdx.x;
    const int lane = threadIdx.x;          // 0..63

    __shared__ float wbuf[CHUNK * NH];
    __shared__ int   srcs[CHUNK];
    __shared__ float mh[NH], lh[NH], scl[NH], linv[NH];
    __shared__ float arr[HD];

    const int beg = row_ptr[n], end = row_ptr[n + 1];
    const ushort_t* qk = kvqs + (size_t)n * LDROW;

    if (lane < NH) { mh[lane] = -1e30f; lh[lane] = 0.f; }

    // softmax lane mapping
    const int sub = lane >> 5;             // 0/1
    const int h32 = lane & 31;
    // pass-2 lane mapping: 48 lanes own 12 dims each, head-aligned
    const int hh  = lane >> 3;             // 0..7 (6,7 idle in pass 2)
    const int j8  = lane & 7;
    const uchar_t* vb = kvf8 + 576 + ((hh < 6) ? hh : 0) * HIDDEN + j8 * 12;

    float acc[12];
    #pragma unroll
    for (int d = 0; d < 12; d++) acc[d] = 0.f;

    __syncthreads();   // m/l ready (single wave: degenerates to waitcnt)

    for (int cb = beg; cb < end; cb += CHUNK) {
        const int c = min(CHUNK, end - cb);
        if (lane < c) srcs[lane] = csrc[cb + lane];
        // contiguous logits load: c*6 floats
        for (int i = lane; i < c * NH; i += 64)
            wbuf[i] = alphag[(size_t)cb * NH + i];
        __syncthreads();

        // ---- softmax: 3 iterations x 2 heads (32 lanes each) ------------
        #pragma unroll
        for (int s = 0; s < 3; s++) {
            int h = 2 * s + sub;
            float logit = (h32 < c) ? wbuf[h32 * NH + h] : -1e30f;
            float cm = logit;
            #pragma unroll
            for (int o = 16; o; o >>= 1) cm = fmaxf(cm, __shfl_xor(cm, o, 32));
            cm = fmaxf(cm, mh[h]);
            float wv = (h32 < c) ? __expf(logit - cm) : 0.f;
            if (h32 < c) wbuf[h32 * NH + h] = wv;
            float lp = wv;
            #pragma unroll
            for (int o = 16; o; o >>= 1) lp += __shfl_xor(lp, o, 32);
            if (h32 == 0) {
                float sc = __expf(mh[h] - cm);
                scl[h] = sc;
                lh[h] = lh[h] * sc + lp;
                mh[h] = cm;
            }
        }
        __syncthreads();

        // ---- V aggregation, 48 lanes x 12 dims, 4-edge staging ----------
        if (lane < 48) {
            float sc = scl[hh];
            #pragma unroll
            for (int d = 0; d < 12; d++) acc[d] *= sc;
            int e = 0;
            for (; e + 4 <= c; e += 4) {
                unsigned int r[4][3];
                #pragma unroll
                for (int j = 0; j < 4; j++) {
                    const uchar_t* p = vb + (size_t)srcs[e + j] * KVF8LD;
                    r[j][0] = *(const unsigned int*)(p);
                    r[j][1] = *(const unsigned int*)(p + 4);
                    r[j][2] = *(const unsigned int*)(p + 8);
                }
                #pragma unroll
                for (int j = 0; j < 4; j++) {
                    float w0 = wbuf[(e + j) * NH + hh];
                    #pragma unroll
                    for (int k = 0; k < 3; k++) {
                        f32x2 lo = __builtin_amdgcn_cvt_pk_f32_fp8(r[j][k], false);
                        f32x2 hi = __builtin_amdgcn_cvt_pk_f32_fp8(r[j][k], true);
                        acc[4 * k]     += w0 * lo[0];
                        acc[4 * k + 1] += w0 * lo[1];
                        acc[4 * k + 2] += w0 * hi[0];
                        acc[4 * k + 3] += w0 * hi[1];
                    }
                }
            }
            for (; e < c; e++) {
                const uchar_t* p0 = vb + (size_t)srcs[e] * KVF8LD;
                float w0 = wbuf[e * NH + hh];
                #pragma unroll
                for (int k = 0; k < 3; k++) {
                    unsigned int r = *(const unsigned int*)(p0 + 4 * k);
                    f32x2 lo = __builtin_amdgcn_cvt_pk_f32_fp8(r, false);
                    f32x2 hi = __builtin_amdgcn_cvt_pk_f32_fp8(r, true);
                    acc[4 * k]     += w0 * lo[0];
                    acc[4 * k + 1] += w0 * lo[1];
                    acc[4 * k + 2] += w0 * hi[0];
                    acc[4 * k + 3] += w0 * hi[1];
                }
            }
        }
        __syncthreads();   // wbuf/srcs reuse guard for next chunk
    }

    if (lane < NH) linv[lane] = (lh[lane] > 0.f) ? 1.0f / lh[lane] : 0.f;
    __syncthreads();
    if (lane < 48) {
        float li = linv[hh];
        #pragma unroll
        for (int d = 0; d < 12; d++)
            arr[hh * HIDDEN + j8 * 12 + d] = acc[d] * li;
    }
    __syncthreads();

    {
        int d = lane;
        float s = (arr[d] + arr[HIDDEN + d] + arr[2 * HIDDEN + d] +
                   arr[3 * HIDDEN + d] + arr[4 * HIDDEN + d] + arr[5 * HIDDEN + d])
                  * (1.0f / 6.0f);
        s += bfs(qk[576 + d]);
        s = fmaxf(s, 0.0f);
        hb[n * HIDDEN + d] = f2bf(s);
        if (lane < 32) {
            int d2 = 64 + lane;
            float s2 = (arr[d2] + arr[HIDDEN + d2] + arr[2 * HIDDEN + d2] +
                        arr[3 * HIDDEN + d2] + arr[4 * HIDDEN + d2] + arr[5 * HIDDEN + d2])
                       * (1.0f / 6.0f);
            s2 += bfs(qk[576 + d2]);
            s2 = fmaxf(s2, 0.0f);
            hb[n * HIDDEN + d2] = f2bf(s2);
        }
    }
}

// ---------------------------------------------------------------------------
// Head with fused mean-pool: block g sums its contiguous node range (bf16 h).
// ---------------------------------------------------------------------------
__global__ __launch_bounds__(128) void k_head(
    const ushort_t* __restrict__ hb, const int* __restrict__ gbound,
    const float* __restrict__ fc1w, const float* __restrict__ fc1b,
    const float* __restrict__ fc2w, const float* __restrict__ fc2b,
    const float* __restrict__ arcw, float* __restrict__ out)
{
    int g = blockIdx.x, t = threadIdx.x;
    __shared__ float v0[HIDDEN], v1[HIDDEN], v2[HIDDEN];
    __shared__ float gnorm;
    const int s0 = gbound[g], s1 = gbound[g + 1];
    float cnt = fmaxf((float)(s1 - s0), 1.0f);
    if (t < HIDDEN) {
        float s = 0.f;
        for (int n = s0; n < s1; n++) s += bfs(hb[(size_t)n * HIDDEN + t]);
        v0[t] = s / cnt;
    }
    __syncthreads();
    if (t < HIDDEN) {
        float s = fc1b[t];
        for (int k = 0; k < HIDDEN; k++) s += v0[k] * fc1w[k * HIDDEN + t];
        v1[t] = fmaxf(s, 0.f);
    }
    __syncthreads();
    if (t < HIDDEN) {
        float s = fc2b[t];
        for (int k = 0; k < HIDDEN; k++) s += v1[k] * fc2w[k * HIDDEN + t];
        v2[t] = fmaxf(s, 0.f);
    }
    __syncthreads();
    if (t == 0) {
        float s = 0.f;
        for (int k = 0; k < HIDDEN; k++) s += v2[k] * v2[k];
        gnorm = sqrtf(s) + 1e-12f;
    }
    __syncthreads();
    if (t < NCLS) {
        float dot = 0.f, wn = 0.f;
        const float* wr = arcw + (size_t)t * HIDDEN;
        for (int k = 0; k < HIDDEN; k++) {
            float w = wr[k];
            dot += w * v2[k];
            wn  += w * w;
        }
        out[g * NCLS + t] = 30.0f * dot / (gnorm * (sqrtf(wn) + 1e-12f));
    }
}

// ---------------------------------------------------------------------------
extern "C" void kernel_launch(void* const* d_in, const int* in_sizes, int n_in,
                              void* d_out, int out_size, void* d_ws, size_t ws_size,
                              hipStream_t stream)
{
    (void)in_sizes; (void)n_in; (void)out_size; (void)ws_size;

    const float* x     = (const float*)d_in[0];
    const int*   ei    = (const int*)d_in[1];
    const int*   batch = (const int*)d_in[2];
    const float* Wq1 = (const float*)d_in[3];  const float* bq1 = (const float*)d_in[4];
    const float* Wk1 = (const float*)d_in[5];  const float* bk1 = (const float*)d_in[6];
    const float* Wv1 = (const float*)d_in[7];  const float* bv1 = (const float*)d_in[8];
    const float* Ws1 = (const float*)d_in[9];  const float* bs1 = (const float*)d_in[10];
    const float* Wq_r = (const float*)d_in[11]; const float* bq_r = (const float*)d_in[12];
    const float* Wk_r = (const float*)d_in[13]; const float* bk_r = (const float*)d_in[14];
    const float* Wv_r = (const float*)d_in[15]; const float* bv_r = (const float*)d_in[16];
    const float* Ws_r = (const float*)d_in[17]; const float* bs_r = (const float*)d_in[18];
    const float* fc1w = (const float*)d_in[19]; const float* fc1b = (const float*)d_in[20];
    const float* fc2w = (const float*)d_in[21]; const float* fc2b = (const float*)d_in[22];
    const float* arcw = (const float*)d_in[23];
    float* out = (float*)d_out;

    const int* esrc = ei;
    const int* edst = ei + N_EDGES;

    char* base = (char*)d_ws;
    size_t off = 0;
    auto alloc = [&](size_t bytes) -> void* {
        off = (off + 255) & ~(size_t)255;
        void* p = base + off;
        off += bytes;
        return p;
    };
    ushort_t* kvqs = (ushort_t*)alloc((size_t)N_NODES * LDROW * 2);  // 28.2 MB
    uchar_t*  kvf8 = (uchar_t*)alloc((size_t)N_NODES * KVF8LD);      // 23.0 MB
    ushort_t* xb  = (ushort_t*)alloc((size_t)N_NODES * DIM_IN * 2);
    ushort_t* hb0 = (ushort_t*)alloc((size_t)N_NODES * HIDDEN * 2);
    ushort_t* hb1 = (ushort_t*)alloc((size_t)N_NODES * HIDDEN * 2);
    ushort_t* Wb0 = (ushort_t*)alloc((size_t)DIM_IN * NALL * 2);
    ushort_t* Wbr = (ushort_t*)alloc((size_t)4 * HIDDEN * NALL * 2);
    float* alphag  = (float*)alloc((size_t)N_EDGES * NH * 4);        // 3.84 MB
    int*   deg     = (int*)alloc(N_NODES * 4);
    int*   row_ptr = (int*)alloc((N_NODES + 1) * 4);
    int*   cursor  = (int*)alloc(N_NODES * 4);
    int*   csrc    = (int*)alloc(N_EDGES * 4);
    int*   cdst    = (int*)alloc(N_EDGES * 4);
    int*   gbound  = (int*)alloc((NGRAPH + 1) * 4);

    // prep: x cast | degree | graph boundaries (one launch) + weight cast
    hipMemsetAsync(deg, 0, N_NODES * 4, stream);
    k_prep<<<PREP_CVT_BLOCKS + PREP_DEG_BLOCKS + PREP_GB_BLOCKS, 256, 0, stream>>>(
        x, xb, edst, deg, batch, gbound);
    {
        dim3 gw((DIM_IN * NALL + 255) / 256, 5);
        k_cvt_wT_all<<<gw, 256, 0, stream>>>(Wq1, Wk1, Wv1, Ws1,
                                             Wq_r, Wk_r, Wv_r, Ws_r, Wb0, Wbr);
    }
    k_scan<<<1, 1024, 0, stream>>>(deg, row_ptr, cursor);
    k_scatter<<<(N_EDGES + 255) / 256, 256, 0, stream>>>(esrc, edst, cursor, csrc, cdst);

    const ushort_t* Ain = xb;
    ushort_t* hbcur = hb0;
    for (int L = 0; L < 5; L++) {
        const ushort_t* Wb = (L == 0) ? Wb0 : (Wbr + (size_t)(L - 1) * HIDDEN * NALL);
        const float *bq, *bk, *bv, *bs;
        if (L == 0) { bq = bq1; bk = bk1; bv = bv1; bs = bs1; }
        else {
            int i = L - 1;
            bq = bq_r + (size_t)i * HD; bk = bk_r + (size_t)i * HD;
            bv = bv_r + (size_t)i * HD; bs = bs_r + (size_t)i * HIDDEN;
        }
        dim3 g(19, (N_NODES + 127) / 128);
        if (L == 0)
            gemm_qkvs_mfma<DIM_IN><<<g, 256, 0, stream>>>(Ain, N_NODES, Wb,
                                                          bq, bk, bv, bs, kvqs, kvf8);
        else
            gemm_qkvs_mfma<HIDDEN><<<g, 256, 0, stream>>>(Ain, N_NODES, Wb,
                                                          bq, bk, bv, bs, kvqs, kvf8);
        k_edge_logits<<<ELOG_BLOCKS, 256, 0, stream>>>(kvqs, kvf8, csrc, cdst, alphag);
        k_node_agg<<<N_NODES, 64, 0, stream>>>(kvqs, kvf8, row_ptr, csrc, alphag, hbcur);
        Ain = hbcur;
        hbcur = (hbcur == hb0) ? hb1 : hb0;
    }

    k_head<<<NGRAPH, 128, 0, stream>>>(hbcur == hb0 ? hb1 : hb0, gbound,
                                       fc1w, fc1b, fc2w, fc2b, arcw, out);
}

// Round 10
// 511.339 us; speedup vs baseline: 1.0972x; 1.0972x over previous
//
#include <hip/hip_runtime.h>
#include <math.h>

#define N_NODES 20000
#define N_EDGES 160000
#define DIM_IN  128
#define HIDDEN  96
#define NH      6
#define HD      576      // NH*HIDDEN
#define LDROW   704      // bf16 row stride: Q(576)|S(96)|pad(32) = 11 lines
#define KVF8LD  1152     // fp8 row stride BYTES: K(576)|V(576) = 9 lines
#define NALL    1824     // concat QKVS weight cols
#define NGRAPH  512
#define NCLS    128
#define CHUNK   32       // edges per softmax chunk
#define SLD     104      // bf16 LDS stage row stride (ushorts)
#define BSTR    112      // fp8 LDS stage row stride (bytes, mult of 16)

typedef unsigned short ushort_t;
typedef unsigned char uchar_t;
typedef __attribute__((ext_vector_type(8))) short bf16x8;
typedef __attribute__((ext_vector_type(4))) float f32x4;
typedef __attribute__((ext_vector_type(2))) float f32x2;

static __device__ __forceinline__ ushort_t f2bf(float f) {
    unsigned int u = __float_as_uint(f);
    return (ushort_t)((u + 0x7fffu + ((u >> 16) & 1u)) >> 16);  // RNE
}
static __device__ __forceinline__ float bfs(ushort_t u) { return __uint_as_float((unsigned int)u << 16); }
static __device__ __forceinline__ float bflo(unsigned int u) { return __uint_as_float(u << 16); }
static __device__ __forceinline__ float bfhi(unsigned int u) { return __uint_as_float(u & 0xffff0000u); }

// ---------------------------------------------------------------------------
// Fused prep: x->bf16 cast | edge degree histogram | graph boundaries.
// ---------------------------------------------------------------------------
#define PREP_CVT_BLOCKS 10000   // 20000*128/256
#define PREP_DEG_BLOCKS 625     // 160000/256
#define PREP_GB_BLOCKS  3       // ceil((NGRAPH+1)/256)
__global__ void k_prep(const float* __restrict__ x, ushort_t* __restrict__ xb,
                       const int* __restrict__ edst, int* __restrict__ deg,
                       const int* __restrict__ batch, int* __restrict__ gbound)
{
    int b = blockIdx.x;
    if (b < PREP_CVT_BLOCKS) {
        int i = b * 256 + threadIdx.x;
        if (i < N_NODES * DIM_IN) xb[i] = f2bf(x[i]);
    } else if (b < PREP_CVT_BLOCKS + PREP_DEG_BLOCKS) {
        int e = (b - PREP_CVT_BLOCKS) * 256 + threadIdx.x;
        if (e < N_EDGES) atomicAdd(&deg[edst[e]], 1);
    } else {
        int g = (b - PREP_CVT_BLOCKS - PREP_DEG_BLOCKS) * 256 + threadIdx.x;
        if (g <= NGRAPH) {
            int lo = 0, hi = N_NODES;
            while (lo < hi) {
                int mid = (lo + hi) >> 1;
                if (batch[mid] < g) lo = mid + 1; else hi = mid;
            }
            gbound[g] = lo;
        }
    }
}

// All 5 layers' transposed concat bf16 weights in one launch. grid.y = layer.
__global__ void k_cvt_wT_all(
    const float* __restrict__ Wq1, const float* __restrict__ Wk1,
    const float* __restrict__ Wv1, const float* __restrict__ Ws1,
    const float* __restrict__ Wq_r, const float* __restrict__ Wk_r,
    const float* __restrict__ Wv_r, const float* __restrict__ Ws_r,
    ushort_t* __restrict__ Wb0, ushort_t* __restrict__ Wbr)
{
    const int L = blockIdx.y;
    const int K = (L == 0) ? DIM_IN : HIDDEN;
    int i = blockIdx.x * blockDim.x + threadIdx.x;
    if (i >= K * NALL) return;
    const float *Wq, *Wk, *Wv, *Ws; ushort_t* dst;
    if (L == 0) { Wq = Wq1; Wk = Wk1; Wv = Wv1; Ws = Ws1; dst = Wb0; }
    else {
        int j = L - 1;
        Wq = Wq_r + (size_t)j * HIDDEN * HD; Wk = Wk_r + (size_t)j * HIDDEN * HD;
        Wv = Wv_r + (size_t)j * HIDDEN * HD; Ws = Ws_r + (size_t)j * HIDDEN * HIDDEN;
        dst = Wbr + (size_t)j * HIDDEN * NALL;
    }
    int n = i / K, k = i - n * K;
    float v;
    if (n < 576)       v = Wq[(size_t)k * HD + n];
    else if (n < 1152) v = Wk[(size_t)k * HD + (n - 576)];
    else if (n < 1728) v = Wv[(size_t)k * HD + (n - 1152)];
    else               v = Ws[(size_t)k * HIDDEN + (n - 1728)];
    dst[i] = f2bf(v);
}

// ---------------------------------------------------------------------------
// bf16 MFMA fused QKVS projection (R14 structure — best measured).
// 128x96 tile, 4 waves (2x2). B staged in LDS; A direct from global.
// Output staged through the same LDS after a barrier. K/V regions (rb 6..17)
// emit fp8-e4m3 into kvf8 [K|V]; Q/S bf16 into kvqs [Q|S].
// ---------------------------------------------------------------------------
template<int KDIM>
__global__ __launch_bounds__(256) void gemm_qkvs_mfma(
    const ushort_t* __restrict__ A, int M,
    const ushort_t* __restrict__ WbT,
    const float* __restrict__ bq, const float* __restrict__ bk,
    const float* __restrict__ bv, const float* __restrict__ bs,
    ushort_t* __restrict__ kvqs, uchar_t* __restrict__ kvf8)
{
    constexpr int LDB = KDIM + 8;       // padded B stride
    constexpr int K8  = KDIM >> 3;
    __shared__ __align__(16) ushort_t smem[128 * SLD];   // 26.6 KB
    const int t    = threadIdx.x;
    const int lane = t & 63;
    const int w    = t >> 6;
    const int wm   = w & 1, wn = w >> 1;
    const int quad = lane >> 4;
    const int l16  = lane & 15;
    const int m0   = blockIdx.y * 128;
    const int rb   = blockIdx.x;          // 0..18
    const int n0   = rb * 96;

    // cooperative B stage: 96 cols x KDIM, contiguous uint4 copies
    for (int idx = t; idx < 96 * K8; idx += 256) {
        int c = idx / K8, kc = idx - c * K8;
        uint4 v = *(const uint4*)(WbT + (size_t)(n0 + c) * KDIM + kc * 8);
        *(uint4*)(&smem[c * LDB + kc * 8]) = v;
    }

    // direct-global A fragment pointers (row-clamped for OOB M)
    const ushort_t* Arow[4];
    #pragma unroll
    for (int i = 0; i < 4; i++) {
        int row = m0 + wm * 64 + i * 16 + l16;
        row = min(row, M - 1);
        Arow[i] = A + (size_t)row * KDIM + quad * 8;
    }
    __syncthreads();

    f32x4 acc[4][3] = {};
    #pragma unroll
    for (int ks = 0; ks < KDIM; ks += 32) {
        bf16x8 af[4], bfv[3];
        #pragma unroll
        for (int i = 0; i < 4; i++) af[i] = *(const bf16x8*)(Arow[i] + ks);
        #pragma unroll
        for (int j = 0; j < 3; j++)
            bfv[j] = *(const bf16x8*)(&smem[(wn * 48 + j * 16 + l16) * LDB + ks + quad * 8]);
        #pragma unroll
        for (int i = 0; i < 4; i++)
            #pragma unroll
            for (int j = 0; j < 3; j++)
                acc[i][j] = __builtin_amdgcn_mfma_f32_16x16x32_bf16(af[i], bfv[j], acc[i][j], 0, 0, 0);
    }

    // region select (boundaries are multiples of 96)
    int region; const float* biasp;
    if (rb < 6)       { region = 0; biasp = bq; }
    else if (rb < 12) { region = 1; biasp = bk; }
    else if (rb < 18) { region = 2; biasp = bv; }
    else              { region = 3; biasp = bs; }
    const int colbase = (region == 3) ? 0 : (rb - region * 6) * 96;
    float bj[3];
    #pragma unroll
    for (int j = 0; j < 3; j++) bj[j] = biasp[colbase + wn * 48 + j * 16 + l16];

    __syncthreads();   // done reading B from smem; safe to overwrite

    if (region == 1 || region == 2) {
        // ---- K/V: fp8-e4m3 byte stage + cooperative 16B stores ---------
        uchar_t* bstage = (uchar_t*)smem;
        #pragma unroll
        for (int i = 0; i < 4; i++) {
            #pragma unroll
            for (int r = 0; r < 4; r++) {
                int row = wm * 64 + i * 16 + quad * 4 + r;
                #pragma unroll
                for (int j = 0; j < 3; j++) {
                    float v = acc[i][j][r] + bj[j];
                    int pk = __builtin_amdgcn_cvt_pk_fp8_f32(v, v, 0, false);
                    bstage[row * BSTR + wn * 48 + j * 16 + l16] = (uchar_t)(pk & 0xff);
                }
            }
        }
        __syncthreads();
        const int c0 = (rb - 6) * 96;   // 0..1056 spans K|V contiguously
        for (int idx = t; idx < 128 * 6; idx += 256) {
            int r = idx / 6, v4 = idx - r * 6;
            int row = m0 + r;
            if (row < M)
                *(uint4*)(kvf8 + (size_t)row * KVF8LD + c0 + v4 * 16) =
                    *(const uint4*)(bstage + r * BSTR + v4 * 16);
        }
    } else {
        // ---- Q/S: bf16 stage + cooperative 16B stores ------------------
        int dstoff = (region == 0) ? n0 : 576;
        #pragma unroll
        for (int i = 0; i < 4; i++) {
            #pragma unroll
            for (int r = 0; r < 4; r++) {
                int row = wm * 64 + i * 16 + quad * 4 + r;
                #pragma unroll
                for (int j = 0; j < 3; j++)
                    smem[row * SLD + wn * 48 + j * 16 + l16] = f2bf(acc[i][j][r] + bj[j]);
            }
        }
        __syncthreads();
        for (int idx = t; idx < 128 * 12; idx += 256) {
            int r = idx / 12, v = idx - r * 12;
            int row = m0 + r;
            if (row < M)
                *(uint4*)(kvqs + (size_t)row * LDROW + dstoff + v * 8) =
                    *(const uint4*)(&smem[r * SLD + v * 8]);
        }
    }
}

// ---------------------------------------------------------------------------
// CSR construction (scan + scatter; degree done in k_prep)
// ---------------------------------------------------------------------------
__global__ __launch_bounds__(1024) void k_scan(const int* __restrict__ deg,
                                               int* __restrict__ row_ptr,
                                               int* __restrict__ cursor)
{
    __shared__ int part[1024];
    int t = threadIdx.x;
    const int chunk = (N_NODES + 1023) / 1024;  // 20
    int b = t * chunk;
    int s = 0;
    for (int i = 0; i < chunk; i++)
        if (b + i < N_NODES) s += deg[b + i];
    part[t] = s;
    __syncthreads();
    for (int o = 1; o < 1024; o <<= 1) {
        int v = (t >= o) ? part[t - o] : 0;
        __syncthreads();
        part[t] += v;
        __syncthreads();
    }
    int run = part[t] - s;
    for (int i = 0; i < chunk; i++) {
        if (b + i < N_NODES) {
            row_ptr[b + i] = run;
            cursor[b + i]  = run;
            run += deg[b + i];
        }
    }
    if (t == 1023) row_ptr[N_NODES] = part[1023];
}

__global__ void k_scatter(const int* __restrict__ esrc, const int* __restrict__ edst,
                          int* __restrict__ cursor, int* __restrict__ csrc)
{
    int e = blockIdx.x * blockDim.x + threadIdx.x;
    if (e < N_EDGES) {
        int pos = atomicAdd(&cursor[edst[e]], 1);
        csrc[pos] = esrc[e];
    }
}

// ---------------------------------------------------------------------------
// Fused per-destination-node attention. fp8 K (pass 1) + fp8 V (pass 2).
// ONE WAVE (64 threads) PER NODE — verified best (R2, 511.7us total).
// ---------------------------------------------------------------------------
__global__ __launch_bounds__(64) void node_attn(
    const ushort_t* __restrict__ kvqs, const uchar_t* __restrict__ kvf8,
    const int* __restrict__ row_ptr, const int* __restrict__ csrc,
    ushort_t* __restrict__ hb)
{
    const int n    = blockIdx.x;
    const int lane = threadIdx.x;          // 0..63

    __shared__ float QA[HD];               // Q as f32; reused as 'arr' in epilogue
    __shared__ float wbuf[CHUNK * NH];
    __shared__ int   srcs[CHUNK];
    __shared__ float mh[NH], lh[NH], scl[NH], linv[NH];

    const int beg = row_ptr[n], end = row_ptr[n + 1];
    const ushort_t* qk = kvqs + (size_t)n * LDROW;

    // Q stage: 72 uint4 (8 bf16 each) -> 576 floats. lanes 0..63 + 0..7.
    {
        uint4 v = *(const uint4*)(qk + lane * 8);
        unsigned int uu[4] = {v.x, v.y, v.z, v.w};
        #pragma unroll
        for (int j = 0; j < 4; j++) {
            QA[lane * 8 + 2 * j]     = bflo(uu[j]);
            QA[lane * 8 + 2 * j + 1] = bfhi(uu[j]);
        }
        if (lane < 8) {
            uint4 v2 = *(const uint4*)(qk + (64 + lane) * 8);
            unsigned int uu2[4] = {v2.x, v2.y, v2.z, v2.w};
            #pragma unroll
            for (int j = 0; j < 4; j++) {
                QA[(64 + lane) * 8 + 2 * j]     = bflo(uu2[j]);
                QA[(64 + lane) * 8 + 2 * j + 1] = bfhi(uu2[j]);
            }
        }
    }
    if (lane < NH) { mh[lane] = -1e30f; lh[lane] = 0.f; }

    // pass-1 lane mapping: sub-edge slot + (head, quarter)
    const int sub = lane >> 5;             // 0/1: which of 2 edges per iter
    const int h32 = lane & 31;
    const int g   = h32 >> 2;              // 0..7 (6,7 idle in pass 1)
    const int gg  = (g < 6) ? g : 0;
    const int qr  = h32 & 3;
    // pass-2 lane mapping: 48 lanes own 12 dims each, head-aligned
    const int hh  = lane >> 3;             // 0..7 (6,7 idle in pass 2)
    const int j8  = lane & 7;
    const uchar_t* vb = kvf8 + 576 + ((hh < 6) ? hh : 0) * HIDDEN + j8 * 12;

    float acc[12];
    #pragma unroll
    for (int d = 0; d < 12; d++) acc[d] = 0.f;
    const float qa = 0.10206207261596577f; // 1/sqrt(96)

    __syncthreads();   // Q, m, l ready (single wave: degenerates to waitcnt)

    for (int cb = beg; cb < end; cb += CHUNK) {
        const int c = min(CHUNK, end - cb);
        __syncthreads();
        if (lane < c) srcs[lane] = csrc[cb + lane];
        __syncthreads();

        // ---- pass 1: logits, 2 edges per iteration, fp8 K ---------------
        #pragma unroll 2
        for (int eb = 0; eb < c; eb += 2) {
            int e = eb + sub;
            bool act = (e < c) && (g < 6);
            int src = srcs[(e < c) ? e : 0];
            const uchar_t* kp = kvf8 + (size_t)src * KVF8LD + gg * HIDDEN + qr * 24;
            uint2 a0 = *(const uint2*)(kp);
            uint2 a1 = *(const uint2*)(kp + 8);
            uint2 a2 = *(const uint2*)(kp + 16);
            const float* qb = &QA[gg * HIDDEN + qr * 24];
            unsigned int uu[6] = {a0.x, a0.y, a1.x, a1.y, a2.x, a2.y};
            float p = 0.f;
            #pragma unroll
            for (int k2 = 0; k2 < 6; k2++) {
                f32x2 lo = __builtin_amdgcn_cvt_pk_f32_fp8(uu[k2], false);
                f32x2 hi = __builtin_amdgcn_cvt_pk_f32_fp8(uu[k2], true);
                p += lo[0] * qb[4 * k2]     + lo[1] * qb[4 * k2 + 1]
                   + hi[0] * qb[4 * k2 + 2] + hi[1] * qb[4 * k2 + 3];
            }
            p += __shfl_xor(p, 1, 64);
            p += __shfl_xor(p, 2, 64);
            if (act && qr == 0) wbuf[e * NH + g] = p * qa;
        }
        __syncthreads();

        // ---- softmax: 3 iterations x 2 heads (32 lanes each) ------------
        #pragma unroll
        for (int s = 0; s < 3; s++) {
            int h = 2 * s + sub;
            float logit = (h32 < c) ? wbuf[h32 * NH + h] : -1e30f;
            float cm = logit;
            #pragma unroll
            for (int o = 16; o; o >>= 1) cm = fmaxf(cm, __shfl_xor(cm, o, 32));
            cm = fmaxf(cm, mh[h]);
            float wv = (h32 < c) ? __expf(logit - cm) : 0.f;
            if (h32 < c) wbuf[h32 * NH + h] = wv;
            float lp = wv;
            #pragma unroll
            for (int o = 16; o; o >>= 1) lp += __shfl_xor(lp, o, 32);
            if (h32 == 0) {
                float sc = __expf(mh[h] - cm);
                scl[h] = sc;
                lh[h] = lh[h] * sc + lp;
                mh[h] = cm;
            }
        }
        __syncthreads();

        // ---- pass 2: fp8 V aggregation, 48 lanes x 12 dims --------------
        if (lane < 48) {
            float sc = scl[hh];
            #pragma unroll
            for (int d = 0; d < 12; d++) acc[d] *= sc;
            int e = 0;
            for (; e + 2 <= c; e += 2) {
                int s0 = srcs[e], s1 = srcs[e + 1];
                const uchar_t* p0 = vb + (size_t)s0 * KVF8LD;
                const uchar_t* p1 = vb + (size_t)s1 * KVF8LD;
                unsigned int r0[3], r1[3];
                #pragma unroll
                for (int k = 0; k < 3; k++) {
                    r0[k] = *(const unsigned int*)(p0 + 4 * k);
                    r1[k] = *(const unsigned int*)(p1 + 4 * k);
                }
                float w0 = wbuf[e * NH + hh], w1 = wbuf[(e + 1) * NH + hh];
                #pragma unroll
                for (int k = 0; k < 3; k++) {
                    f32x2 lo0 = __builtin_amdgcn_cvt_pk_f32_fp8(r0[k], false);
                    f32x2 hi0 = __builtin_amdgcn_cvt_pk_f32_fp8(r0[k], true);
                    acc[4 * k]     += w0 * lo0[0];
                    acc[4 * k + 1] += w0 * lo0[1];
                    acc[4 * k + 2] += w0 * hi0[0];
                    acc[4 * k + 3] += w0 * hi0[1];
                    f32x2 lo1 = __builtin_amdgcn_cvt_pk_f32_fp8(r1[k], false);
                    f32x2 hi1 = __builtin_amdgcn_cvt_pk_f32_fp8(r1[k], true);
                    acc[4 * k]     += w1 * lo1[0];
                    acc[4 * k + 1] += w1 * lo1[1];
                    acc[4 * k + 2] += w1 * hi1[0];
                    acc[4 * k + 3] += w1 * hi1[1];
                }
            }
            if (e < c) {
                int s0 = srcs[e];
                const uchar_t* p0 = vb + (size_t)s0 * KVF8LD;
                float w0 = wbuf[e * NH + hh];
                #pragma unroll
                for (int k = 0; k < 3; k++) {
                    unsigned int r = *(const unsigned int*)(p0 + 4 * k);
                    f32x2 lo = __builtin_amdgcn_cvt_pk_f32_fp8(r, false);
                    f32x2 hi = __builtin_amdgcn_cvt_pk_f32_fp8(r, true);
                    acc[4 * k]     += w0 * lo[0];
                    acc[4 * k + 1] += w0 * lo[1];
                    acc[4 * k + 2] += w0 * hi[0];
                    acc[4 * k + 3] += w0 * hi[1];
                }
            }
        }
    }

    if (lane < NH) linv[lane] = (lh[lane] > 0.f) ? 1.0f / lh[lane] : 0.f;
    __syncthreads();
    if (lane < 48) {
        float li = linv[hh];
        #pragma unroll
        for (int d = 0; d < 12; d++)
            QA[hh * HIDDEN + j8 * 12 + d] = acc[d] * li;   // QA reused as 'arr'
    }
    __syncthreads();

    {
        int d = lane;
        float s = (QA[d] + QA[HIDDEN + d] + QA[2 * HIDDEN + d] +
                   QA[3 * HIDDEN + d] + QA[4 * HIDDEN + d] + QA[5 * HIDDEN + d])
                  * (1.0f / 6.0f);
        s += bfs(qk[576 + d]);
        s = fmaxf(s, 0.0f);
        hb[n * HIDDEN + d] = f2bf(s);
        if (lane < 32) {
            int d2 = 64 + lane;
            float s2 = (QA[d2] + QA[HIDDEN + d2] + QA[2 * HIDDEN + d2] +
                        QA[3 * HIDDEN + d2] + QA[4 * HIDDEN + d2] + QA[5 * HIDDEN + d2])
                       * (1.0f / 6.0f);
            s2 += bfs(qk[576 + d2]);
            s2 = fmaxf(s2, 0.0f);
            hb[n * HIDDEN + d2] = f2bf(s2);
        }
    }
}

// ---------------------------------------------------------------------------
// Head with fused mean-pool: block g sums its contiguous node range (bf16 h).
// ---------------------------------------------------------------------------
__global__ __launch_bounds__(128) void k_head(
    const ushort_t* __restrict__ hb, const int* __restrict__ gbound,
    const float* __restrict__ fc1w, const float* __restrict__ fc1b,
    const float* __restrict__ fc2w, const float* __restrict__ fc2b,
    const float* __restrict__ arcw, float* __restrict__ out)
{
    int g = blockIdx.x, t = threadIdx.x;
    __shared__ float v0[HIDDEN], v1[HIDDEN], v2[HIDDEN];
    __shared__ float gnorm;
    const int s0 = gbound[g], s1 = gbound[g + 1];
    float cnt = fmaxf((float)(s1 - s0), 1.0f);
    if (t < HIDDEN) {
        float s = 0.f;
        for (int n = s0; n < s1; n++) s += bfs(hb[(size_t)n * HIDDEN + t]);
        v0[t] = s / cnt;
    }
    __syncthreads();
    if (t < HIDDEN) {
        float s = fc1b[t];
        for (int k = 0; k < HIDDEN; k++) s += v0[k] * fc1w[k * HIDDEN + t];
        v1[t] = fmaxf(s, 0.f);
    }
    __syncthreads();
    if (t < HIDDEN) {
        float s = fc2b[t];
        for (int k = 0; k < HIDDEN; k++) s += v1[k] * fc2w[k * HIDDEN + t];
        v2[t] = fmaxf(s, 0.f);
    }
    __syncthreads();
    if (t == 0) {
        float s = 0.f;
        for (int k = 0; k < HIDDEN; k++) s += v2[k] * v2[k];
        gnorm = sqrtf(s) + 1e-12f;
    }
    __syncthreads();
    if (t < NCLS) {
        float dot = 0.f, wn = 0.f;
        const float* wr = arcw + (size_t)t * HIDDEN;
        for (int k = 0; k < HIDDEN; k++) {
            float w = wr[k];
            dot += w * v2[k];
            wn  += w * w;
        }
        out[g * NCLS + t] = 30.0f * dot / (gnorm * (sqrtf(wn) + 1e-12f));
    }
}

// ---------------------------------------------------------------------------
extern "C" void kernel_launch(void* const* d_in, const int* in_sizes, int n_in,
                              void* d_out, int out_size, void* d_ws, size_t ws_size,
                              hipStream_t stream)
{
    (void)in_sizes; (void)n_in; (void)out_size; (void)ws_size;

    const float* x     = (const float*)d_in[0];
    const int*   ei    = (const int*)d_in[1];
    const int*   batch = (const int*)d_in[2];
    const float* Wq1 = (const float*)d_in[3];  const float* bq1 = (const float*)d_in[4];
    const float* Wk1 = (const float*)d_in[5];  const float* bk1 = (const float*)d_in[6];
    const float* Wv1 = (const float*)d_in[7];  const float* bv1 = (const float*)d_in[8];
    const float* Ws1 = (const float*)d_in[9];  const float* bs1 = (const float*)d_in[10];
    const float* Wq_r = (const float*)d_in[11]; const float* bq_r = (const float*)d_in[12];
    const float* Wk_r = (const float*)d_in[13]; const float* bk_r = (const float*)d_in[14];
    const float* Wv_r = (const float*)d_in[15]; const float* bv_r = (const float*)d_in[16];
    const float* Ws_r = (const float*)d_in[17]; const float* bs_r = (const float*)d_in[18];
    const float* fc1w = (const float*)d_in[19]; const float* fc1b = (const float*)d_in[20];
    const float* fc2w = (const float*)d_in[21]; const float* fc2b = (const float*)d_in[22];
    const float* arcw = (const float*)d_in[23];
    float* out = (float*)d_out;

    const int* esrc = ei;
    const int* edst = ei + N_EDGES;

    char* base = (char*)d_ws;
    size_t off = 0;
    auto alloc = [&](size_t bytes) -> void* {
        off = (off + 255) & ~(size_t)255;
        void* p = base + off;
        off += bytes;
        return p;
    };
    ushort_t* kvqs = (ushort_t*)alloc((size_t)N_NODES * LDROW * 2);  // 28.2 MB
    uchar_t*  kvf8 = (uchar_t*)alloc((size_t)N_NODES * KVF8LD);      // 23.0 MB
    ushort_t* xb  = (ushort_t*)alloc((size_t)N_NODES * DIM_IN * 2);
    ushort_t* hb0 = (ushort_t*)alloc((size_t)N_NODES * HIDDEN * 2);
    ushort_t* hb1 = (ushort_t*)alloc((size_t)N_NODES * HIDDEN * 2);
    ushort_t* Wb0 = (ushort_t*)alloc((size_t)DIM_IN * NALL * 2);
    ushort_t* Wbr = (ushort_t*)alloc((size_t)4 * HIDDEN * NALL * 2);
    int*   deg     = (int*)alloc(N_NODES * 4);
    int*   row_ptr = (int*)alloc((N_NODES + 1) * 4);
    int*   cursor  = (int*)alloc(N_NODES * 4);
    int*   csrc    = (int*)alloc(N_EDGES * 4);
    int*   gbound  = (int*)alloc((NGRAPH + 1) * 4);

    // prep: x cast | degree | graph boundaries (one launch) + weight cast
    hipMemsetAsync(deg, 0, N_NODES * 4, stream);
    k_prep<<<PREP_CVT_BLOCKS + PREP_DEG_BLOCKS + PREP_GB_BLOCKS, 256, 0, stream>>>(
        x, xb, edst, deg, batch, gbound);
    {
        dim3 gw((DIM_IN * NALL + 255) / 256, 5);
        k_cvt_wT_all<<<gw, 256, 0, stream>>>(Wq1, Wk1, Wv1, Ws1,
                                             Wq_r, Wk_r, Wv_r, Ws_r, Wb0, Wbr);
    }
    k_scan<<<1, 1024, 0, stream>>>(deg, row_ptr, cursor);
    k_scatter<<<(N_EDGES + 255) / 256, 256, 0, stream>>>(esrc, edst, cursor, csrc);

    const ushort_t* Ain = xb;
    ushort_t* hbcur = hb0;
    for (int L = 0; L < 5; L++) {
        const ushort_t* Wb = (L == 0) ? Wb0 : (Wbr + (size_t)(L - 1) * HIDDEN * NALL);
        const float *bq, *bk, *bv, *bs;
        if (L == 0) { bq = bq1; bk = bk1; bv = bv1; bs = bs1; }
        else {
            int i = L - 1;
            bq = bq_r + (size_t)i * HD; bk = bk_r + (size_t)i * HD;
            bv = bv_r + (size_t)i * HD; bs = bs_r + (size_t)i * HIDDEN;
        }
        dim3 g(19, (N_NODES + 127) / 128);
        if (L == 0)
            gemm_qkvs_mfma<DIM_IN><<<g, 256, 0, stream>>>(Ain, N_NODES, Wb,
                                                          bq, bk, bv, bs, kvqs, kvf8);
        else
            gemm_qkvs_mfma<HIDDEN><<<g, 256, 0, stream>>>(Ain, N_NODES, Wb,
                                                          bq, bk, bv, bs, kvqs, kvf8);
        node_attn<<<N_NODES, 64, 0, stream>>>(kvqs, kvf8, row_ptr, csrc, hbcur);
        Ain = hbcur;
        hbcur = (hbcur == hb0) ? hb1 : hb0;
    }

    k_head<<<NGRAPH, 128, 0, stream>>>(hbcur == hb0 ? hb1 : hb0, gbound,
                                       fc1w, fc1b, fc2w, fc2b, arcw, out);
}

// Round 11
// 502.171 us; speedup vs baseline: 1.1172x; 1.0183x over previous
//
#include <hip/hip_runtime.h>
#include <math.h>

#define N_NODES 20000
#define N_EDGES 160000
#define DIM_IN  128
#define HIDDEN  96
#define NH      6
#define HD      576      // NH*HIDDEN
#define LDROW   704      // bf16 row stride: Q(576)|S(96)|pad(32) = 11 lines
#define KVF8LD  1152     // fp8 row stride BYTES: K(576)|V(576) = 9 lines
#define NALL    1824     // concat QKVS weight cols
#define NGRAPH  512
#define NCLS    128
#define CHUNK   32       // edges per softmax chunk
#define SLD     104      // bf16 LDS stage row stride (ushorts)
#define BSTR    112      // fp8 LDS stage row stride (bytes, mult of 16)

typedef unsigned short ushort_t;
typedef unsigned char uchar_t;
typedef __attribute__((ext_vector_type(8))) short bf16x8;
typedef __attribute__((ext_vector_type(4))) float f32x4;
typedef __attribute__((ext_vector_type(2))) float f32x2;

static __device__ __forceinline__ ushort_t f2bf(float f) {
    unsigned int u = __float_as_uint(f);
    return (ushort_t)((u + 0x7fffu + ((u >> 16) & 1u)) >> 16);  // RNE
}
static __device__ __forceinline__ float bfs(ushort_t u) { return __uint_as_float((unsigned int)u << 16); }
static __device__ __forceinline__ float bflo(unsigned int u) { return __uint_as_float(u << 16); }
static __device__ __forceinline__ float bfhi(unsigned int u) { return __uint_as_float(u & 0xffff0000u); }

// pack 4 f32 -> 4 fp8 bytes in one dword, via two independent cvt_pk calls
// (no read-modify 'old' operand chain)
static __device__ __forceinline__ unsigned int pk_fp8x4(float a, float b, float c, float d) {
    unsigned int lo = (unsigned int)__builtin_amdgcn_cvt_pk_fp8_f32(a, b, 0, false);
    unsigned int hi = (unsigned int)__builtin_amdgcn_cvt_pk_fp8_f32(c, d, 0, false);
    return (lo & 0xffffu) | (hi << 16);
}

// ---------------------------------------------------------------------------
// Fused prep: x->bf16 cast | edge degree histogram | graph boundaries.
// ---------------------------------------------------------------------------
#define PREP_CVT_BLOCKS 10000   // 20000*128/256
#define PREP_DEG_BLOCKS 625     // 160000/256
#define PREP_GB_BLOCKS  3       // ceil((NGRAPH+1)/256)
__global__ void k_prep(const float* __restrict__ x, ushort_t* __restrict__ xb,
                       const int* __restrict__ edst, int* __restrict__ deg,
                       const int* __restrict__ batch, int* __restrict__ gbound)
{
    int b = blockIdx.x;
    if (b < PREP_CVT_BLOCKS) {
        int i = b * 256 + threadIdx.x;
        if (i < N_NODES * DIM_IN) xb[i] = f2bf(x[i]);
    } else if (b < PREP_CVT_BLOCKS + PREP_DEG_BLOCKS) {
        int e = (b - PREP_CVT_BLOCKS) * 256 + threadIdx.x;
        if (e < N_EDGES) atomicAdd(&deg[edst[e]], 1);
    } else {
        int g = (b - PREP_CVT_BLOCKS - PREP_DEG_BLOCKS) * 256 + threadIdx.x;
        if (g <= NGRAPH) {
            int lo = 0, hi = N_NODES;
            while (lo < hi) {
                int mid = (lo + hi) >> 1;
                if (batch[mid] < g) lo = mid + 1; else hi = mid;
            }
            gbound[g] = lo;
        }
    }
}

// All 5 layers' transposed concat bf16 weights in one launch. grid.y = layer.
__global__ void k_cvt_wT_all(
    const float* __restrict__ Wq1, const float* __restrict__ Wk1,
    const float* __restrict__ Wv1, const float* __restrict__ Ws1,
    const float* __restrict__ Wq_r, const float* __restrict__ Wk_r,
    const float* __restrict__ Wv_r, const float* __restrict__ Ws_r,
    ushort_t* __restrict__ Wb0, ushort_t* __restrict__ Wbr)
{
    const int L = blockIdx.y;
    const int K = (L == 0) ? DIM_IN : HIDDEN;
    int i = blockIdx.x * blockDim.x + threadIdx.x;
    if (i >= K * NALL) return;
    const float *Wq, *Wk, *Wv, *Ws; ushort_t* dst;
    if (L == 0) { Wq = Wq1; Wk = Wk1; Wv = Wv1; Ws = Ws1; dst = Wb0; }
    else {
        int j = L - 1;
        Wq = Wq_r + (size_t)j * HIDDEN * HD; Wk = Wk_r + (size_t)j * HIDDEN * HD;
        Wv = Wv_r + (size_t)j * HIDDEN * HD; Ws = Ws_r + (size_t)j * HIDDEN * HIDDEN;
        dst = Wbr + (size_t)j * HIDDEN * NALL;
    }
    int n = i / K, k = i - n * K;
    float v;
    if (n < 576)       v = Wq[(size_t)k * HD + n];
    else if (n < 1152) v = Wk[(size_t)k * HD + (n - 576)];
    else if (n < 1728) v = Wv[(size_t)k * HD + (n - 1152)];
    else               v = Ws[(size_t)k * HIDDEN + (n - 1728)];
    dst[i] = f2bf(v);
}

// ---------------------------------------------------------------------------
// bf16 MFMA fused QKVS projection. R14 structure + SWAPPED-OPERAND epilogue:
// acc = mfma(B_frag, A_frag, acc) computes C^T. A/B fragment lane layouts are
// symmetric for 16x16x32 (row/col = lane&15, k = quad*8+reg), so each lane's
// 4-reg quad holds 4 CONSECUTIVE COLUMNS (quad*4+{0..3}) of output row l16.
// Epilogue packs 4 values per LDS write: fp8 -> 1 ds_write_b32 (was 4x b8),
// bf16 -> 1 8B write (was 4x b16).
// ---------------------------------------------------------------------------
template<int KDIM>
__global__ __launch_bounds__(256) void gemm_qkvs_mfma(
    const ushort_t* __restrict__ A, int M,
    const ushort_t* __restrict__ WbT,
    const float* __restrict__ bq, const float* __restrict__ bk,
    const float* __restrict__ bv, const float* __restrict__ bs,
    ushort_t* __restrict__ kvqs, uchar_t* __restrict__ kvf8)
{
    constexpr int LDB = KDIM + 8;       // padded B stride
    constexpr int K8  = KDIM >> 3;
    __shared__ __align__(16) ushort_t smem[128 * SLD];   // 26.6 KB
    const int t    = threadIdx.x;
    const int lane = t & 63;
    const int w    = t >> 6;
    const int wm   = w & 1, wn = w >> 1;
    const int quad = lane >> 4;
    const int l16  = lane & 15;
    const int m0   = blockIdx.y * 128;
    const int rb   = blockIdx.x;          // 0..18
    const int n0   = rb * 96;

    // cooperative B stage: 96 cols x KDIM, contiguous uint4 copies
    for (int idx = t; idx < 96 * K8; idx += 256) {
        int c = idx / K8, kc = idx - c * K8;
        uint4 v = *(const uint4*)(WbT + (size_t)(n0 + c) * KDIM + kc * 8);
        *(uint4*)(&smem[c * LDB + kc * 8]) = v;
    }

    // direct-global A fragment pointers (row-clamped for OOB M)
    const ushort_t* Arow[4];
    #pragma unroll
    for (int i = 0; i < 4; i++) {
        int row = m0 + wm * 64 + i * 16 + l16;
        row = min(row, M - 1);
        Arow[i] = A + (size_t)row * KDIM + quad * 8;
    }
    __syncthreads();

    f32x4 acc[4][3] = {};
    #pragma unroll
    for (int ks = 0; ks < KDIM; ks += 32) {
        bf16x8 af[4], bfv[3];
        #pragma unroll
        for (int i = 0; i < 4; i++) af[i] = *(const bf16x8*)(Arow[i] + ks);
        #pragma unroll
        for (int j = 0; j < 3; j++)
            bfv[j] = *(const bf16x8*)(&smem[(wn * 48 + j * 16 + l16) * LDB + ks + quad * 8]);
        // swapped operands: lane holds row m = wm*64+i*16+l16,
        // cols n = wn*48+j*16+quad*4+{0..3}
        #pragma unroll
        for (int i = 0; i < 4; i++)
            #pragma unroll
            for (int j = 0; j < 3; j++)
                acc[i][j] = __builtin_amdgcn_mfma_f32_16x16x32_bf16(bfv[j], af[i], acc[i][j], 0, 0, 0);
    }

    // region select (boundaries are multiples of 96)
    int region; const float* biasp;
    if (rb < 6)       { region = 0; biasp = bq; }
    else if (rb < 12) { region = 1; biasp = bk; }
    else if (rb < 18) { region = 2; biasp = bv; }
    else              { region = 3; biasp = bs; }
    const int colbase = (region == 3) ? 0 : (rb - region * 6) * 96;
    // per-lane 4-col bias (scalar loads; cols quad*4..quad*4+3)
    float bb[3][4];
    #pragma unroll
    for (int j = 0; j < 3; j++)
        #pragma unroll
        for (int r = 0; r < 4; r++)
            bb[j][r] = biasp[colbase + wn * 48 + j * 16 + quad * 4 + r];

    __syncthreads();   // done reading B from smem; safe to overwrite

    if (region == 1 || region == 2) {
        // ---- K/V: packed fp8 dword stage + cooperative 16B stores ------
        uchar_t* bstage = (uchar_t*)smem;
        #pragma unroll
        for (int i = 0; i < 4; i++) {
            int row = wm * 64 + i * 16 + l16;
            #pragma unroll
            for (int j = 0; j < 3; j++) {
                unsigned int pk = pk_fp8x4(acc[i][j][0] + bb[j][0],
                                           acc[i][j][1] + bb[j][1],
                                           acc[i][j][2] + bb[j][2],
                                           acc[i][j][3] + bb[j][3]);
                *(unsigned int*)(bstage + row * BSTR + wn * 48 + j * 16 + quad * 4) = pk;
            }
        }
        __syncthreads();
        const int c0 = (rb - 6) * 96;   // 0..1056 spans K|V contiguously
        for (int idx = t; idx < 128 * 6; idx += 256) {
            int r = idx / 6, v4 = idx - r * 6;
            int row = m0 + r;
            if (row < M)
                *(uint4*)(kvf8 + (size_t)row * KVF8LD + c0 + v4 * 16) =
                    *(const uint4*)(bstage + r * BSTR + v4 * 16);
        }
    } else {
        // ---- Q/S: packed bf16 8B stage + cooperative 16B stores --------
        int dstoff = (region == 0) ? n0 : 576;
        #pragma unroll
        for (int i = 0; i < 4; i++) {
            int row = wm * 64 + i * 16 + l16;
            #pragma unroll
            for (int j = 0; j < 3; j++) {
                unsigned int d0 = (unsigned int)f2bf(acc[i][j][0] + bb[j][0])
                                | ((unsigned int)f2bf(acc[i][j][1] + bb[j][1]) << 16);
                unsigned int d1 = (unsigned int)f2bf(acc[i][j][2] + bb[j][2])
                                | ((unsigned int)f2bf(acc[i][j][3] + bb[j][3]) << 16);
                uint2 dd; dd.x = d0; dd.y = d1;
                *(uint2*)(&smem[row * SLD + wn * 48 + j * 16 + quad * 4]) = dd;
            }
        }
        __syncthreads();
        for (int idx = t; idx < 128 * 12; idx += 256) {
            int r = idx / 12, v = idx - r * 12;
            int row = m0 + r;
            if (row < M)
                *(uint4*)(kvqs + (size_t)row * LDROW + dstoff + v * 8) =
                    *(const uint4*)(&smem[r * SLD + v * 8]);
        }
    }
}

// ---------------------------------------------------------------------------
// CSR construction (scan + scatter; degree done in k_prep)
// ---------------------------------------------------------------------------
__global__ __launch_bounds__(1024) void k_scan(const int* __restrict__ deg,
                                               int* __restrict__ row_ptr,
                                               int* __restrict__ cursor)
{
    __shared__ int part[1024];
    int t = threadIdx.x;
    const int chunk = (N_NODES + 1023) / 1024;  // 20
    int b = t * chunk;
    int s = 0;
    for (int i = 0; i < chunk; i++)
        if (b + i < N_NODES) s += deg[b + i];
    part[t] = s;
    __syncthreads();
    for (int o = 1; o < 1024; o <<= 1) {
        int v = (t >= o) ? part[t - o] : 0;
        __syncthreads();
        part[t] += v;
        __syncthreads();
    }
    int run = part[t] - s;
    for (int i = 0; i < chunk; i++) {
        if (b + i < N_NODES) {
            row_ptr[b + i] = run;
            cursor[b + i]  = run;
            run += deg[b + i];
        }
    }
    if (t == 1023) row_ptr[N_NODES] = part[1023];
}

__global__ void k_scatter(const int* __restrict__ esrc, const int* __restrict__ edst,
                          int* __restrict__ cursor, int* __restrict__ csrc)
{
    int e = blockIdx.x * blockDim.x + threadIdx.x;
    if (e < N_EDGES) {
        int pos = atomicAdd(&cursor[edst[e]], 1);
        csrc[pos] = esrc[e];
    }
}

// ---------------------------------------------------------------------------
// Fused per-destination-node attention. fp8 K (pass 1) + fp8 V (pass 2).
// ONE WAVE (64 threads) PER NODE — verified best (R2, 511.3us total).
// ---------------------------------------------------------------------------
__global__ __launch_bounds__(64) void node_attn(
    const ushort_t* __restrict__ kvqs, const uchar_t* __restrict__ kvf8,
    const int* __restrict__ row_ptr, const int* __restrict__ csrc,
    ushort_t* __restrict__ hb)
{
    const int n    = blockIdx.x;
    const int lane = threadIdx.x;          // 0..63

    __shared__ float QA[HD];               // Q as f32; reused as 'arr' in epilogue
    __shared__ float wbuf[CHUNK * NH];
    __shared__ int   srcs[CHUNK];
    __shared__ float mh[NH], lh[NH], scl[NH], linv[NH];

    const int beg = row_ptr[n], end = row_ptr[n + 1];
    const ushort_t* qk = kvqs + (size_t)n * LDROW;

    // Q stage: 72 uint4 (8 bf16 each) -> 576 floats. lanes 0..63 + 0..7.
    {
        uint4 v = *(const uint4*)(qk + lane * 8);
        unsigned int uu[4] = {v.x, v.y, v.z, v.w};
        #pragma unroll
        for (int j = 0; j < 4; j++) {
            QA[lane * 8 + 2 * j]     = bflo(uu[j]);
            QA[lane * 8 + 2 * j + 1] = bfhi(uu[j]);
        }
        if (lane < 8) {
            uint4 v2 = *(const uint4*)(qk + (64 + lane) * 8);
            unsigned int uu2[4] = {v2.x, v2.y, v2.z, v2.w};
            #pragma unroll
            for (int j = 0; j < 4; j++) {
                QA[(64 + lane) * 8 + 2 * j]     = bflo(uu2[j]);
                QA[(64 + lane) * 8 + 2 * j + 1] = bfhi(uu2[j]);
            }
        }
    }
    if (lane < NH) { mh[lane] = -1e30f; lh[lane] = 0.f; }

    // pass-1 lane mapping: sub-edge slot + (head, quarter)
    const int sub = lane >> 5;             // 0/1: which of 2 edges per iter
    const int h32 = lane & 31;
    const int g   = h32 >> 2;              // 0..7 (6,7 idle in pass 1)
    const int gg  = (g < 6) ? g : 0;
    const int qr  = h32 & 3;
    // pass-2 lane mapping: 48 lanes own 12 dims each, head-aligned
    const int hh  = lane >> 3;             // 0..7 (6,7 idle in pass 2)
    const int j8  = lane & 7;
    const uchar_t* vb = kvf8 + 576 + ((hh < 6) ? hh : 0) * HIDDEN + j8 * 12;

    float acc[12];
    #pragma unroll
    for (int d = 0; d < 12; d++) acc[d] = 0.f;
    const float qa = 0.10206207261596577f; // 1/sqrt(96)

    __syncthreads();   // Q, m, l ready (single wave: degenerates to waitcnt)

    for (int cb = beg; cb < end; cb += CHUNK) {
        const int c = min(CHUNK, end - cb);
        __syncthreads();
        if (lane < c) srcs[lane] = csrc[cb + lane];
        __syncthreads();

        // ---- pass 1: logits, 2 edges per iteration, fp8 K ---------------
        #pragma unroll 2
        for (int eb = 0; eb < c; eb += 2) {
            int e = eb + sub;
            bool act = (e < c) && (g < 6);
            int src = srcs[(e < c) ? e : 0];
            const uchar_t* kp = kvf8 + (size_t)src * KVF8LD + gg * HIDDEN + qr * 24;
            uint2 a0 = *(const uint2*)(kp);
            uint2 a1 = *(const uint2*)(kp + 8);
            uint2 a2 = *(const uint2*)(kp + 16);
            const float* qb = &QA[gg * HIDDEN + qr * 24];
            unsigned int uu[6] = {a0.x, a0.y, a1.x, a1.y, a2.x, a2.y};
            float p = 0.f;
            #pragma unroll
            for (int k2 = 0; k2 < 6; k2++) {
                f32x2 lo = __builtin_amdgcn_cvt_pk_f32_fp8(uu[k2], false);
                f32x2 hi = __builtin_amdgcn_cvt_pk_f32_fp8(uu[k2], true);
                p += lo[0] * qb[4 * k2]     + lo[1] * qb[4 * k2 + 1]
                   + hi[0] * qb[4 * k2 + 2] + hi[1] * qb[4 * k2 + 3];
            }
            p += __shfl_xor(p, 1, 64);
            p += __shfl_xor(p, 2, 64);
            if (act && qr == 0) wbuf[e * NH + g] = p * qa;
        }
        __syncthreads();

        // ---- softmax: 3 iterations x 2 heads (32 lanes each) ------------
        #pragma unroll
        for (int s = 0; s < 3; s++) {
            int h = 2 * s + sub;
            float logit = (h32 < c) ? wbuf[h32 * NH + h] : -1e30f;
            float cm = logit;
            #pragma unroll
            for (int o = 16; o; o >>= 1) cm = fmaxf(cm, __shfl_xor(cm, o, 32));
            cm = fmaxf(cm, mh[h]);
            float wv = (h32 < c) ? __expf(logit - cm) : 0.f;
            if (h32 < c) wbuf[h32 * NH + h] = wv;
            float lp = wv;
            #pragma unroll
            for (int o = 16; o; o >>= 1) lp += __shfl_xor(lp, o, 32);
            if (h32 == 0) {
                float sc = __expf(mh[h] - cm);
                scl[h] = sc;
                lh[h] = lh[h] * sc + lp;
                mh[h] = cm;
            }
        }
        __syncthreads();

        // ---- pass 2: fp8 V aggregation, 48 lanes x 12 dims --------------
        if (lane < 48) {
            float sc = scl[hh];
            #pragma unroll
            for (int d = 0; d < 12; d++) acc[d] *= sc;
            int e = 0;
            for (; e + 2 <= c; e += 2) {
                int s0 = srcs[e], s1 = srcs[e + 1];
                const uchar_t* p0 = vb + (size_t)s0 * KVF8LD;
                const uchar_t* p1 = vb + (size_t)s1 * KVF8LD;
                unsigned int r0[3], r1[3];
                #pragma unroll
                for (int k = 0; k < 3; k++) {
                    r0[k] = *(const unsigned int*)(p0 + 4 * k);
                    r1[k] = *(const unsigned int*)(p1 + 4 * k);
                }
                float w0 = wbuf[e * NH + hh], w1 = wbuf[(e + 1) * NH + hh];
                #pragma unroll
                for (int k = 0; k < 3; k++) {
                    f32x2 lo0 = __builtin_amdgcn_cvt_pk_f32_fp8(r0[k], false);
                    f32x2 hi0 = __builtin_amdgcn_cvt_pk_f32_fp8(r0[k], true);
                    acc[4 * k]     += w0 * lo0[0];
                    acc[4 * k + 1] += w0 * lo0[1];
                    acc[4 * k + 2] += w0 * hi0[0];
                    acc[4 * k + 3] += w0 * hi0[1];
                    f32x2 lo1 = __builtin_amdgcn_cvt_pk_f32_fp8(r1[k], false);
                    f32x2 hi1 = __builtin_amdgcn_cvt_pk_f32_fp8(r1[k], true);
                    acc[4 * k]     += w1 * lo1[0];
                    acc[4 * k + 1] += w1 * lo1[1];
                    acc[4 * k + 2] += w1 * hi1[0];
                    acc[4 * k + 3] += w1 * hi1[1];
                }
            }
            if (e < c) {
                int s0 = srcs[e];
                const uchar_t* p0 = vb + (size_t)s0 * KVF8LD;
                float w0 = wbuf[e * NH + hh];
                #pragma unroll
                for (int k = 0; k < 3; k++) {
                    unsigned int r = *(const unsigned int*)(p0 + 4 * k);
                    f32x2 lo = __builtin_amdgcn_cvt_pk_f32_fp8(r, false);
                    f32x2 hi = __builtin_amdgcn_cvt_pk_f32_fp8(r, true);
                    acc[4 * k]     += w0 * lo[0];
                    acc[4 * k + 1] += w0 * lo[1];
                    acc[4 * k + 2] += w0 * hi[0];
                    acc[4 * k + 3] += w0 * hi[1];
                }
            }
        }
    }

    if (lane < NH) linv[lane] = (lh[lane] > 0.f) ? 1.0f / lh[lane] : 0.f;
    __syncthreads();
    if (lane < 48) {
        float li = linv[hh];
        #pragma unroll
        for (int d = 0; d < 12; d++)
            QA[hh * HIDDEN + j8 * 12 + d] = acc[d] * li;   // QA reused as 'arr'
    }
    __syncthreads();

    {
        int d = lane;
        float s = (QA[d] + QA[HIDDEN + d] + QA[2 * HIDDEN + d] +
                   QA[3 * HIDDEN + d] + QA[4 * HIDDEN + d] + QA[5 * HIDDEN + d])
                  * (1.0f / 6.0f);
        s += bfs(qk[576 + d]);
        s = fmaxf(s, 0.0f);
        hb[n * HIDDEN + d] = f2bf(s);
        if (lane < 32) {
            int d2 = 64 + lane;
            float s2 = (QA[d2] + QA[HIDDEN + d2] + QA[2 * HIDDEN + d2] +
                        QA[3 * HIDDEN + d2] + QA[4 * HIDDEN + d2] + QA[5 * HIDDEN + d2])
                       * (1.0f / 6.0f);
            s2 += bfs(qk[576 + d2]);
            s2 = fmaxf(s2, 0.0f);
            hb[n * HIDDEN + d2] = f2bf(s2);
        }
    }
}

// ---------------------------------------------------------------------------
// Head with fused mean-pool: block g sums its contiguous node range (bf16 h).
// ---------------------------------------------------------------------------
__global__ __launch_bounds__(128) void k_head(
    const ushort_t* __restrict__ hb, const int* __restrict__ gbound,
    const float* __restrict__ fc1w, const float* __restrict__ fc1b,
    const float* __restrict__ fc2w, const float* __restrict__ fc2b,
    const float* __restrict__ arcw, float* __restrict__ out)
{
    int g = blockIdx.x, t = threadIdx.x;
    __shared__ float v0[HIDDEN], v1[HIDDEN], v2[HIDDEN];
    __shared__ float gnorm;
    const int s0 = gbound[g], s1 = gbound[g + 1];
    float cnt = fmaxf((float)(s1 - s0), 1.0f);
    if (t < HIDDEN) {
        float s = 0.f;
        for (int n = s0; n < s1; n++) s += bfs(hb[(size_t)n * HIDDEN + t]);
        v0[t] = s / cnt;
    }
    __syncthreads();
    if (t < HIDDEN) {
        float s = fc1b[t];
        for (int k = 0; k < HIDDEN; k++) s += v0[k] * fc1w[k * HIDDEN + t];
        v1[t] = fmaxf(s, 0.f);
    }
    __syncthreads();
    if (t < HIDDEN) {
        float s = fc2b[t];
        for (int k = 0; k < HIDDEN; k++) s += v1[k] * fc2w[k * HIDDEN + t];
        v2[t] = fmaxf(s, 0.f);
    }
    __syncthreads();
    if (t == 0) {
        float s = 0.f;
        for (int k = 0; k < HIDDEN; k++) s += v2[k] * v2[k];
        gnorm = sqrtf(s) + 1e-12f;
    }
    __syncthreads();
    if (t < NCLS) {
        float dot = 0.f, wn = 0.f;
        const float* wr = arcw + (size_t)t * HIDDEN;
        for (int k = 0; k < HIDDEN; k++) {
            float w = wr[k];
            dot += w * v2[k];
            wn  += w * w;
        }
        out[g * NCLS + t] = 30.0f * dot / (gnorm * (sqrtf(wn) + 1e-12f));
    }
}

// ---------------------------------------------------------------------------
extern "C" void kernel_launch(void* const* d_in, const int* in_sizes, int n_in,
                              void* d_out, int out_size, void* d_ws, size_t ws_size,
                              hipStream_t stream)
{
    (void)in_sizes; (void)n_in; (void)out_size; (void)ws_size;

    const float* x     = (const float*)d_in[0];
    const int*   ei    = (const int*)d_in[1];
    const int*   batch = (const int*)d_in[2];
    const float* Wq1 = (const float*)d_in[3];  const float* bq1 = (const float*)d_in[4];
    const float* Wk1 = (const float*)d_in[5];  const float* bk1 = (const float*)d_in[6];
    const float* Wv1 = (const float*)d_in[7];  const float* bv1 = (const float*)d_in[8];
    const float* Ws1 = (const float*)d_in[9];  const float* bs1 = (const float*)d_in[10];
    const float* Wq_r = (const float*)d_in[11]; const float* bq_r = (const float*)d_in[12];
    const float* Wk_r = (const float*)d_in[13]; const float* bk_r = (const float*)d_in[14];
    const float* Wv_r = (const float*)d_in[15]; const float* bv_r = (const float*)d_in[16];
    const float* Ws_r = (const float*)d_in[17]; const float* bs_r = (const float*)d_in[18];
    const float* fc1w = (const float*)d_in[19]; const float* fc1b = (const float*)d_in[20];
    const float* fc2w = (const float*)d_in[21]; const float* fc2b = (const float*)d_in[22];
    const float* arcw = (const float*)d_in[23];
    float* out = (float*)d_out;

    const int* esrc = ei;
    const int* edst = ei + N_EDGES;

    char* base = (char*)d_ws;
    size_t off = 0;
    auto alloc = [&](size_t bytes) -> void* {
        off = (off + 255) & ~(size_t)255;
        void* p = base + off;
        off += bytes;
        return p;
    };
    ushort_t* kvqs = (ushort_t*)alloc((size_t)N_NODES * LDROW * 2);  // 28.2 MB
    uchar_t*  kvf8 = (uchar_t*)alloc((size_t)N_NODES * KVF8LD);      // 23.0 MB
    ushort_t* xb  = (ushort_t*)alloc((size_t)N_NODES * DIM_IN * 2);
    ushort_t* hb0 = (ushort_t*)alloc((size_t)N_NODES * HIDDEN * 2);
    ushort_t* hb1 = (ushort_t*)alloc((size_t)N_NODES * HIDDEN * 2);
    ushort_t* Wb0 = (ushort_t*)alloc((size_t)DIM_IN * NALL * 2);
    ushort_t* Wbr = (ushort_t*)alloc((size_t)4 * HIDDEN * NALL * 2);
    int*   deg     = (int*)alloc(N_NODES * 4);
    int*   row_ptr = (int*)alloc((N_NODES + 1) * 4);
    int*   cursor  = (int*)alloc(N_NODES * 4);
    int*   csrc    = (int*)alloc(N_EDGES * 4);
    int*   gbound  = (int*)alloc((NGRAPH + 1) * 4);

    // prep: x cast | degree | graph boundaries (one launch) + weight cast
    hipMemsetAsync(deg, 0, N_NODES * 4, stream);
    k_prep<<<PREP_CVT_BLOCKS + PREP_DEG_BLOCKS + PREP_GB_BLOCKS, 256, 0, stream>>>(
        x, xb, edst, deg, batch, gbound);
    {
        dim3 gw((DIM_IN * NALL + 255) / 256, 5);
        k_cvt_wT_all<<<gw, 256, 0, stream>>>(Wq1, Wk1, Wv1, Ws1,
                                             Wq_r, Wk_r, Wv_r, Ws_r, Wb0, Wbr);
    }
    k_scan<<<1, 1024, 0, stream>>>(deg, row_ptr, cursor);
    k_scatter<<<(N_EDGES + 255) / 256, 256, 0, stream>>>(esrc, edst, cursor, csrc);

    const ushort_t* Ain = xb;
    ushort_t* hbcur = hb0;
    for (int L = 0; L < 5; L++) {
        const ushort_t* Wb = (L == 0) ? Wb0 : (Wbr + (size_t)(L - 1) * HIDDEN * NALL);
        const float *bq, *bk, *bv, *bs;
        if (L == 0) { bq = bq1; bk = bk1; bv = bv1; bs = bs1; }
        else {
            int i = L - 1;
            bq = bq_r + (size_t)i * HD; bk = bk_r + (size_t)i * HD;
            bv = bv_r + (size_t)i * HD; bs = bs_r + (size_t)i * HIDDEN;
        }
        dim3 g(19, (N_NODES + 127) / 128);
        if (L == 0)
            gemm_qkvs_mfma<DIM_IN><<<g, 256, 0, stream>>>(Ain, N_NODES, Wb,
                                                          bq, bk, bv, bs, kvqs, kvf8);
        else
            gemm_qkvs_mfma<HIDDEN><<<g, 256, 0, stream>>>(Ain, N_NODES, Wb,
                                                          bq, bk, bv, bs, kvqs, kvf8);
        node_attn<<<N_NODES, 64, 0, stream>>>(kvqs, kvf8, row_ptr, csrc, hbcur);
        Ain = hbcur;
        hbcur = (hbcur == hb0) ? hb1 : hb0;
    }

    k_head<<<NGRAPH, 128, 0, stream>>>(hbcur == hb0 ? hb1 : hb0, gbound,
                                       fc1w, fc1b, fc2w, fc2b, arcw, out);
}

// Round 12
// 495.566 us; speedup vs baseline: 1.1321x; 1.0133x over previous
//
#include <hip/hip_runtime.h>
#include <math.h>

#define N_NODES 20000
#define N_EDGES 160000
#define DIM_IN  128
#define HIDDEN  96
#define NH      6
#define HD      576      // NH*HIDDEN
#define LDROW   704      // bf16 row stride: Q(576)|S(96)|pad(32) = 11 lines
#define KVF8LD  1152     // fp8 row stride BYTES: K(576)|V(576) = 9 lines
#define NALL    1824     // concat QKVS weight cols
#define NGRAPH  512
#define NCLS    128
#define CHUNK   32       // edges per softmax chunk
#define SLD     104      // bf16 LDS stage row stride (ushorts)
#define BSTR    112      // fp8 LDS stage row stride (bytes, mult of 16)
#define GEMM_NB   19     // column blocks (1824/96)
#define GEMM_NMT  157    // row tiles (ceil(20000/128))
#define GEMM_LIN  (GEMM_NB * GEMM_NMT)          // 2983
#define GEMM_NCH  ((GEMM_LIN + 7) / 8)          // 373 per XCD chunk
#define GEMM_GRID (GEMM_NCH * 8)                // 2984 (1 pad block)

typedef unsigned short ushort_t;
typedef unsigned char uchar_t;
typedef __attribute__((ext_vector_type(8))) short bf16x8;
typedef __attribute__((ext_vector_type(4))) float f32x4;
typedef __attribute__((ext_vector_type(2))) float f32x2;

static __device__ __forceinline__ ushort_t f2bf(float f) {
    unsigned int u = __float_as_uint(f);
    return (ushort_t)((u + 0x7fffu + ((u >> 16) & 1u)) >> 16);  // RNE
}
static __device__ __forceinline__ float bfs(ushort_t u) { return __uint_as_float((unsigned int)u << 16); }
static __device__ __forceinline__ float bflo(unsigned int u) { return __uint_as_float(u << 16); }
static __device__ __forceinline__ float bfhi(unsigned int u) { return __uint_as_float(u & 0xffff0000u); }

// pack 4 f32 -> 4 fp8 bytes in one dword, via two independent cvt_pk calls
static __device__ __forceinline__ unsigned int pk_fp8x4(float a, float b, float c, float d) {
    unsigned int lo = (unsigned int)__builtin_amdgcn_cvt_pk_fp8_f32(a, b, 0, false);
    unsigned int hi = (unsigned int)__builtin_amdgcn_cvt_pk_fp8_f32(c, d, 0, false);
    return (lo & 0xffffu) | (hi << 16);
}

// ---------------------------------------------------------------------------
// Fused prep: x->bf16 cast | edge degree histogram | graph boundaries.
// ---------------------------------------------------------------------------
#define PREP_CVT_BLOCKS 10000   // 20000*128/256
#define PREP_DEG_BLOCKS 625     // 160000/256
#define PREP_GB_BLOCKS  3       // ceil((NGRAPH+1)/256)
__global__ void k_prep(const float* __restrict__ x, ushort_t* __restrict__ xb,
                       const int* __restrict__ edst, int* __restrict__ deg,
                       const int* __restrict__ batch, int* __restrict__ gbound)
{
    int b = blockIdx.x;
    if (b < PREP_CVT_BLOCKS) {
        int i = b * 256 + threadIdx.x;
        if (i < N_NODES * DIM_IN) xb[i] = f2bf(x[i]);
    } else if (b < PREP_CVT_BLOCKS + PREP_DEG_BLOCKS) {
        int e = (b - PREP_CVT_BLOCKS) * 256 + threadIdx.x;
        if (e < N_EDGES) atomicAdd(&deg[edst[e]], 1);
    } else {
        int g = (b - PREP_CVT_BLOCKS - PREP_DEG_BLOCKS) * 256 + threadIdx.x;
        if (g <= NGRAPH) {
            int lo = 0, hi = N_NODES;
            while (lo < hi) {
                int mid = (lo + hi) >> 1;
                if (batch[mid] < g) lo = mid + 1; else hi = mid;
            }
            gbound[g] = lo;
        }
    }
}

// All 5 layers' transposed concat bf16 weights in one launch. grid.y = layer.
__global__ void k_cvt_wT_all(
    const float* __restrict__ Wq1, const float* __restrict__ Wk1,
    const float* __restrict__ Wv1, const float* __restrict__ Ws1,
    const float* __restrict__ Wq_r, const float* __restrict__ Wk_r,
    const float* __restrict__ Wv_r, const float* __restrict__ Ws_r,
    ushort_t* __restrict__ Wb0, ushort_t* __restrict__ Wbr)
{
    const int L = blockIdx.y;
    const int K = (L == 0) ? DIM_IN : HIDDEN;
    int i = blockIdx.x * blockDim.x + threadIdx.x;
    if (i >= K * NALL) return;
    const float *Wq, *Wk, *Wv, *Ws; ushort_t* dst;
    if (L == 0) { Wq = Wq1; Wk = Wk1; Wv = Wv1; Ws = Ws1; dst = Wb0; }
    else {
        int j = L - 1;
        Wq = Wq_r + (size_t)j * HIDDEN * HD; Wk = Wk_r + (size_t)j * HIDDEN * HD;
        Wv = Wv_r + (size_t)j * HIDDEN * HD; Ws = Ws_r + (size_t)j * HIDDEN * HIDDEN;
        dst = Wbr + (size_t)j * HIDDEN * NALL;
    }
    int n = i / K, k = i - n * K;
    float v;
    if (n < 576)       v = Wq[(size_t)k * HD + n];
    else if (n < 1152) v = Wk[(size_t)k * HD + (n - 576)];
    else if (n < 1728) v = Wv[(size_t)k * HD + (n - 1152)];
    else               v = Ws[(size_t)k * HIDDEN + (n - 1728)];
    dst[i] = f2bf(v);
}

// ---------------------------------------------------------------------------
// bf16 MFMA fused QKVS projection. Swapped-operand epilogue (verified R11)
// + XCD-chunked block swizzle (T1): all 19 column-blocks of one 128-row
// A-subtile run on the SAME XCD, so the 24.6 KB subtile is an L2 hit after
// first touch instead of being re-fetched by up to 8 XCD-private L2s.
// ---------------------------------------------------------------------------
template<int KDIM>
__global__ __launch_bounds__(256) void gemm_qkvs_mfma(
    const ushort_t* __restrict__ A, int M,
    const ushort_t* __restrict__ WbT,
    const float* __restrict__ bq, const float* __restrict__ bk,
    const float* __restrict__ bv, const float* __restrict__ bs,
    ushort_t* __restrict__ kvqs, uchar_t* __restrict__ kvf8)
{
    // XCD-chunked swizzle: HW round-robins blockIdx across 8 XCDs, so
    // blocks with equal (blockIdx&7) share an XCD; give each a contiguous
    // lin range -> rb-blocks of one mtile stay on one XCD. Perf-only.
    const int lin = (blockIdx.x & 7) * GEMM_NCH + (blockIdx.x >> 3);
    if (lin >= GEMM_LIN) return;           // uniform per block (pad block)
    const int rb = lin % GEMM_NB;          // 0..18 column block
    const int m0 = (lin / GEMM_NB) * 128;  // row tile base

    constexpr int LDB = KDIM + 8;       // padded B stride
    constexpr int K8  = KDIM >> 3;
    __shared__ __align__(16) ushort_t smem[128 * SLD];   // 26.6 KB
    const int t    = threadIdx.x;
    const int lane = t & 63;
    const int w    = t >> 6;
    const int wm   = w & 1, wn = w >> 1;
    const int quad = lane >> 4;
    const int l16  = lane & 15;
    const int n0   = rb * 96;

    // cooperative B stage: 96 cols x KDIM, contiguous uint4 copies
    for (int idx = t; idx < 96 * K8; idx += 256) {
        int c = idx / K8, kc = idx - c * K8;
        uint4 v = *(const uint4*)(WbT + (size_t)(n0 + c) * KDIM + kc * 8);
        *(uint4*)(&smem[c * LDB + kc * 8]) = v;
    }

    // direct-global A fragment pointers (row-clamped for OOB M)
    const ushort_t* Arow[4];
    #pragma unroll
    for (int i = 0; i < 4; i++) {
        int row = m0 + wm * 64 + i * 16 + l16;
        row = min(row, M - 1);
        Arow[i] = A + (size_t)row * KDIM + quad * 8;
    }
    __syncthreads();

    f32x4 acc[4][3] = {};
    #pragma unroll
    for (int ks = 0; ks < KDIM; ks += 32) {
        bf16x8 af[4], bfv[3];
        #pragma unroll
        for (int i = 0; i < 4; i++) af[i] = *(const bf16x8*)(Arow[i] + ks);
        #pragma unroll
        for (int j = 0; j < 3; j++)
            bfv[j] = *(const bf16x8*)(&smem[(wn * 48 + j * 16 + l16) * LDB + ks + quad * 8]);
        // swapped operands: lane holds row m = m0+wm*64+i*16+l16,
        // cols n = wn*48+j*16+quad*4+{0..3}
        #pragma unroll
        for (int i = 0; i < 4; i++)
            #pragma unroll
            for (int j = 0; j < 3; j++)
                acc[i][j] = __builtin_amdgcn_mfma_f32_16x16x32_bf16(bfv[j], af[i], acc[i][j], 0, 0, 0);
    }

    // region select (boundaries are multiples of 96)
    int region; const float* biasp;
    if (rb < 6)       { region = 0; biasp = bq; }
    else if (rb < 12) { region = 1; biasp = bk; }
    else if (rb < 18) { region = 2; biasp = bv; }
    else              { region = 3; biasp = bs; }
    const int colbase = (region == 3) ? 0 : (rb - region * 6) * 96;
    // per-lane 4-col bias (scalar loads; cols quad*4..quad*4+3)
    float bb[3][4];
    #pragma unroll
    for (int j = 0; j < 3; j++)
        #pragma unroll
        for (int r = 0; r < 4; r++)
            bb[j][r] = biasp[colbase + wn * 48 + j * 16 + quad * 4 + r];

    __syncthreads();   // done reading B from smem; safe to overwrite

    if (region == 1 || region == 2) {
        // ---- K/V: packed fp8 dword stage + cooperative 16B stores ------
        uchar_t* bstage = (uchar_t*)smem;
        #pragma unroll
        for (int i = 0; i < 4; i++) {
            int row = wm * 64 + i * 16 + l16;
            #pragma unroll
            for (int j = 0; j < 3; j++) {
                unsigned int pk = pk_fp8x4(acc[i][j][0] + bb[j][0],
                                           acc[i][j][1] + bb[j][1],
                                           acc[i][j][2] + bb[j][2],
                                           acc[i][j][3] + bb[j][3]);
                *(unsigned int*)(bstage + row * BSTR + wn * 48 + j * 16 + quad * 4) = pk;
            }
        }
        __syncthreads();
        const int c0 = (rb - 6) * 96;   // 0..1056 spans K|V contiguously
        for (int idx = t; idx < 128 * 6; idx += 256) {
            int r = idx / 6, v4 = idx - r * 6;
            int row = m0 + r;
            if (row < M)
                *(uint4*)(kvf8 + (size_t)row * KVF8LD + c0 + v4 * 16) =
                    *(const uint4*)(bstage + r * BSTR + v4 * 16);
        }
    } else {
        // ---- Q/S: packed bf16 8B stage + cooperative 16B stores --------
        int dstoff = (region == 0) ? n0 : 576;
        #pragma unroll
        for (int i = 0; i < 4; i++) {
            int row = wm * 64 + i * 16 + l16;
            #pragma unroll
            for (int j = 0; j < 3; j++) {
                unsigned int d0 = (unsigned int)f2bf(acc[i][j][0] + bb[j][0])
                                | ((unsigned int)f2bf(acc[i][j][1] + bb[j][1]) << 16);
                unsigned int d1 = (unsigned int)f2bf(acc[i][j][2] + bb[j][2])
                                | ((unsigned int)f2bf(acc[i][j][3] + bb[j][3]) << 16);
                uint2 dd; dd.x = d0; dd.y = d1;
                *(uint2*)(&smem[row * SLD + wn * 48 + j * 16 + quad * 4]) = dd;
            }
        }
        __syncthreads();
        for (int idx = t; idx < 128 * 12; idx += 256) {
            int r = idx / 12, v = idx - r * 12;
            int row = m0 + r;
            if (row < M)
                *(uint4*)(kvqs + (size_t)row * LDROW + dstoff + v * 8) =
                    *(const uint4*)(&smem[r * SLD + v * 8]);
        }
    }
}

// ---------------------------------------------------------------------------
// CSR construction (scan + scatter; degree done in k_prep)
// ---------------------------------------------------------------------------
__global__ __launch_bounds__(1024) void k_scan(const int* __restrict__ deg,
                                               int* __restrict__ row_ptr,
                                               int* __restrict__ cursor)
{
    __shared__ int part[1024];
    int t = threadIdx.x;
    const int chunk = (N_NODES + 1023) / 1024;  // 20
    int b = t * chunk;
    int s = 0;
    for (int i = 0; i < chunk; i++)
        if (b + i < N_NODES) s += deg[b + i];
    part[t] = s;
    __syncthreads();
    for (int o = 1; o < 1024; o <<= 1) {
        int v = (t >= o) ? part[t - o] : 0;
        __syncthreads();
        part[t] += v;
        __syncthreads();
    }
    int run = part[t] - s;
    for (int i = 0; i < chunk; i++) {
        if (b + i < N_NODES) {
            row_ptr[b + i] = run;
            cursor[b + i]  = run;
            run += deg[b + i];
        }
    }
    if (t == 1023) row_ptr[N_NODES] = part[1023];
}

__global__ void k_scatter(const int* __restrict__ esrc, const int* __restrict__ edst,
                          int* __restrict__ cursor, int* __restrict__ csrc)
{
    int e = blockIdx.x * blockDim.x + threadIdx.x;
    if (e < N_EDGES) {
        int pos = atomicAdd(&cursor[edst[e]], 1);
        csrc[pos] = esrc[e];
    }
}

// ---------------------------------------------------------------------------
// Fused per-destination-node attention. fp8 K (pass 1) + fp8 V (pass 2).
// ONE WAVE (64 threads) PER NODE — verified best (R2/R11).
// ---------------------------------------------------------------------------
__global__ __launch_bounds__(64) void node_attn(
    const ushort_t* __restrict__ kvqs, const uchar_t* __restrict__ kvf8,
    const int* __restrict__ row_ptr, const int* __restrict__ csrc,
    ushort_t* __restrict__ hb)
{
    const int n    = blockIdx.x;
    const int lane = threadIdx.x;          // 0..63

    __shared__ float QA[HD];               // Q as f32; reused as 'arr' in epilogue
    __shared__ float wbuf[CHUNK * NH];
    __shared__ int   srcs[CHUNK];
    __shared__ float mh[NH], lh[NH], scl[NH], linv[NH];

    const int beg = row_ptr[n], end = row_ptr[n + 1];
    const ushort_t* qk = kvqs + (size_t)n * LDROW;

    // Q stage: 72 uint4 (8 bf16 each) -> 576 floats. lanes 0..63 + 0..7.
    {
        uint4 v = *(const uint4*)(qk + lane * 8);
        unsigned int uu[4] = {v.x, v.y, v.z, v.w};
        #pragma unroll
        for (int j = 0; j < 4; j++) {
            QA[lane * 8 + 2 * j]     = bflo(uu[j]);
            QA[lane * 8 + 2 * j + 1] = bfhi(uu[j]);
        }
        if (lane < 8) {
            uint4 v2 = *(const uint4*)(qk + (64 + lane) * 8);
            unsigned int uu2[4] = {v2.x, v2.y, v2.z, v2.w};
            #pragma unroll
            for (int j = 0; j < 4; j++) {
                QA[(64 + lane) * 8 + 2 * j]     = bflo(uu2[j]);
                QA[(64 + lane) * 8 + 2 * j + 1] = bfhi(uu2[j]);
            }
        }
    }
    if (lane < NH) { mh[lane] = -1e30f; lh[lane] = 0.f; }

    // pass-1 lane mapping: sub-edge slot + (head, quarter)
    const int sub = lane >> 5;             // 0/1: which of 2 edges per iter
    const int h32 = lane & 31;
    const int g   = h32 >> 2;              // 0..7 (6,7 idle in pass 1)
    const int gg  = (g < 6) ? g : 0;
    const int qr  = h32 & 3;
    // pass-2 lane mapping: 48 lanes own 12 dims each, head-aligned
    const int hh  = lane >> 3;             // 0..7 (6,7 idle in pass 2)
    const int j8  = lane & 7;
    const uchar_t* vb = kvf8 + 576 + ((hh < 6) ? hh : 0) * HIDDEN + j8 * 12;

    float acc[12];
    #pragma unroll
    for (int d = 0; d < 12; d++) acc[d] = 0.f;
    const float qa = 0.10206207261596577f; // 1/sqrt(96)

    __syncthreads();   // Q, m, l ready (single wave: degenerates to waitcnt)

    for (int cb = beg; cb < end; cb += CHUNK) {
        const int c = min(CHUNK, end - cb);
        __syncthreads();
        if (lane < c) srcs[lane] = csrc[cb + lane];
        __syncthreads();

        // ---- pass 1: logits, 2 edges per iteration, fp8 K ---------------
        #pragma unroll 2
        for (int eb = 0; eb < c; eb += 2) {
            int e = eb + sub;
            bool act = (e < c) && (g < 6);
            int src = srcs[(e < c) ? e : 0];
            const uchar_t* kp = kvf8 + (size_t)src * KVF8LD + gg * HIDDEN + qr * 24;
            uint2 a0 = *(const uint2*)(kp);
            uint2 a1 = *(const uint2*)(kp + 8);
            uint2 a2 = *(const uint2*)(kp + 16);
            const float* qb = &QA[gg * HIDDEN + qr * 24];
            unsigned int uu[6] = {a0.x, a0.y, a1.x, a1.y, a2.x, a2.y};
            float p = 0.f;
            #pragma unroll
            for (int k2 = 0; k2 < 6; k2++) {
                f32x2 lo = __builtin_amdgcn_cvt_pk_f32_fp8(uu[k2], false);
                f32x2 hi = __builtin_amdgcn_cvt_pk_f32_fp8(uu[k2], true);
                p += lo[0] * qb[4 * k2]     + lo[1] * qb[4 * k2 + 1]
                   + hi[0] * qb[4 * k2 + 2] + hi[1] * qb[4 * k2 + 3];
            }
            p += __shfl_xor(p, 1, 64);
            p += __shfl_xor(p, 2, 64);
            if (act && qr == 0) wbuf[e * NH + g] = p * qa;
        }
        __syncthreads();

        // ---- softmax: 3 iterations x 2 heads (32 lanes each) ------------
        #pragma unroll
        for (int s = 0; s < 3; s++) {
            int h = 2 * s + sub;
            float logit = (h32 < c) ? wbuf[h32 * NH + h] : -1e30f;
            float cm = logit;
            #pragma unroll
            for (int o = 16; o; o >>= 1) cm = fmaxf(cm, __shfl_xor(cm, o, 32));
            cm = fmaxf(cm, mh[h]);
            float wv = (h32 < c) ? __expf(logit - cm) : 0.f;
            if (h32 < c) wbuf[h32 * NH + h] = wv;
            float lp = wv;
            #pragma unroll
            for (int o = 16; o; o >>= 1) lp += __shfl_xor(lp, o, 32);
            if (h32 == 0) {
                float sc = __expf(mh[h] - cm);
                scl[h] = sc;
                lh[h] = lh[h] * sc + lp;
                mh[h] = cm;
            }
        }
        __syncthreads();

        // ---- pass 2: fp8 V aggregation, 48 lanes x 12 dims --------------
        if (lane < 48) {
            float sc = scl[hh];
            #pragma unroll
            for (int d = 0; d < 12; d++) acc[d] *= sc;
            int e = 0;
            for (; e + 2 <= c; e += 2) {
                int s0 = srcs[e], s1 = srcs[e + 1];
                const uchar_t* p0 = vb + (size_t)s0 * KVF8LD;
                const uchar_t* p1 = vb + (size_t)s1 * KVF8LD;
                unsigned int r0[3], r1[3];
                #pragma unroll
                for (int k = 0; k < 3; k++) {
                    r0[k] = *(const unsigned int*)(p0 + 4 * k);
                    r1[k] = *(const unsigned int*)(p1 + 4 * k);
                }
                float w0 = wbuf[e * NH + hh], w1 = wbuf[(e + 1) * NH + hh];
                #pragma unroll
                for (int k = 0; k < 3; k++) {
                    f32x2 lo0 = __builtin_amdgcn_cvt_pk_f32_fp8(r0[k], false);
                    f32x2 hi0 = __builtin_amdgcn_cvt_pk_f32_fp8(r0[k], true);
                    acc[4 * k]     += w0 * lo0[0];
                    acc[4 * k + 1] += w0 * lo0[1];
                    acc[4 * k + 2] += w0 * hi0[0];
                    acc[4 * k + 3] += w0 * hi0[1];
                    f32x2 lo1 = __builtin_amdgcn_cvt_pk_f32_fp8(r1[k], false);
                    f32x2 hi1 = __builtin_amdgcn_cvt_pk_f32_fp8(r1[k], true);
                    acc[4 * k]     += w1 * lo1[0];
                    acc[4 * k + 1] += w1 * lo1[1];
                    acc[4 * k + 2] += w1 * hi1[0];
                    acc[4 * k + 3] += w1 * hi1[1];
                }
            }
            if (e < c) {
                int s0 = srcs[e];
                const uchar_t* p0 = vb + (size_t)s0 * KVF8LD;
                float w0 = wbuf[e * NH + hh];
                #pragma unroll
                for (int k = 0; k < 3; k++) {
                    unsigned int r = *(const unsigned int*)(p0 + 4 * k);
                    f32x2 lo = __builtin_amdgcn_cvt_pk_f32_fp8(r, false);
                    f32x2 hi = __builtin_amdgcn_cvt_pk_f32_fp8(r, true);
                    acc[4 * k]     += w0 * lo[0];
                    acc[4 * k + 1] += w0 * lo[1];
                    acc[4 * k + 2] += w0 * hi[0];
                    acc[4 * k + 3] += w0 * hi[1];
                }
            }
        }
    }

    if (lane < NH) linv[lane] = (lh[lane] > 0.f) ? 1.0f / lh[lane] : 0.f;
    __syncthreads();
    if (lane < 48) {
        float li = linv[hh];
        #pragma unroll
        for (int d = 0; d < 12; d++)
            QA[hh * HIDDEN + j8 * 12 + d] = acc[d] * li;   // QA reused as 'arr'
    }
    __syncthreads();

    {
        int d = lane;
        float s = (QA[d] + QA[HIDDEN + d] + QA[2 * HIDDEN + d] +
                   QA[3 * HIDDEN + d] + QA[4 * HIDDEN + d] + QA[5 * HIDDEN + d])
                  * (1.0f / 6.0f);
        s += bfs(qk[576 + d]);
        s = fmaxf(s, 0.0f);
        hb[n * HIDDEN + d] = f2bf(s);
        if (lane < 32) {
            int d2 = 64 + lane;
            float s2 = (QA[d2] + QA[HIDDEN + d2] + QA[2 * HIDDEN + d2] +
                        QA[3 * HIDDEN + d2] + QA[4 * HIDDEN + d2] + QA[5 * HIDDEN + d2])
                       * (1.0f / 6.0f);
            s2 += bfs(qk[576 + d2]);
            s2 = fmaxf(s2, 0.0f);
            hb[n * HIDDEN + d2] = f2bf(s2);
        }
    }
}

// ---------------------------------------------------------------------------
// Head with fused mean-pool: block g sums its contiguous node range (bf16 h).
// ---------------------------------------------------------------------------
__global__ __launch_bounds__(128) void k_head(
    const ushort_t* __restrict__ hb, const int* __restrict__ gbound,
    const float* __restrict__ fc1w, const float* __restrict__ fc1b,
    const float* __restrict__ fc2w, const float* __restrict__ fc2b,
    const float* __restrict__ arcw, float* __restrict__ out)
{
    int g = blockIdx.x, t = threadIdx.x;
    __shared__ float v0[HIDDEN], v1[HIDDEN], v2[HIDDEN];
    __shared__ float gnorm;
    const int s0 = gbound[g], s1 = gbound[g + 1];
    float cnt = fmaxf((float)(s1 - s0), 1.0f);
    if (t < HIDDEN) {
        float s = 0.f;
        for (int n = s0; n < s1; n++) s += bfs(hb[(size_t)n * HIDDEN + t]);
        v0[t] = s / cnt;
    }
    __syncthreads();
    if (t < HIDDEN) {
        float s = fc1b[t];
        for (int k = 0; k < HIDDEN; k++) s += v0[k] * fc1w[k * HIDDEN + t];
        v1[t] = fmaxf(s, 0.f);
    }
    __syncthreads();
    if (t < HIDDEN) {
        float s = fc2b[t];
        for (int k = 0; k < HIDDEN; k++) s += v1[k] * fc2w[k * HIDDEN + t];
        v2[t] = fmaxf(s, 0.f);
    }
    __syncthreads();
    if (t == 0) {
        float s = 0.f;
        for (int k = 0; k < HIDDEN; k++) s += v2[k] * v2[k];
        gnorm = sqrtf(s) + 1e-12f;
    }
    __syncthreads();
    if (t < NCLS) {
        float dot = 0.f, wn = 0.f;
        const float* wr = arcw + (size_t)t * HIDDEN;
        for (int k = 0; k < HIDDEN; k++) {
            float w = wr[k];
            dot += w * v2[k];
            wn  += w * w;
        }
        out[g * NCLS + t] = 30.0f * dot / (gnorm * (sqrtf(wn) + 1e-12f));
    }
}

// ---------------------------------------------------------------------------
extern "C" void kernel_launch(void* const* d_in, const int* in_sizes, int n_in,
                              void* d_out, int out_size, void* d_ws, size_t ws_size,
                              hipStream_t stream)
{
    (void)in_sizes; (void)n_in; (void)out_size; (void)ws_size;

    const float* x     = (const float*)d_in[0];
    const int*   ei    = (const int*)d_in[1];
    const int*   batch = (const int*)d_in[2];
    const float* Wq1 = (const float*)d_in[3];  const float* bq1 = (const float*)d_in[4];
    const float* Wk1 = (const float*)d_in[5];  const float* bk1 = (const float*)d_in[6];
    const float* Wv1 = (const float*)d_in[7];  const float* bv1 = (const float*)d_in[8];
    const float* Ws1 = (const float*)d_in[9];  const float* bs1 = (const float*)d_in[10];
    const float* Wq_r = (const float*)d_in[11]; const float* bq_r = (const float*)d_in[12];
    const float* Wk_r = (const float*)d_in[13]; const float* bk_r = (const float*)d_in[14];
    const float* Wv_r = (const float*)d_in[15]; const float* bv_r = (const float*)d_in[16];
    const float* Ws_r = (const float*)d_in[17]; const float* bs_r = (const float*)d_in[18];
    const float* fc1w = (const float*)d_in[19]; const float* fc1b = (const float*)d_in[20];
    const float* fc2w = (const float*)d_in[21]; const float* fc2b = (const float*)d_in[22];
    const float* arcw = (const float*)d_in[23];
    float* out = (float*)d_out;

    const int* esrc = ei;
    const int* edst = ei + N_EDGES;

    char* base = (char*)d_ws;
    size_t off = 0;
    auto alloc = [&](size_t bytes) -> void* {
        off = (off + 255) & ~(size_t)255;
        void* p = base + off;
        off += bytes;
        return p;
    };
    ushort_t* kvqs = (ushort_t*)alloc((size_t)N_NODES * LDROW * 2);  // 28.2 MB
    uchar_t*  kvf8 = (uchar_t*)alloc((size_t)N_NODES * KVF8LD);      // 23.0 MB
    ushort_t* xb  = (ushort_t*)alloc((size_t)N_NODES * DIM_IN * 2);
    ushort_t* hb0 = (ushort_t*)alloc((size_t)N_NODES * HIDDEN * 2);
    ushort_t* hb1 = (ushort_t*)alloc((size_t)N_NODES * HIDDEN * 2);
    ushort_t* Wb0 = (ushort_t*)alloc((size_t)DIM_IN * NALL * 2);
    ushort_t* Wbr = (ushort_t*)alloc((size_t)4 * HIDDEN * NALL * 2);
    int*   deg     = (int*)alloc(N_NODES * 4);
    int*   row_ptr = (int*)alloc((N_NODES + 1) * 4);
    int*   cursor  = (int*)alloc(N_NODES * 4);
    int*   csrc    = (int*)alloc(N_EDGES * 4);
    int*   gbound  = (int*)alloc((NGRAPH + 1) * 4);

    // prep: x cast | degree | graph boundaries (one launch) + weight cast
    hipMemsetAsync(deg, 0, N_NODES * 4, stream);
    k_prep<<<PREP_CVT_BLOCKS + PREP_DEG_BLOCKS + PREP_GB_BLOCKS, 256, 0, stream>>>(
        x, xb, edst, deg, batch, gbound);
    {
        dim3 gw((DIM_IN * NALL + 255) / 256, 5);
        k_cvt_wT_all<<<gw, 256, 0, stream>>>(Wq1, Wk1, Wv1, Ws1,
                                             Wq_r, Wk_r, Wv_r, Ws_r, Wb0, Wbr);
    }
    k_scan<<<1, 1024, 0, stream>>>(deg, row_ptr, cursor);
    k_scatter<<<(N_EDGES + 255) / 256, 256, 0, stream>>>(esrc, edst, cursor, csrc);

    const ushort_t* Ain = xb;
    ushort_t* hbcur = hb0;
    for (int L = 0; L < 5; L++) {
        const ushort_t* Wb = (L == 0) ? Wb0 : (Wbr + (size_t)(L - 1) * HIDDEN * NALL);
        const float *bq, *bk, *bv, *bs;
        if (L == 0) { bq = bq1; bk = bk1; bv = bv1; bs = bs1; }
        else {
            int i = L - 1;
            bq = bq_r + (size_t)i * HD; bk = bk_r + (size_t)i * HD;
            bv = bv_r + (size_t)i * HD; bs = bs_r + (size_t)i * HIDDEN;
        }
        if (L == 0)
            gemm_qkvs_mfma<DIM_IN><<<GEMM_GRID, 256, 0, stream>>>(Ain, N_NODES, Wb,
                                                                  bq, bk, bv, bs, kvqs, kvf8);
        else
            gemm_qkvs_mfma<HIDDEN><<<GEMM_GRID, 256, 0, stream>>>(Ain, N_NODES, Wb,
                                                                  bq, bk, bv, bs, kvqs, kvf8);
        node_attn<<<N_NODES, 64, 0, stream>>>(kvqs, kvf8, row_ptr, csrc, hbcur);
        Ain = hbcur;
        hbcur = (hbcur == hb0) ? hb1 : hb0;
    }

    k_head<<<NGRAPH, 128, 0, stream>>>(hbcur == hb0 ? hb1 : hb0, gbound,
                                       fc1w, fc1b, fc2w, fc2b, arcw, out);
}

// Round 13
// 490.059 us; speedup vs baseline: 1.1448x; 1.0112x over previous
//
#include <hip/hip_runtime.h>
#include <math.h>

#define N_NODES 20000
#define N_EDGES 160000
#define DIM_IN  128
#define HIDDEN  96
#define NH      6
#define HD      576      // NH*HIDDEN
#define LDROW   704      // bf16 row stride: Q(576)|S(96)|pad(32) = 11 lines
#define KVF8LD  1152     // fp8 row stride BYTES: K(576)|V(576) = 9 lines
#define NALL    1824     // concat QKVS weight cols
#define NGRAPH  512
#define NCLS    128
#define CHUNK   32       // edges per softmax chunk
#define SLD     104      // bf16 LDS stage row stride (ushorts)
#define BSTR    112      // fp8 LDS stage row stride (bytes, mult of 16)
#define GEMM_NB   19     // column blocks (1824/96)
#define GEMM_NMT  79     // 256-row tiles (ceil(20000/256))
#define GEMM_LIN  (GEMM_NB * GEMM_NMT)          // 1501
#define GEMM_NCH  ((GEMM_LIN + 7) / 8)          // 188 per XCD chunk
#define GEMM_GRID (GEMM_NCH * 8)                // 1504 (3 pad blocks)

typedef unsigned short ushort_t;
typedef unsigned char uchar_t;
typedef __attribute__((ext_vector_type(8))) short bf16x8;
typedef __attribute__((ext_vector_type(4))) float f32x4;
typedef __attribute__((ext_vector_type(2))) float f32x2;

static __device__ __forceinline__ ushort_t f2bf(float f) {
    unsigned int u = __float_as_uint(f);
    return (ushort_t)((u + 0x7fffu + ((u >> 16) & 1u)) >> 16);  // RNE
}
static __device__ __forceinline__ float bfs(ushort_t u) { return __uint_as_float((unsigned int)u << 16); }
static __device__ __forceinline__ float bflo(unsigned int u) { return __uint_as_float(u << 16); }
static __device__ __forceinline__ float bfhi(unsigned int u) { return __uint_as_float(u & 0xffff0000u); }

// pack 4 f32 -> 4 fp8 bytes in one dword, via two independent cvt_pk calls
static __device__ __forceinline__ unsigned int pk_fp8x4(float a, float b, float c, float d) {
    unsigned int lo = (unsigned int)__builtin_amdgcn_cvt_pk_fp8_f32(a, b, 0, false);
    unsigned int hi = (unsigned int)__builtin_amdgcn_cvt_pk_fp8_f32(c, d, 0, false);
    return (lo & 0xffffu) | (hi << 16);
}

// ---------------------------------------------------------------------------
// Fused prep: x->bf16 cast | edge degree histogram | graph boundaries.
// ---------------------------------------------------------------------------
#define PREP_CVT_BLOCKS 10000   // 20000*128/256
#define PREP_DEG_BLOCKS 625     // 160000/256
#define PREP_GB_BLOCKS  3       // ceil((NGRAPH+1)/256)
__global__ void k_prep(const float* __restrict__ x, ushort_t* __restrict__ xb,
                       const int* __restrict__ edst, int* __restrict__ deg,
                       const int* __restrict__ batch, int* __restrict__ gbound)
{
    int b = blockIdx.x;
    if (b < PREP_CVT_BLOCKS) {
        int i = b * 256 + threadIdx.x;
        if (i < N_NODES * DIM_IN) xb[i] = f2bf(x[i]);
    } else if (b < PREP_CVT_BLOCKS + PREP_DEG_BLOCKS) {
        int e = (b - PREP_CVT_BLOCKS) * 256 + threadIdx.x;
        if (e < N_EDGES) atomicAdd(&deg[edst[e]], 1);
    } else {
        int g = (b - PREP_CVT_BLOCKS - PREP_DEG_BLOCKS) * 256 + threadIdx.x;
        if (g <= NGRAPH) {
            int lo = 0, hi = N_NODES;
            while (lo < hi) {
                int mid = (lo + hi) >> 1;
                if (batch[mid] < g) lo = mid + 1; else hi = mid;
            }
            gbound[g] = lo;
        }
    }
}

// All 5 layers' transposed concat bf16 weights in one launch. grid.y = layer.
__global__ void k_cvt_wT_all(
    const float* __restrict__ Wq1, const float* __restrict__ Wk1,
    const float* __restrict__ Wv1, const float* __restrict__ Ws1,
    const float* __restrict__ Wq_r, const float* __restrict__ Wk_r,
    const float* __restrict__ Wv_r, const float* __restrict__ Ws_r,
    ushort_t* __restrict__ Wb0, ushort_t* __restrict__ Wbr)
{
    const int L = blockIdx.y;
    const int K = (L == 0) ? DIM_IN : HIDDEN;
    int i = blockIdx.x * blockDim.x + threadIdx.x;
    if (i >= K * NALL) return;
    const float *Wq, *Wk, *Wv, *Ws; ushort_t* dst;
    if (L == 0) { Wq = Wq1; Wk = Wk1; Wv = Wv1; Ws = Ws1; dst = Wb0; }
    else {
        int j = L - 1;
        Wq = Wq_r + (size_t)j * HIDDEN * HD; Wk = Wk_r + (size_t)j * HIDDEN * HD;
        Wv = Wv_r + (size_t)j * HIDDEN * HD; Ws = Ws_r + (size_t)j * HIDDEN * HIDDEN;
        dst = Wbr + (size_t)j * HIDDEN * NALL;
    }
    int n = i / K, k = i - n * K;
    float v;
    if (n < 576)       v = Wq[(size_t)k * HD + n];
    else if (n < 1152) v = Wk[(size_t)k * HD + (n - 576)];
    else if (n < 1728) v = Wv[(size_t)k * HD + (n - 1152)];
    else               v = Ws[(size_t)k * HIDDEN + (n - 1728)];
    dst[i] = f2bf(v);
}

// ---------------------------------------------------------------------------
// bf16 MFMA fused QKVS projection. Swapped-operand epilogue (verified R11)
// + XCD-chunked swizzle (verified R12) + 256-ROW TILE: 4 waves each own
// 64 rows x 96 cols (acc[4][6]). Per output element this halves B-stage
// traffic, barrier count, and launch overhead vs the 128-row tile, and
// doubles per-wave MFMA density (72 vs 36).
// ---------------------------------------------------------------------------
template<int KDIM>
__global__ __launch_bounds__(256) void gemm_qkvs_mfma(
    const ushort_t* __restrict__ A, int M,
    const ushort_t* __restrict__ WbT,
    const float* __restrict__ bq, const float* __restrict__ bk,
    const float* __restrict__ bv, const float* __restrict__ bs,
    ushort_t* __restrict__ kvqs, uchar_t* __restrict__ kvf8)
{
    // XCD-chunked swizzle (verified): blocks with equal (blockIdx&7) share
    // an XCD; contiguous lin ranges keep one mtile's rb-blocks on one XCD.
    const int lin = (blockIdx.x & 7) * GEMM_NCH + (blockIdx.x >> 3);
    if (lin >= GEMM_LIN) return;           // uniform per block (pad blocks)
    const int rb = lin % GEMM_NB;          // 0..18 column block
    const int m0 = (lin / GEMM_NB) * 256;  // row tile base (256 rows)

    constexpr int LDB = KDIM + 8;       // padded B stride
    constexpr int K8  = KDIM >> 3;
    __shared__ __align__(16) ushort_t smem[256 * SLD];   // 53.2 KB
    const int t    = threadIdx.x;
    const int lane = t & 63;
    const int wm   = t >> 6;            // wave 0..3 -> 64-row band
    const int quad = lane >> 4;
    const int l16  = lane & 15;
    const int n0   = rb * 96;

    // cooperative B stage: 96 cols x KDIM, contiguous uint4 copies
    for (int idx = t; idx < 96 * K8; idx += 256) {
        int c = idx / K8, kc = idx - c * K8;
        uint4 v = *(const uint4*)(WbT + (size_t)(n0 + c) * KDIM + kc * 8);
        *(uint4*)(&smem[c * LDB + kc * 8]) = v;
    }

    // direct-global A fragment pointers (row-clamped for OOB M)
    const ushort_t* Arow[4];
    #pragma unroll
    for (int i = 0; i < 4; i++) {
        int row = m0 + wm * 64 + i * 16 + l16;
        row = min(row, M - 1);
        Arow[i] = A + (size_t)row * KDIM + quad * 8;
    }
    __syncthreads();

    f32x4 acc[4][6] = {};
    #pragma unroll
    for (int ks = 0; ks < KDIM; ks += 32) {
        bf16x8 af[4], bfv[6];
        #pragma unroll
        for (int i = 0; i < 4; i++) af[i] = *(const bf16x8*)(Arow[i] + ks);
        #pragma unroll
        for (int j = 0; j < 6; j++)
            bfv[j] = *(const bf16x8*)(&smem[(j * 16 + l16) * LDB + ks + quad * 8]);
        // swapped operands: lane holds row m = m0+wm*64+i*16+l16,
        // cols n = j*16+quad*4+{0..3}
        #pragma unroll
        for (int i = 0; i < 4; i++)
            #pragma unroll
            for (int j = 0; j < 6; j++)
                acc[i][j] = __builtin_amdgcn_mfma_f32_16x16x32_bf16(bfv[j], af[i], acc[i][j], 0, 0, 0);
    }

    // region select (boundaries are multiples of 96)
    int region; const float* biasp;
    if (rb < 6)       { region = 0; biasp = bq; }
    else if (rb < 12) { region = 1; biasp = bk; }
    else if (rb < 18) { region = 2; biasp = bv; }
    else              { region = 3; biasp = bs; }
    const int colbase = (region == 3) ? 0 : (rb - region * 6) * 96;
    // per-lane 4-col bias (cols j*16 + quad*4 + r)
    float bb[6][4];
    #pragma unroll
    for (int j = 0; j < 6; j++)
        #pragma unroll
        for (int r = 0; r < 4; r++)
            bb[j][r] = biasp[colbase + j * 16 + quad * 4 + r];

    __syncthreads();   // done reading B from smem; safe to overwrite

    if (region == 1 || region == 2) {
        // ---- K/V: packed fp8 dword stage + cooperative 16B stores ------
        uchar_t* bstage = (uchar_t*)smem;
        #pragma unroll
        for (int i = 0; i < 4; i++) {
            int row = wm * 64 + i * 16 + l16;
            #pragma unroll
            for (int j = 0; j < 6; j++) {
                unsigned int pk = pk_fp8x4(acc[i][j][0] + bb[j][0],
                                           acc[i][j][1] + bb[j][1],
                                           acc[i][j][2] + bb[j][2],
                                           acc[i][j][3] + bb[j][3]);
                *(unsigned int*)(bstage + row * BSTR + j * 16 + quad * 4) = pk;
            }
        }
        __syncthreads();
        const int c0 = (rb - 6) * 96;   // 0..1056 spans K|V contiguously
        for (int idx = t; idx < 256 * 6; idx += 256) {
            int r = idx / 6, v4 = idx - r * 6;
            int row = m0 + r;
            if (row < M)
                *(uint4*)(kvf8 + (size_t)row * KVF8LD + c0 + v4 * 16) =
                    *(const uint4*)(bstage + r * BSTR + v4 * 16);
        }
    } else {
        // ---- Q/S: packed bf16 8B stage + cooperative 16B stores --------
        int dstoff = (region == 0) ? n0 : 576;
        #pragma unroll
        for (int i = 0; i < 4; i++) {
            int row = wm * 64 + i * 16 + l16;
            #pragma unroll
            for (int j = 0; j < 6; j++) {
                unsigned int d0 = (unsigned int)f2bf(acc[i][j][0] + bb[j][0])
                                | ((unsigned int)f2bf(acc[i][j][1] + bb[j][1]) << 16);
                unsigned int d1 = (unsigned int)f2bf(acc[i][j][2] + bb[j][2])
                                | ((unsigned int)f2bf(acc[i][j][3] + bb[j][3]) << 16);
                uint2 dd; dd.x = d0; dd.y = d1;
                *(uint2*)(&smem[row * SLD + j * 16 + quad * 4]) = dd;
            }
        }
        __syncthreads();
        for (int idx = t; idx < 256 * 12; idx += 256) {
            int r = idx / 12, v = idx - r * 12;
            int row = m0 + r;
            if (row < M)
                *(uint4*)(kvqs + (size_t)row * LDROW + dstoff + v * 8) =
                    *(const uint4*)(&smem[r * SLD + v * 8]);
        }
    }
}

// ---------------------------------------------------------------------------
// CSR construction (scan + scatter; degree done in k_prep)
// ---------------------------------------------------------------------------
__global__ __launch_bounds__(1024) void k_scan(const int* __restrict__ deg,
                                               int* __restrict__ row_ptr,
                                               int* __restrict__ cursor)
{
    __shared__ int part[1024];
    int t = threadIdx.x;
    const int chunk = (N_NODES + 1023) / 1024;  // 20
    int b = t * chunk;
    int s = 0;
    for (int i = 0; i < chunk; i++)
        if (b + i < N_NODES) s += deg[b + i];
    part[t] = s;
    __syncthreads();
    for (int o = 1; o < 1024; o <<= 1) {
        int v = (t >= o) ? part[t - o] : 0;
        __syncthreads();
        part[t] += v;
        __syncthreads();
    }
    int run = part[t] - s;
    for (int i = 0; i < chunk; i++) {
        if (b + i < N_NODES) {
            row_ptr[b + i] = run;
            cursor[b + i]  = run;
            run += deg[b + i];
        }
    }
    if (t == 1023) row_ptr[N_NODES] = part[1023];
}

__global__ void k_scatter(const int* __restrict__ esrc, const int* __restrict__ edst,
                          int* __restrict__ cursor, int* __restrict__ csrc)
{
    int e = blockIdx.x * blockDim.x + threadIdx.x;
    if (e < N_EDGES) {
        int pos = atomicAdd(&cursor[edst[e]], 1);
        csrc[pos] = esrc[e];
    }
}

// ---------------------------------------------------------------------------
// Fused per-destination-node attention. fp8 K (pass 1) + fp8 V (pass 2).
// ONE WAVE (64 threads) PER NODE — verified best (R2/R11/R12).
// ---------------------------------------------------------------------------
__global__ __launch_bounds__(64) void node_attn(
    const ushort_t* __restrict__ kvqs, const uchar_t* __restrict__ kvf8,
    const int* __restrict__ row_ptr, const int* __restrict__ csrc,
    ushort_t* __restrict__ hb)
{
    const int n    = blockIdx.x;
    const int lane = threadIdx.x;          // 0..63

    __shared__ float QA[HD];               // Q as f32; reused as 'arr' in epilogue
    __shared__ float wbuf[CHUNK * NH];
    __shared__ int   srcs[CHUNK];
    __shared__ float mh[NH], lh[NH], scl[NH], linv[NH];

    const int beg = row_ptr[n], end = row_ptr[n + 1];
    const ushort_t* qk = kvqs + (size_t)n * LDROW;

    // Q stage: 72 uint4 (8 bf16 each) -> 576 floats. lanes 0..63 + 0..7.
    {
        uint4 v = *(const uint4*)(qk + lane * 8);
        unsigned int uu[4] = {v.x, v.y, v.z, v.w};
        #pragma unroll
        for (int j = 0; j < 4; j++) {
            QA[lane * 8 + 2 * j]     = bflo(uu[j]);
            QA[lane * 8 + 2 * j + 1] = bfhi(uu[j]);
        }
        if (lane < 8) {
            uint4 v2 = *(const uint4*)(qk + (64 + lane) * 8);
            unsigned int uu2[4] = {v2.x, v2.y, v2.z, v2.w};
            #pragma unroll
            for (int j = 0; j < 4; j++) {
                QA[(64 + lane) * 8 + 2 * j]     = bflo(uu2[j]);
                QA[(64 + lane) * 8 + 2 * j + 1] = bfhi(uu2[j]);
            }
        }
    }
    if (lane < NH) { mh[lane] = -1e30f; lh[lane] = 0.f; }

    // pass-1 lane mapping: sub-edge slot + (head, quarter)
    const int sub = lane >> 5;             // 0/1: which of 2 edges per iter
    const int h32 = lane & 31;
    const int g   = h32 >> 2;              // 0..7 (6,7 idle in pass 1)
    const int gg  = (g < 6) ? g : 0;
    const int qr  = h32 & 3;
    // pass-2 lane mapping: 48 lanes own 12 dims each, head-aligned
    const int hh  = lane >> 3;             // 0..7 (6,7 idle in pass 2)
    const int j8  = lane & 7;
    const uchar_t* vb = kvf8 + 576 + ((hh < 6) ? hh : 0) * HIDDEN + j8 * 12;

    float acc[12];
    #pragma unroll
    for (int d = 0; d < 12; d++) acc[d] = 0.f;
    const float qa = 0.10206207261596577f; // 1/sqrt(96)

    __syncthreads();   // Q, m, l ready (single wave: degenerates to waitcnt)

    for (int cb = beg; cb < end; cb += CHUNK) {
        const int c = min(CHUNK, end - cb);
        __syncthreads();
        if (lane < c) srcs[lane] = csrc[cb + lane];
        __syncthreads();

        // ---- pass 1: logits, 2 edges per iteration, fp8 K ---------------
        #pragma unroll 2
        for (int eb = 0; eb < c; eb += 2) {
            int e = eb + sub;
            bool act = (e < c) && (g < 6);
            int src = srcs[(e < c) ? e : 0];
            const uchar_t* kp = kvf8 + (size_t)src * KVF8LD + gg * HIDDEN + qr * 24;
            uint2 a0 = *(const uint2*)(kp);
            uint2 a1 = *(const uint2*)(kp + 8);
            uint2 a2 = *(const uint2*)(kp + 16);
            const float* qb = &QA[gg * HIDDEN + qr * 24];
            unsigned int uu[6] = {a0.x, a0.y, a1.x, a1.y, a2.x, a2.y};
            float p = 0.f;
            #pragma unroll
            for (int k2 = 0; k2 < 6; k2++) {
                f32x2 lo = __builtin_amdgcn_cvt_pk_f32_fp8(uu[k2], false);
                f32x2 hi = __builtin_amdgcn_cvt_pk_f32_fp8(uu[k2], true);
                p += lo[0] * qb[4 * k2]     + lo[1] * qb[4 * k2 + 1]
                   + hi[0] * qb[4 * k2 + 2] + hi[1] * qb[4 * k2 + 3];
            }
            p += __shfl_xor(p, 1, 64);
            p += __shfl_xor(p, 2, 64);
            if (act && qr == 0) wbuf[e * NH + g] = p * qa;
        }
        __syncthreads();

        // ---- softmax: 3 iterations x 2 heads (32 lanes each) ------------
        #pragma unroll
        for (int s = 0; s < 3; s++) {
            int h = 2 * s + sub;
            float logit = (h32 < c) ? wbuf[h32 * NH + h] : -1e30f;
            float cm = logit;
            #pragma unroll
            for (int o = 16; o; o >>= 1) cm = fmaxf(cm, __shfl_xor(cm, o, 32));
            cm = fmaxf(cm, mh[h]);
            float wv = (h32 < c) ? __expf(logit - cm) : 0.f;
            if (h32 < c) wbuf[h32 * NH + h] = wv;
            float lp = wv;
            #pragma unroll
            for (int o = 16; o; o >>= 1) lp += __shfl_xor(lp, o, 32);
            if (h32 == 0) {
                float sc = __expf(mh[h] - cm);
                scl[h] = sc;
                lh[h] = lh[h] * sc + lp;
                mh[h] = cm;
            }
        }
        __syncthreads();

        // ---- pass 2: fp8 V aggregation, 48 lanes x 12 dims --------------
        if (lane < 48) {
            float sc = scl[hh];
            #pragma unroll
            for (int d = 0; d < 12; d++) acc[d] *= sc;
            int e = 0;
            for (; e + 2 <= c; e += 2) {
                int s0 = srcs[e], s1 = srcs[e + 1];
                const uchar_t* p0 = vb + (size_t)s0 * KVF8LD;
                const uchar_t* p1 = vb + (size_t)s1 * KVF8LD;
                unsigned int r0[3], r1[3];
                #pragma unroll
                for (int k = 0; k < 3; k++) {
                    r0[k] = *(const unsigned int*)(p0 + 4 * k);
                    r1[k] = *(const unsigned int*)(p1 + 4 * k);
                }
                float w0 = wbuf[e * NH + hh], w1 = wbuf[(e + 1) * NH + hh];
                #pragma unroll
                for (int k = 0; k < 3; k++) {
                    f32x2 lo0 = __builtin_amdgcn_cvt_pk_f32_fp8(r0[k], false);
                    f32x2 hi0 = __builtin_amdgcn_cvt_pk_f32_fp8(r0[k], true);
                    acc[4 * k]     += w0 * lo0[0];
                    acc[4 * k + 1] += w0 * lo0[1];
                    acc[4 * k + 2] += w0 * hi0[0];
                    acc[4 * k + 3] += w0 * hi0[1];
                    f32x2 lo1 = __builtin_amdgcn_cvt_pk_f32_fp8(r1[k], false);
                    f32x2 hi1 = __builtin_amdgcn_cvt_pk_f32_fp8(r1[k], true);
                    acc[4 * k]     += w1 * lo1[0];
                    acc[4 * k + 1] += w1 * lo1[1];
                    acc[4 * k + 2] += w1 * hi1[0];
                    acc[4 * k + 3] += w1 * hi1[1];
                }
            }
            if (e < c) {
                int s0 = srcs[e];
                const uchar_t* p0 = vb + (size_t)s0 * KVF8LD;
                float w0 = wbuf[e * NH + hh];
                #pragma unroll
                for (int k = 0; k < 3; k++) {
                    unsigned int r = *(const unsigned int*)(p0 + 4 * k);
                    f32x2 lo = __builtin_amdgcn_cvt_pk_f32_fp8(r, false);
                    f32x2 hi = __builtin_amdgcn_cvt_pk_f32_fp8(r, true);
                    acc[4 * k]     += w0 * lo[0];
                    acc[4 * k + 1] += w0 * lo[1];
                    acc[4 * k + 2] += w0 * hi[0];
                    acc[4 * k + 3] += w0 * hi[1];
                }
            }
        }
    }

    if (lane < NH) linv[lane] = (lh[lane] > 0.f) ? 1.0f / lh[lane] : 0.f;
    __syncthreads();
    if (lane < 48) {
        float li = linv[hh];
        #pragma unroll
        for (int d = 0; d < 12; d++)
            QA[hh * HIDDEN + j8 * 12 + d] = acc[d] * li;   // QA reused as 'arr'
    }
    __syncthreads();

    {
        int d = lane;
        float s = (QA[d] + QA[HIDDEN + d] + QA[2 * HIDDEN + d] +
                   QA[3 * HIDDEN + d] + QA[4 * HIDDEN + d] + QA[5 * HIDDEN + d])
                  * (1.0f / 6.0f);
        s += bfs(qk[576 + d]);
        s = fmaxf(s, 0.0f);
        hb[n * HIDDEN + d] = f2bf(s);
        if (lane < 32) {
            int d2 = 64 + lane;
            float s2 = (QA[d2] + QA[HIDDEN + d2] + QA[2 * HIDDEN + d2] +
                        QA[3 * HIDDEN + d2] + QA[4 * HIDDEN + d2] + QA[5 * HIDDEN + d2])
                       * (1.0f / 6.0f);
            s2 += bfs(qk[576 + d2]);
            s2 = fmaxf(s2, 0.0f);
            hb[n * HIDDEN + d2] = f2bf(s2);
        }
    }
}

// ---------------------------------------------------------------------------
// Head with fused mean-pool: block g sums its contiguous node range (bf16 h).
// ---------------------------------------------------------------------------
__global__ __launch_bounds__(128) void k_head(
    const ushort_t* __restrict__ hb, const int* __restrict__ gbound,
    const float* __restrict__ fc1w, const float* __restrict__ fc1b,
    const float* __restrict__ fc2w, const float* __restrict__ fc2b,
    const float* __restrict__ arcw, float* __restrict__ out)
{
    int g = blockIdx.x, t = threadIdx.x;
    __shared__ float v0[HIDDEN], v1[HIDDEN], v2[HIDDEN];
    __shared__ float gnorm;
    const int s0 = gbound[g], s1 = gbound[g + 1];
    float cnt = fmaxf((float)(s1 - s0), 1.0f);
    if (t < HIDDEN) {
        float s = 0.f;
        for (int n = s0; n < s1; n++) s += bfs(hb[(size_t)n * HIDDEN + t]);
        v0[t] = s / cnt;
    }
    __syncthreads();
    if (t < HIDDEN) {
        float s = fc1b[t];
        for (int k = 0; k < HIDDEN; k++) s += v0[k] * fc1w[k * HIDDEN + t];
        v1[t] = fmaxf(s, 0.f);
    }
    __syncthreads();
    if (t < HIDDEN) {
        float s = fc2b[t];
        for (int k = 0; k < HIDDEN; k++) s += v1[k] * fc2w[k * HIDDEN + t];
        v2[t] = fmaxf(s, 0.f);
    }
    __syncthreads();
    if (t == 0) {
        float s = 0.f;
        for (int k = 0; k < HIDDEN; k++) s += v2[k] * v2[k];
        gnorm = sqrtf(s) + 1e-12f;
    }
    __syncthreads();
    if (t < NCLS) {
        float dot = 0.f, wn = 0.f;
        const float* wr = arcw + (size_t)t * HIDDEN;
        for (int k = 0; k < HIDDEN; k++) {
            float w = wr[k];
            dot += w * v2[k];
            wn  += w * w;
        }
        out[g * NCLS + t] = 30.0f * dot / (gnorm * (sqrtf(wn) + 1e-12f));
    }
}

// ---------------------------------------------------------------------------
extern "C" void kernel_launch(void* const* d_in, const int* in_sizes, int n_in,
                              void* d_out, int out_size, void* d_ws, size_t ws_size,
                              hipStream_t stream)
{
    (void)in_sizes; (void)n_in; (void)out_size; (void)ws_size;

    const float* x     = (const float*)d_in[0];
    const int*   ei    = (const int*)d_in[1];
    const int*   batch = (const int*)d_in[2];
    const float* Wq1 = (const float*)d_in[3];  const float* bq1 = (const float*)d_in[4];
    const float* Wk1 = (const float*)d_in[5];  const float* bk1 = (const float*)d_in[6];
    const float* Wv1 = (const float*)d_in[7];  const float* bv1 = (const float*)d_in[8];
    const float* Ws1 = (const float*)d_in[9];  const float* bs1 = (const float*)d_in[10];
    const float* Wq_r = (const float*)d_in[11]; const float* bq_r = (const float*)d_in[12];
    const float* Wk_r = (const float*)d_in[13]; const float* bk_r = (const float*)d_in[14];
    const float* Wv_r = (const float*)d_in[15]; const float* bv_r = (const float*)d_in[16];
    const float* Ws_r = (const float*)d_in[17]; const float* bs_r = (const float*)d_in[18];
    const float* fc1w = (const float*)d_in[19]; const float* fc1b = (const float*)d_in[20];
    const float* fc2w = (const float*)d_in[21]; const float* fc2b = (const float*)d_in[22];
    const float* arcw = (const float*)d_in[23];
    float* out = (float*)d_out;

    const int* esrc = ei;
    const int* edst = ei + N_EDGES;

    char* base = (char*)d_ws;
    size_t off = 0;
    auto alloc = [&](size_t bytes) -> void* {
        off = (off + 255) & ~(size_t)255;
        void* p = base + off;
        off += bytes;
        return p;
    };
    ushort_t* kvqs = (ushort_t*)alloc((size_t)N_NODES * LDROW * 2);  // 28.2 MB
    uchar_t*  kvf8 = (uchar_t*)alloc((size_t)N_NODES * KVF8LD);      // 23.0 MB
    ushort_t* xb  = (ushort_t*)alloc((size_t)N_NODES * DIM_IN * 2);
    ushort_t* hb0 = (ushort_t*)alloc((size_t)N_NODES * HIDDEN * 2);
    ushort_t* hb1 = (ushort_t*)alloc((size_t)N_NODES * HIDDEN * 2);
    ushort_t* Wb0 = (ushort_t*)alloc((size_t)DIM_IN * NALL * 2);
    ushort_t* Wbr = (ushort_t*)alloc((size_t)4 * HIDDEN * NALL * 2);
    int*   deg     = (int*)alloc(N_NODES * 4);
    int*   row_ptr = (int*)alloc((N_NODES + 1) * 4);
    int*   cursor  = (int*)alloc(N_NODES * 4);
    int*   csrc    = (int*)alloc(N_EDGES * 4);
    int*   gbound  = (int*)alloc((NGRAPH + 1) * 4);

    // prep: x cast | degree | graph boundaries (one launch) + weight cast
    hipMemsetAsync(deg, 0, N_NODES * 4, stream);
    k_prep<<<PREP_CVT_BLOCKS + PREP_DEG_BLOCKS + PREP_GB_BLOCKS, 256, 0, stream>>>(
        x, xb, edst, deg, batch, gbound);
    {
        dim3 gw((DIM_IN * NALL + 255) / 256, 5);
        k_cvt_wT_all<<<gw, 256, 0, stream>>>(Wq1, Wk1, Wv1, Ws1,
                                             Wq_r, Wk_r, Wv_r, Ws_r, Wb0, Wbr);
    }
    k_scan<<<1, 1024, 0, stream>>>(deg, row_ptr, cursor);
    k_scatter<<<(N_EDGES + 255) / 256, 256, 0, stream>>>(esrc, edst, cursor, csrc);

    const ushort_t* Ain = xb;
    ushort_t* hbcur = hb0;
    for (int L = 0; L < 5; L++) {
        const ushort_t* Wb = (L == 0) ? Wb0 : (Wbr + (size_t)(L - 1) * HIDDEN * NALL);
        const float *bq, *bk, *bv, *bs;
        if (L == 0) { bq = bq1; bk = bk1; bv = bv1; bs = bs1; }
        else {
            int i = L - 1;
            bq = bq_r + (size_t)i * HD; bk = bk_r + (size_t)i * HD;
            bv = bv_r + (size_t)i * HD; bs = bs_r + (size_t)i * HIDDEN;
        }
        if (L == 0)
            gemm_qkvs_mfma<DIM_IN><<<GEMM_GRID, 256, 0, stream>>>(Ain, N_NODES, Wb,
                                                                  bq, bk, bv, bs, kvqs, kvf8);
        else
            gemm_qkvs_mfma<HIDDEN><<<GEMM_GRID, 256, 0, stream>>>(Ain, N_NODES, Wb,
                                                                  bq, bk, bv, bs, kvqs, kvf8);
        node_attn<<<N_NODES, 64, 0, stream>>>(kvqs, kvf8, row_ptr, csrc, hbcur);
        Ain = hbcur;
        hbcur = (hbcur == hb0) ? hb1 : hb0;
    }

    k_head<<<NGRAPH, 128, 0, stream>>>(hbcur == hb0 ? hb1 : hb0, gbound,
                                       fc1w, fc1b, fc2w, fc2b, arcw, out);
}

// Round 14
// 460.858 us; speedup vs baseline: 1.2173x; 1.0634x over previous
//
#include <hip/hip_runtime.h>
#include <math.h>

#define N_NODES 20000
#define N_EDGES 160000
#define DIM_IN  128
#define HIDDEN  96
#define NH      6
#define HD      576      // NH*HIDDEN
#define LDROW   704      // bf16 row stride: Q(576)|S(96)|pad(32) = 11 lines
#define KVF8LD  1152     // fp8 row stride BYTES: K(576)|V(576) = 9 lines
#define NALL    1824     // concat QKVS weight cols
#define NGRAPH  512
#define NCLS    128
#define CHUNK   32       // edges per softmax chunk
#define SLD     104      // bf16 LDS stage row stride (ushorts)
#define BSTR    112      // fp8 LDS stage row stride (bytes, mult of 16)
#define GEMM_NB   19     // column blocks (1824/96)
#define GEMM_NMT  79     // 256-row tiles (ceil(20000/256))
#define GEMM_LIN  (GEMM_NB * GEMM_NMT)          // 1501
#define GEMM_NCH  ((GEMM_LIN + 7) / 8)          // 188 per XCD chunk
#define GEMM_GRID (GEMM_NCH * 8)                // 1504 (3 pad blocks)
#define SC_BLKS 80       // scan blocks
#define SC_NPB  250      // nodes per scan block (80*250 = 20000 exact)

typedef unsigned short ushort_t;
typedef unsigned char uchar_t;
typedef __attribute__((ext_vector_type(8))) short bf16x8;
typedef __attribute__((ext_vector_type(4))) float f32x4;
typedef __attribute__((ext_vector_type(2))) float f32x2;

static __device__ __forceinline__ ushort_t f2bf(float f) {
    unsigned int u = __float_as_uint(f);
    return (ushort_t)((u + 0x7fffu + ((u >> 16) & 1u)) >> 16);  // RNE
}
static __device__ __forceinline__ float bfs(ushort_t u) { return __uint_as_float((unsigned int)u << 16); }
static __device__ __forceinline__ float bflo(unsigned int u) { return __uint_as_float(u << 16); }
static __device__ __forceinline__ float bfhi(unsigned int u) { return __uint_as_float(u & 0xffff0000u); }

// pack 4 f32 -> 4 fp8 bytes in one dword, via two independent cvt_pk calls
static __device__ __forceinline__ unsigned int pk_fp8x4(float a, float b, float c, float d) {
    unsigned int lo = (unsigned int)__builtin_amdgcn_cvt_pk_fp8_f32(a, b, 0, false);
    unsigned int hi = (unsigned int)__builtin_amdgcn_cvt_pk_fp8_f32(c, d, 0, false);
    return (lo & 0xffffu) | (hi << 16);
}

// ---------------------------------------------------------------------------
// Fused prep: x->bf16 cast | edge degree histogram | graph boundaries.
// ---------------------------------------------------------------------------
#define PREP_CVT_BLOCKS 10000   // 20000*128/256
#define PREP_DEG_BLOCKS 625     // 160000/256
#define PREP_GB_BLOCKS  3       // ceil((NGRAPH+1)/256)
__global__ void k_prep(const float* __restrict__ x, ushort_t* __restrict__ xb,
                       const int* __restrict__ edst, int* __restrict__ deg,
                       const int* __restrict__ batch, int* __restrict__ gbound)
{
    int b = blockIdx.x;
    if (b < PREP_CVT_BLOCKS) {
        int i = b * 256 + threadIdx.x;
        if (i < N_NODES * DIM_IN) xb[i] = f2bf(x[i]);
    } else if (b < PREP_CVT_BLOCKS + PREP_DEG_BLOCKS) {
        int e = (b - PREP_CVT_BLOCKS) * 256 + threadIdx.x;
        if (e < N_EDGES) atomicAdd(&deg[edst[e]], 1);
    } else {
        int g = (b - PREP_CVT_BLOCKS - PREP_DEG_BLOCKS) * 256 + threadIdx.x;
        if (g <= NGRAPH) {
            int lo = 0, hi = N_NODES;
            while (lo < hi) {
                int mid = (lo + hi) >> 1;
                if (batch[mid] < g) lo = mid + 1; else hi = mid;
            }
            gbound[g] = lo;
        }
    }
}

// All 5 layers' transposed concat bf16 weights in one launch. grid.y = layer.
__global__ void k_cvt_wT_all(
    const float* __restrict__ Wq1, const float* __restrict__ Wk1,
    const float* __restrict__ Wv1, const float* __restrict__ Ws1,
    const float* __restrict__ Wq_r, const float* __restrict__ Wk_r,
    const float* __restrict__ Wv_r, const float* __restrict__ Ws_r,
    ushort_t* __restrict__ Wb0, ushort_t* __restrict__ Wbr)
{
    const int L = blockIdx.y;
    const int K = (L == 0) ? DIM_IN : HIDDEN;
    int i = blockIdx.x * blockDim.x + threadIdx.x;
    if (i >= K * NALL) return;
    const float *Wq, *Wk, *Wv, *Ws; ushort_t* dst;
    if (L == 0) { Wq = Wq1; Wk = Wk1; Wv = Wv1; Ws = Ws1; dst = Wb0; }
    else {
        int j = L - 1;
        Wq = Wq_r + (size_t)j * HIDDEN * HD; Wk = Wk_r + (size_t)j * HIDDEN * HD;
        Wv = Wv_r + (size_t)j * HIDDEN * HD; Ws = Ws_r + (size_t)j * HIDDEN * HIDDEN;
        dst = Wbr + (size_t)j * HIDDEN * NALL;
    }
    int n = i / K, k = i - n * K;
    float v;
    if (n < 576)       v = Wq[(size_t)k * HD + n];
    else if (n < 1152) v = Wk[(size_t)k * HD + (n - 576)];
    else if (n < 1728) v = Wv[(size_t)k * HD + (n - 1152)];
    else               v = Ws[(size_t)k * HIDDEN + (n - 1728)];
    dst[i] = f2bf(v);
}

// ---------------------------------------------------------------------------
// bf16 MFMA fused QKVS projection. Swapped-operand epilogue (verified R11)
// + XCD-chunked swizzle (verified R12) + 256-row tile (verified R13).
// ---------------------------------------------------------------------------
template<int KDIM>
__global__ __launch_bounds__(256) void gemm_qkvs_mfma(
    const ushort_t* __restrict__ A, int M,
    const ushort_t* __restrict__ WbT,
    const float* __restrict__ bq, const float* __restrict__ bk,
    const float* __restrict__ bv, const float* __restrict__ bs,
    ushort_t* __restrict__ kvqs, uchar_t* __restrict__ kvf8)
{
    // XCD-chunked swizzle (verified): blocks with equal (blockIdx&7) share
    // an XCD; contiguous lin ranges keep one mtile's rb-blocks on one XCD.
    const int lin = (blockIdx.x & 7) * GEMM_NCH + (blockIdx.x >> 3);
    if (lin >= GEMM_LIN) return;           // uniform per block (pad blocks)
    const int rb = lin % GEMM_NB;          // 0..18 column block
    const int m0 = (lin / GEMM_NB) * 256;  // row tile base (256 rows)

    constexpr int LDB = KDIM + 8;       // padded B stride
    constexpr int K8  = KDIM >> 3;
    __shared__ __align__(16) ushort_t smem[256 * SLD];   // 53.2 KB
    const int t    = threadIdx.x;
    const int lane = t & 63;
    const int wm   = t >> 6;            // wave 0..3 -> 64-row band
    const int quad = lane >> 4;
    const int l16  = lane & 15;
    const int n0   = rb * 96;

    // cooperative B stage: 96 cols x KDIM, contiguous uint4 copies
    for (int idx = t; idx < 96 * K8; idx += 256) {
        int c = idx / K8, kc = idx - c * K8;
        uint4 v = *(const uint4*)(WbT + (size_t)(n0 + c) * KDIM + kc * 8);
        *(uint4*)(&smem[c * LDB + kc * 8]) = v;
    }

    // direct-global A fragment pointers (row-clamped for OOB M)
    const ushort_t* Arow[4];
    #pragma unroll
    for (int i = 0; i < 4; i++) {
        int row = m0 + wm * 64 + i * 16 + l16;
        row = min(row, M - 1);
        Arow[i] = A + (size_t)row * KDIM + quad * 8;
    }
    __syncthreads();

    f32x4 acc[4][6] = {};
    #pragma unroll
    for (int ks = 0; ks < KDIM; ks += 32) {
        bf16x8 af[4], bfv[6];
        #pragma unroll
        for (int i = 0; i < 4; i++) af[i] = *(const bf16x8*)(Arow[i] + ks);
        #pragma unroll
        for (int j = 0; j < 6; j++)
            bfv[j] = *(const bf16x8*)(&smem[(j * 16 + l16) * LDB + ks + quad * 8]);
        // swapped operands: lane holds row m = m0+wm*64+i*16+l16,
        // cols n = j*16+quad*4+{0..3}
        #pragma unroll
        for (int i = 0; i < 4; i++)
            #pragma unroll
            for (int j = 0; j < 6; j++)
                acc[i][j] = __builtin_amdgcn_mfma_f32_16x16x32_bf16(bfv[j], af[i], acc[i][j], 0, 0, 0);
    }

    // region select (boundaries are multiples of 96)
    int region; const float* biasp;
    if (rb < 6)       { region = 0; biasp = bq; }
    else if (rb < 12) { region = 1; biasp = bk; }
    else if (rb < 18) { region = 2; biasp = bv; }
    else              { region = 3; biasp = bs; }
    const int colbase = (region == 3) ? 0 : (rb - region * 6) * 96;
    // per-lane 4-col bias (cols j*16 + quad*4 + r)
    float bb[6][4];
    #pragma unroll
    for (int j = 0; j < 6; j++)
        #pragma unroll
        for (int r = 0; r < 4; r++)
            bb[j][r] = biasp[colbase + j * 16 + quad * 4 + r];

    __syncthreads();   // done reading B from smem; safe to overwrite

    if (region == 1 || region == 2) {
        // ---- K/V: packed fp8 dword stage + cooperative 16B stores ------
        uchar_t* bstage = (uchar_t*)smem;
        #pragma unroll
        for (int i = 0; i < 4; i++) {
            int row = wm * 64 + i * 16 + l16;
            #pragma unroll
            for (int j = 0; j < 6; j++) {
                unsigned int pk = pk_fp8x4(acc[i][j][0] + bb[j][0],
                                           acc[i][j][1] + bb[j][1],
                                           acc[i][j][2] + bb[j][2],
                                           acc[i][j][3] + bb[j][3]);
                *(unsigned int*)(bstage + row * BSTR + j * 16 + quad * 4) = pk;
            }
        }
        __syncthreads();
        const int c0 = (rb - 6) * 96;   // 0..1056 spans K|V contiguously
        for (int idx = t; idx < 256 * 6; idx += 256) {
            int r = idx / 6, v4 = idx - r * 6;
            int row = m0 + r;
            if (row < M)
                *(uint4*)(kvf8 + (size_t)row * KVF8LD + c0 + v4 * 16) =
                    *(const uint4*)(bstage + r * BSTR + v4 * 16);
        }
    } else {
        // ---- Q/S: packed bf16 8B stage + cooperative 16B stores --------
        int dstoff = (region == 0) ? n0 : 576;
        #pragma unroll
        for (int i = 0; i < 4; i++) {
            int row = wm * 64 + i * 16 + l16;
            #pragma unroll
            for (int j = 0; j < 6; j++) {
                unsigned int d0 = (unsigned int)f2bf(acc[i][j][0] + bb[j][0])
                                | ((unsigned int)f2bf(acc[i][j][1] + bb[j][1]) << 16);
                unsigned int d1 = (unsigned int)f2bf(acc[i][j][2] + bb[j][2])
                                | ((unsigned int)f2bf(acc[i][j][3] + bb[j][3]) << 16);
                uint2 dd; dd.x = d0; dd.y = d1;
                *(uint2*)(&smem[row * SLD + j * 16 + quad * 4]) = dd;
            }
        }
        __syncthreads();
        for (int idx = t; idx < 256 * 12; idx += 256) {
            int r = idx / 12, v = idx - r * 12;
            int row = m0 + r;
            if (row < M)
                *(uint4*)(kvqs + (size_t)row * LDROW + dstoff + v * 8) =
                    *(const uint4*)(&smem[r * SLD + v * 8]);
        }
    }
}

// ---------------------------------------------------------------------------
// CSR construction — MULTI-BLOCK 3-phase scan (replaces the single-block
// k_scan that serialized ~240KB of traffic on one CU) + scatter.
// ---------------------------------------------------------------------------
__global__ __launch_bounds__(256) void k_scan_part(const int* __restrict__ deg,
                                                   int* __restrict__ bsum)
{
    __shared__ int red[256];
    int b = blockIdx.x, t = threadIdx.x;
    int v = (t < SC_NPB) ? deg[b * SC_NPB + t] : 0;
    red[t] = v;
    __syncthreads();
    for (int o = 128; o; o >>= 1) {
        if (t < o) red[t] += red[t + o];
        __syncthreads();
    }
    if (t == 0) bsum[b] = red[0];
}

__global__ __launch_bounds__(128) void k_scan_top(const int* __restrict__ bsum,
                                                  int* __restrict__ boff,
                                                  int* __restrict__ row_ptr)
{
    __shared__ int part[128];
    int t = threadIdx.x;
    int v = (t < SC_BLKS) ? bsum[t] : 0;
    part[t] = v;
    __syncthreads();
    for (int o = 1; o < 128; o <<= 1) {
        int x = (t >= o) ? part[t - o] : 0;
        __syncthreads();
        part[t] += x;
        __syncthreads();
    }
    if (t < SC_BLKS) boff[t] = part[t] - v;   // exclusive
    if (t == SC_BLKS - 1) row_ptr[N_NODES] = part[t];
}

__global__ __launch_bounds__(256) void k_scan_down(const int* __restrict__ deg,
                                                   const int* __restrict__ boff,
                                                   int* __restrict__ row_ptr,
                                                   int* __restrict__ cursor)
{
    __shared__ int part[256];
    int b = blockIdx.x, t = threadIdx.x;
    int idx = b * SC_NPB + t;
    int v = (t < SC_NPB) ? deg[idx] : 0;
    part[t] = v;
    __syncthreads();
    for (int o = 1; o < 256; o <<= 1) {
        int x = (t >= o) ? part[t - o] : 0;
        __syncthreads();
        part[t] += x;
        __syncthreads();
    }
    if (t < SC_NPB) {
        int r = boff[b] + part[t] - v;   // exclusive within block + offset
        row_ptr[idx] = r;
        cursor[idx]  = r;
    }
}

__global__ void k_scatter(const int* __restrict__ esrc, const int* __restrict__ edst,
                          int* __restrict__ cursor, int* __restrict__ csrc)
{
    int e = blockIdx.x * blockDim.x + threadIdx.x;
    if (e < N_EDGES) {
        int pos = atomicAdd(&cursor[edst[e]], 1);
        csrc[pos] = esrc[e];
    }
}

// ---------------------------------------------------------------------------
// Fused per-destination-node attention. fp8 K (pass 1) + fp8 V (pass 2).
// ONE WAVE (64 threads) PER NODE — verified best (R2/R11/R12/R13).
// ---------------------------------------------------------------------------
__global__ __launch_bounds__(64) void node_attn(
    const ushort_t* __restrict__ kvqs, const uchar_t* __restrict__ kvf8,
    const int* __restrict__ row_ptr, const int* __restrict__ csrc,
    ushort_t* __restrict__ hb)
{
    const int n    = blockIdx.x;
    const int lane = threadIdx.x;          // 0..63

    __shared__ float QA[HD];               // Q as f32; reused as 'arr' in epilogue
    __shared__ float wbuf[CHUNK * NH];
    __shared__ int   srcs[CHUNK];
    __shared__ float mh[NH], lh[NH], scl[NH], linv[NH];

    const int beg = row_ptr[n], end = row_ptr[n + 1];
    const ushort_t* qk = kvqs + (size_t)n * LDROW;

    // Q stage: 72 uint4 (8 bf16 each) -> 576 floats. lanes 0..63 + 0..7.
    {
        uint4 v = *(const uint4*)(qk + lane * 8);
        unsigned int uu[4] = {v.x, v.y, v.z, v.w};
        #pragma unroll
        for (int j = 0; j < 4; j++) {
            QA[lane * 8 + 2 * j]     = bflo(uu[j]);
            QA[lane * 8 + 2 * j + 1] = bfhi(uu[j]);
        }
        if (lane < 8) {
            uint4 v2 = *(const uint4*)(qk + (64 + lane) * 8);
            unsigned int uu2[4] = {v2.x, v2.y, v2.z, v2.w};
            #pragma unroll
            for (int j = 0; j < 4; j++) {
                QA[(64 + lane) * 8 + 2 * j]     = bflo(uu2[j]);
                QA[(64 + lane) * 8 + 2 * j + 1] = bfhi(uu2[j]);
            }
        }
    }
    if (lane < NH) { mh[lane] = -1e30f; lh[lane] = 0.f; }

    // pass-1 lane mapping: sub-edge slot + (head, quarter)
    const int sub = lane >> 5;             // 0/1: which of 2 edges per iter
    const int h32 = lane & 31;
    const int g   = h32 >> 2;              // 0..7 (6,7 idle in pass 1)
    const int gg  = (g < 6) ? g : 0;
    const int qr  = h32 & 3;
    // pass-2 lane mapping: 48 lanes own 12 dims each, head-aligned
    const int hh  = lane >> 3;             // 0..7 (6,7 idle in pass 2)
    const int j8  = lane & 7;
    const uchar_t* vb = kvf8 + 576 + ((hh < 6) ? hh : 0) * HIDDEN + j8 * 12;

    float acc[12];
    #pragma unroll
    for (int d = 0; d < 12; d++) acc[d] = 0.f;
    const float qa = 0.10206207261596577f; // 1/sqrt(96)

    __syncthreads();   // Q, m, l ready (single wave: degenerates to waitcnt)

    for (int cb = beg; cb < end; cb += CHUNK) {
        const int c = min(CHUNK, end - cb);
        __syncthreads();
        if (lane < c) srcs[lane] = csrc[cb + lane];
        __syncthreads();

        // ---- pass 1: logits, 2 edges per iteration, fp8 K ---------------
        #pragma unroll 2
        for (int eb = 0; eb < c; eb += 2) {
            int e = eb + sub;
            bool act = (e < c) && (g < 6);
            int src = srcs[(e < c) ? e : 0];
            const uchar_t* kp = kvf8 + (size_t)src * KVF8LD + gg * HIDDEN + qr * 24;
            uint2 a0 = *(const uint2*)(kp);
            uint2 a1 = *(const uint2*)(kp + 8);
            uint2 a2 = *(const uint2*)(kp + 16);
            const float* qb = &QA[gg * HIDDEN + qr * 24];
            unsigned int uu[6] = {a0.x, a0.y, a1.x, a1.y, a2.x, a2.y};
            float p = 0.f;
            #pragma unroll
            for (int k2 = 0; k2 < 6; k2++) {
                f32x2 lo = __builtin_amdgcn_cvt_pk_f32_fp8(uu[k2], false);
                f32x2 hi = __builtin_amdgcn_cvt_pk_f32_fp8(uu[k2], true);
                p += lo[0] * qb[4 * k2]     + lo[1] * qb[4 * k2 + 1]
                   + hi[0] * qb[4 * k2 + 2] + hi[1] * qb[4 * k2 + 3];
            }
            p += __shfl_xor(p, 1, 64);
            p += __shfl_xor(p, 2, 64);
            if (act && qr == 0) wbuf[e * NH + g] = p * qa;
        }
        __syncthreads();

        // ---- softmax: 3 iterations x 2 heads (32 lanes each) ------------
        #pragma unroll
        for (int s = 0; s < 3; s++) {
            int h = 2 * s + sub;
            float logit = (h32 < c) ? wbuf[h32 * NH + h] : -1e30f;
            float cm = logit;
            #pragma unroll
            for (int o = 16; o; o >>= 1) cm = fmaxf(cm, __shfl_xor(cm, o, 32));
            cm = fmaxf(cm, mh[h]);
            float wv = (h32 < c) ? __expf(logit - cm) : 0.f;
            if (h32 < c) wbuf[h32 * NH + h] = wv;
            float lp = wv;
            #pragma unroll
            for (int o = 16; o; o >>= 1) lp += __shfl_xor(lp, o, 32);
            if (h32 == 0) {
                float sc = __expf(mh[h] - cm);
                scl[h] = sc;
                lh[h] = lh[h] * sc + lp;
                mh[h] = cm;
            }
        }
        __syncthreads();

        // ---- pass 2: fp8 V aggregation, 48 lanes x 12 dims --------------
        if (lane < 48) {
            float sc = scl[hh];
            #pragma unroll
            for (int d = 0; d < 12; d++) acc[d] *= sc;
            int e = 0;
            for (; e + 2 <= c; e += 2) {
                int s0 = srcs[e], s1 = srcs[e + 1];
                const uchar_t* p0 = vb + (size_t)s0 * KVF8LD;
                const uchar_t* p1 = vb + (size_t)s1 * KVF8LD;
                unsigned int r0[3], r1[3];
                #pragma unroll
                for (int k = 0; k < 3; k++) {
                    r0[k] = *(const unsigned int*)(p0 + 4 * k);
                    r1[k] = *(const unsigned int*)(p1 + 4 * k);
                }
                float w0 = wbuf[e * NH + hh], w1 = wbuf[(e + 1) * NH + hh];
                #pragma unroll
                for (int k = 0; k < 3; k++) {
                    f32x2 lo0 = __builtin_amdgcn_cvt_pk_f32_fp8(r0[k], false);
                    f32x2 hi0 = __builtin_amdgcn_cvt_pk_f32_fp8(r0[k], true);
                    acc[4 * k]     += w0 * lo0[0];
                    acc[4 * k + 1] += w0 * lo0[1];
                    acc[4 * k + 2] += w0 * hi0[0];
                    acc[4 * k + 3] += w0 * hi0[1];
                    f32x2 lo1 = __builtin_amdgcn_cvt_pk_f32_fp8(r1[k], false);
                    f32x2 hi1 = __builtin_amdgcn_cvt_pk_f32_fp8(r1[k], true);
                    acc[4 * k]     += w1 * lo1[0];
                    acc[4 * k + 1] += w1 * lo1[1];
                    acc[4 * k + 2] += w1 * hi1[0];
                    acc[4 * k + 3] += w1 * hi1[1];
                }
            }
            if (e < c) {
                int s0 = srcs[e];
                const uchar_t* p0 = vb + (size_t)s0 * KVF8LD;
                float w0 = wbuf[e * NH + hh];
                #pragma unroll
                for (int k = 0; k < 3; k++) {
                    unsigned int r = *(const unsigned int*)(p0 + 4 * k);
                    f32x2 lo = __builtin_amdgcn_cvt_pk_f32_fp8(r, false);
                    f32x2 hi = __builtin_amdgcn_cvt_pk_f32_fp8(r, true);
                    acc[4 * k]     += w0 * lo[0];
                    acc[4 * k + 1] += w0 * lo[1];
                    acc[4 * k + 2] += w0 * hi[0];
                    acc[4 * k + 3] += w0 * hi[1];
                }
            }
        }
    }

    if (lane < NH) linv[lane] = (lh[lane] > 0.f) ? 1.0f / lh[lane] : 0.f;
    __syncthreads();
    if (lane < 48) {
        float li = linv[hh];
        #pragma unroll
        for (int d = 0; d < 12; d++)
            QA[hh * HIDDEN + j8 * 12 + d] = acc[d] * li;   // QA reused as 'arr'
    }
    __syncthreads();

    {
        int d = lane;
        float s = (QA[d] + QA[HIDDEN + d] + QA[2 * HIDDEN + d] +
                   QA[3 * HIDDEN + d] + QA[4 * HIDDEN + d] + QA[5 * HIDDEN + d])
                  * (1.0f / 6.0f);
        s += bfs(qk[576 + d]);
        s = fmaxf(s, 0.0f);
        hb[n * HIDDEN + d] = f2bf(s);
        if (lane < 32) {
            int d2 = 64 + lane;
            float s2 = (QA[d2] + QA[HIDDEN + d2] + QA[2 * HIDDEN + d2] +
                        QA[3 * HIDDEN + d2] + QA[4 * HIDDEN + d2] + QA[5 * HIDDEN + d2])
                       * (1.0f / 6.0f);
            s2 += bfs(qk[576 + d2]);
            s2 = fmaxf(s2, 0.0f);
            hb[n * HIDDEN + d2] = f2bf(s2);
        }
    }
}

// ---------------------------------------------------------------------------
// Head with fused mean-pool: block g sums its contiguous node range (bf16 h).
// ---------------------------------------------------------------------------
__global__ __launch_bounds__(128) void k_head(
    const ushort_t* __restrict__ hb, const int* __restrict__ gbound,
    const float* __restrict__ fc1w, const float* __restrict__ fc1b,
    const float* __restrict__ fc2w, const float* __restrict__ fc2b,
    const float* __restrict__ arcw, float* __restrict__ out)
{
    int g = blockIdx.x, t = threadIdx.x;
    __shared__ float v0[HIDDEN], v1[HIDDEN], v2[HIDDEN];
    __shared__ float gnorm;
    const int s0 = gbound[g], s1 = gbound[g + 1];
    float cnt = fmaxf((float)(s1 - s0), 1.0f);
    if (t < HIDDEN) {
        float s = 0.f;
        for (int n = s0; n < s1; n++) s += bfs(hb[(size_t)n * HIDDEN + t]);
        v0[t] = s / cnt;
    }
    __syncthreads();
    if (t < HIDDEN) {
        float s = fc1b[t];
        for (int k = 0; k < HIDDEN; k++) s += v0[k] * fc1w[k * HIDDEN + t];
        v1[t] = fmaxf(s, 0.f);
    }
    __syncthreads();
    if (t < HIDDEN) {
        float s = fc2b[t];
        for (int k = 0; k < HIDDEN; k++) s += v1[k] * fc2w[k * HIDDEN + t];
        v2[t] = fmaxf(s, 0.f);
    }
    __syncthreads();
    if (t == 0) {
        float s = 0.f;
        for (int k = 0; k < HIDDEN; k++) s += v2[k] * v2[k];
        gnorm = sqrtf(s) + 1e-12f;
    }
    __syncthreads();
    if (t < NCLS) {
        float dot = 0.f, wn = 0.f;
        const float* wr = arcw + (size_t)t * HIDDEN;
        for (int k = 0; k < HIDDEN; k++) {
            float w = wr[k];
            dot += w * v2[k];
            wn  += w * w;
        }
        out[g * NCLS + t] = 30.0f * dot / (gnorm * (sqrtf(wn) + 1e-12f));
    }
}

// ---------------------------------------------------------------------------
extern "C" void kernel_launch(void* const* d_in, const int* in_sizes, int n_in,
                              void* d_out, int out_size, void* d_ws, size_t ws_size,
                              hipStream_t stream)
{
    (void)in_sizes; (void)n_in; (void)out_size; (void)ws_size;

    const float* x     = (const float*)d_in[0];
    const int*   ei    = (const int*)d_in[1];
    const int*   batch = (const int*)d_in[2];
    const float* Wq1 = (const float*)d_in[3];  const float* bq1 = (const float*)d_in[4];
    const float* Wk1 = (const float*)d_in[5];  const float* bk1 = (const float*)d_in[6];
    const float* Wv1 = (const float*)d_in[7];  const float* bv1 = (const float*)d_in[8];
    const float* Ws1 = (const float*)d_in[9];  const float* bs1 = (const float*)d_in[10];
    const float* Wq_r = (const float*)d_in[11]; const float* bq_r = (const float*)d_in[12];
    const float* Wk_r = (const float*)d_in[13]; const float* bk_r = (const float*)d_in[14];
    const float* Wv_r = (const float*)d_in[15]; const float* bv_r = (const float*)d_in[16];
    const float* Ws_r = (const float*)d_in[17]; const float* bs_r = (const float*)d_in[18];
    const float* fc1w = (const float*)d_in[19]; const float* fc1b = (const float*)d_in[20];
    const float* fc2w = (const float*)d_in[21]; const float* fc2b = (const float*)d_in[22];
    const float* arcw = (const float*)d_in[23];
    float* out = (float*)d_out;

    const int* esrc = ei;
    const int* edst = ei + N_EDGES;

    char* base = (char*)d_ws;
    size_t off = 0;
    auto alloc = [&](size_t bytes) -> void* {
        off = (off + 255) & ~(size_t)255;
        void* p = base + off;
        off += bytes;
        return p;
    };
    ushort_t* kvqs = (ushort_t*)alloc((size_t)N_NODES * LDROW * 2);  // 28.2 MB
    uchar_t*  kvf8 = (uchar_t*)alloc((size_t)N_NODES * KVF8LD);      // 23.0 MB
    ushort_t* xb  = (ushort_t*)alloc((size_t)N_NODES * DIM_IN * 2);
    ushort_t* hb0 = (ushort_t*)alloc((size_t)N_NODES * HIDDEN * 2);
    ushort_t* hb1 = (ushort_t*)alloc((size_t)N_NODES * HIDDEN * 2);
    ushort_t* Wb0 = (ushort_t*)alloc((size_t)DIM_IN * NALL * 2);
    ushort_t* Wbr = (ushort_t*)alloc((size_t)4 * HIDDEN * NALL * 2);
    int*   deg     = (int*)alloc(N_NODES * 4);
    int*   row_ptr = (int*)alloc((N_NODES + 1) * 4);
    int*   cursor  = (int*)alloc(N_NODES * 4);
    int*   csrc    = (int*)alloc(N_EDGES * 4);
    int*   gbound  = (int*)alloc((NGRAPH + 1) * 4);
    int*   bsum    = (int*)alloc(SC_BLKS * 4);
    int*   boff    = (int*)alloc(SC_BLKS * 4);

    // prep: x cast | degree | graph boundaries (one launch) + weight cast
    hipMemsetAsync(deg, 0, N_NODES * 4, stream);
    k_prep<<<PREP_CVT_BLOCKS + PREP_DEG_BLOCKS + PREP_GB_BLOCKS, 256, 0, stream>>>(
        x, xb, edst, deg, batch, gbound);
    {
        dim3 gw((DIM_IN * NALL + 255) / 256, 5);
        k_cvt_wT_all<<<gw, 256, 0, stream>>>(Wq1, Wk1, Wv1, Ws1,
                                             Wq_r, Wk_r, Wv_r, Ws_r, Wb0, Wbr);
    }
    k_scan_part<<<SC_BLKS, 256, 0, stream>>>(deg, bsum);
    k_scan_top<<<1, 128, 0, stream>>>(bsum, boff, row_ptr);
    k_scan_down<<<SC_BLKS, 256, 0, stream>>>(deg, boff, row_ptr, cursor);
    k_scatter<<<(N_EDGES + 255) / 256, 256, 0, stream>>>(esrc, edst, cursor, csrc);

    const ushort_t* Ain = xb;
    ushort_t* hbcur = hb0;
    for (int L = 0; L < 5; L++) {
        const ushort_t* Wb = (L == 0) ? Wb0 : (Wbr + (size_t)(L - 1) * HIDDEN * NALL);
        const float *bq, *bk, *bv, *bs;
        if (L == 0) { bq = bq1; bk = bk1; bv = bv1; bs = bs1; }
        else {
            int i = L - 1;
            bq = bq_r + (size_t)i * HD; bk = bk_r + (size_t)i * HD;
            bv = bv_r + (size_t)i * HD; bs = bs_r + (size_t)i * HIDDEN;
        }
        if (L == 0)
            gemm_qkvs_mfma<DIM_IN><<<GEMM_GRID, 256, 0, stream>>>(Ain, N_NODES, Wb,
                                                                  bq, bk, bv, bs, kvqs, kvf8);
        else
            gemm_qkvs_mfma<HIDDEN><<<GEMM_GRID, 256, 0, stream>>>(Ain, N_NODES, Wb,
                                                                  bq, bk, bv, bs, kvqs, kvf8);
        node_attn<<<N_NODES, 64, 0, stream>>>(kvqs, kvf8, row_ptr, csrc, hbcur);
        Ain = hbcur;
        hbcur = (hbcur == hb0) ? hb1 : hb0;
    }

    k_head<<<NGRAPH, 128, 0, stream>>>(hbcur == hb0 ? hb1 : hb0, gbound,
                                       fc1w, fc1b, fc2w, fc2b, arcw, out);
}

// Round 15
// 449.741 us; speedup vs baseline: 1.2474x; 1.0247x over previous
//
#include <hip/hip_runtime.h>
#include <math.h>

#define N_NODES 20000
#define N_EDGES 160000
#define DIM_IN  128
#define HIDDEN  96
#define NH      6
#define HD      576      // NH*HIDDEN
#define LDROW   704      // bf16 row stride: Q(576)|S(96)|pad(32) = 11 lines
#define KVF8LD  1152     // fp8 row stride BYTES: K(576)|V(576) = 9 lines
#define NALL    1824     // concat QKVS weight cols
#define NGRAPH  512
#define NCLS    128
#define CHUNK   32       // edges per softmax chunk
#define SLD     104      // bf16 LDS stage row stride (ushorts)
#define BSTR    112      // fp8 LDS stage row stride (bytes, mult of 16)
#define GEMM_NB   19     // column blocks (1824/96)
#define GEMM_NMT  79     // 256-row tiles (ceil(20000/256))
#define GEMM_LIN  (GEMM_NB * GEMM_NMT)          // 1501
#define GEMM_NCH  ((GEMM_LIN + 7) / 8)          // 188 per XCD chunk
#define GEMM_GRID (GEMM_NCH * 8)                // 1504 (3 pad blocks)
#define SC_BLKS 80       // scan blocks
#define SC_NPB  250      // nodes per scan block (80*250 = 20000 exact)

typedef unsigned short ushort_t;
typedef unsigned char uchar_t;
typedef __attribute__((ext_vector_type(8))) short bf16x8;
typedef __attribute__((ext_vector_type(4))) float f32x4;
typedef __attribute__((ext_vector_type(2))) float f32x2;

static __device__ __forceinline__ ushort_t f2bf(float f) {
    unsigned int u = __float_as_uint(f);
    return (ushort_t)((u + 0x7fffu + ((u >> 16) & 1u)) >> 16);  // RNE
}
static __device__ __forceinline__ float bfs(ushort_t u) { return __uint_as_float((unsigned int)u << 16); }
static __device__ __forceinline__ float bflo(unsigned int u) { return __uint_as_float(u << 16); }
static __device__ __forceinline__ float bfhi(unsigned int u) { return __uint_as_float(u & 0xffff0000u); }

// pack 4 f32 -> 4 fp8 bytes in one dword, via two independent cvt_pk calls
static __device__ __forceinline__ unsigned int pk_fp8x4(float a, float b, float c, float d) {
    unsigned int lo = (unsigned int)__builtin_amdgcn_cvt_pk_fp8_f32(a, b, 0, false);
    unsigned int hi = (unsigned int)__builtin_amdgcn_cvt_pk_fp8_f32(c, d, 0, false);
    return (lo & 0xffffu) | (hi << 16);
}

// ---------------------------------------------------------------------------
// Fused prep: x->bf16 cast | edge degree histogram | graph boundaries.
// ---------------------------------------------------------------------------
#define PREP_CVT_BLOCKS 10000   // 20000*128/256
#define PREP_DEG_BLOCKS 625     // 160000/256
#define PREP_GB_BLOCKS  3       // ceil((NGRAPH+1)/256)
__global__ void k_prep(const float* __restrict__ x, ushort_t* __restrict__ xb,
                       const int* __restrict__ edst, int* __restrict__ deg,
                       const int* __restrict__ batch, int* __restrict__ gbound)
{
    int b = blockIdx.x;
    if (b < PREP_CVT_BLOCKS) {
        int i = b * 256 + threadIdx.x;
        if (i < N_NODES * DIM_IN) xb[i] = f2bf(x[i]);
    } else if (b < PREP_CVT_BLOCKS + PREP_DEG_BLOCKS) {
        int e = (b - PREP_CVT_BLOCKS) * 256 + threadIdx.x;
        if (e < N_EDGES) atomicAdd(&deg[edst[e]], 1);
    } else {
        int g = (b - PREP_CVT_BLOCKS - PREP_DEG_BLOCKS) * 256 + threadIdx.x;
        if (g <= NGRAPH) {
            int lo = 0, hi = N_NODES;
            while (lo < hi) {
                int mid = (lo + hi) >> 1;
                if (batch[mid] < g) lo = mid + 1; else hi = mid;
            }
            gbound[g] = lo;
        }
    }
}

// All 5 layers' transposed concat bf16 weights in one launch. grid.y = layer.
__global__ void k_cvt_wT_all(
    const float* __restrict__ Wq1, const float* __restrict__ Wk1,
    const float* __restrict__ Wv1, const float* __restrict__ Ws1,
    const float* __restrict__ Wq_r, const float* __restrict__ Wk_r,
    const float* __restrict__ Wv_r, const float* __restrict__ Ws_r,
    ushort_t* __restrict__ Wb0, ushort_t* __restrict__ Wbr)
{
    const int L = blockIdx.y;
    const int K = (L == 0) ? DIM_IN : HIDDEN;
    int i = blockIdx.x * blockDim.x + threadIdx.x;
    if (i >= K * NALL) return;
    const float *Wq, *Wk, *Wv, *Ws; ushort_t* dst;
    if (L == 0) { Wq = Wq1; Wk = Wk1; Wv = Wv1; Ws = Ws1; dst = Wb0; }
    else {
        int j = L - 1;
        Wq = Wq_r + (size_t)j * HIDDEN * HD; Wk = Wk_r + (size_t)j * HIDDEN * HD;
        Wv = Wv_r + (size_t)j * HIDDEN * HD; Ws = Ws_r + (size_t)j * HIDDEN * HIDDEN;
        dst = Wbr + (size_t)j * HIDDEN * NALL;
    }
    int n = i / K, k = i - n * K;
    float v;
    if (n < 576)       v = Wq[(size_t)k * HD + n];
    else if (n < 1152) v = Wk[(size_t)k * HD + (n - 576)];
    else if (n < 1728) v = Wv[(size_t)k * HD + (n - 1152)];
    else               v = Ws[(size_t)k * HIDDEN + (n - 1728)];
    dst[i] = f2bf(v);
}

// ---------------------------------------------------------------------------
// bf16 MFMA fused QKVS projection. Swapped-operand epilogue (verified R11)
// + XCD-chunked swizzle (verified R12) + 256-row tile (verified R13).
// ---------------------------------------------------------------------------
template<int KDIM>
__global__ __launch_bounds__(256) void gemm_qkvs_mfma(
    const ushort_t* __restrict__ A, int M,
    const ushort_t* __restrict__ WbT,
    const float* __restrict__ bq, const float* __restrict__ bk,
    const float* __restrict__ bv, const float* __restrict__ bs,
    ushort_t* __restrict__ kvqs, uchar_t* __restrict__ kvf8)
{
    // XCD-chunked swizzle (verified): blocks with equal (blockIdx&7) share
    // an XCD; contiguous lin ranges keep one mtile's rb-blocks on one XCD.
    const int lin = (blockIdx.x & 7) * GEMM_NCH + (blockIdx.x >> 3);
    if (lin >= GEMM_LIN) return;           // uniform per block (pad blocks)
    const int rb = lin % GEMM_NB;          // 0..18 column block
    const int m0 = (lin / GEMM_NB) * 256;  // row tile base (256 rows)

    constexpr int LDB = KDIM + 8;       // padded B stride
    constexpr int K8  = KDIM >> 3;
    __shared__ __align__(16) ushort_t smem[256 * SLD];   // 53.2 KB
    const int t    = threadIdx.x;
    const int lane = t & 63;
    const int wm   = t >> 6;            // wave 0..3 -> 64-row band
    const int quad = lane >> 4;
    const int l16  = lane & 15;
    const int n0   = rb * 96;

    // cooperative B stage: 96 cols x KDIM, contiguous uint4 copies
    for (int idx = t; idx < 96 * K8; idx += 256) {
        int c = idx / K8, kc = idx - c * K8;
        uint4 v = *(const uint4*)(WbT + (size_t)(n0 + c) * KDIM + kc * 8);
        *(uint4*)(&smem[c * LDB + kc * 8]) = v;
    }

    // direct-global A fragment pointers (row-clamped for OOB M)
    const ushort_t* Arow[4];
    #pragma unroll
    for (int i = 0; i < 4; i++) {
        int row = m0 + wm * 64 + i * 16 + l16;
        row = min(row, M - 1);
        Arow[i] = A + (size_t)row * KDIM + quad * 8;
    }
    __syncthreads();

    f32x4 acc[4][6] = {};
    #pragma unroll
    for (int ks = 0; ks < KDIM; ks += 32) {
        bf16x8 af[4], bfv[6];
        #pragma unroll
        for (int i = 0; i < 4; i++) af[i] = *(const bf16x8*)(Arow[i] + ks);
        #pragma unroll
        for (int j = 0; j < 6; j++)
            bfv[j] = *(const bf16x8*)(&smem[(j * 16 + l16) * LDB + ks + quad * 8]);
        // swapped operands: lane holds row m = m0+wm*64+i*16+l16,
        // cols n = j*16+quad*4+{0..3}
        #pragma unroll
        for (int i = 0; i < 4; i++)
            #pragma unroll
            for (int j = 0; j < 6; j++)
                acc[i][j] = __builtin_amdgcn_mfma_f32_16x16x32_bf16(bfv[j], af[i], acc[i][j], 0, 0, 0);
    }

    // region select (boundaries are multiples of 96)
    int region; const float* biasp;
    if (rb < 6)       { region = 0; biasp = bq; }
    else if (rb < 12) { region = 1; biasp = bk; }
    else if (rb < 18) { region = 2; biasp = bv; }
    else              { region = 3; biasp = bs; }
    const int colbase = (region == 3) ? 0 : (rb - region * 6) * 96;
    // per-lane 4-col bias (cols j*16 + quad*4 + r)
    float bb[6][4];
    #pragma unroll
    for (int j = 0; j < 6; j++)
        #pragma unroll
        for (int r = 0; r < 4; r++)
            bb[j][r] = biasp[colbase + j * 16 + quad * 4 + r];

    __syncthreads();   // done reading B from smem; safe to overwrite

    if (region == 1 || region == 2) {
        // ---- K/V: packed fp8 dword stage + cooperative 16B stores ------
        uchar_t* bstage = (uchar_t*)smem;
        #pragma unroll
        for (int i = 0; i < 4; i++) {
            int row = wm * 64 + i * 16 + l16;
            #pragma unroll
            for (int j = 0; j < 6; j++) {
                unsigned int pk = pk_fp8x4(acc[i][j][0] + bb[j][0],
                                           acc[i][j][1] + bb[j][1],
                                           acc[i][j][2] + bb[j][2],
                                           acc[i][j][3] + bb[j][3]);
                *(unsigned int*)(bstage + row * BSTR + j * 16 + quad * 4) = pk;
            }
        }
        __syncthreads();
        const int c0 = (rb - 6) * 96;   // 0..1056 spans K|V contiguously
        for (int idx = t; idx < 256 * 6; idx += 256) {
            int r = idx / 6, v4 = idx - r * 6;
            int row = m0 + r;
            if (row < M)
                *(uint4*)(kvf8 + (size_t)row * KVF8LD + c0 + v4 * 16) =
                    *(const uint4*)(bstage + r * BSTR + v4 * 16);
        }
    } else {
        // ---- Q/S: packed bf16 8B stage + cooperative 16B stores --------
        int dstoff = (region == 0) ? n0 : 576;
        #pragma unroll
        for (int i = 0; i < 4; i++) {
            int row = wm * 64 + i * 16 + l16;
            #pragma unroll
            for (int j = 0; j < 6; j++) {
                unsigned int d0 = (unsigned int)f2bf(acc[i][j][0] + bb[j][0])
                                | ((unsigned int)f2bf(acc[i][j][1] + bb[j][1]) << 16);
                unsigned int d1 = (unsigned int)f2bf(acc[i][j][2] + bb[j][2])
                                | ((unsigned int)f2bf(acc[i][j][3] + bb[j][3]) << 16);
                uint2 dd; dd.x = d0; dd.y = d1;
                *(uint2*)(&smem[row * SLD + j * 16 + quad * 4]) = dd;
            }
        }
        __syncthreads();
        for (int idx = t; idx < 256 * 12; idx += 256) {
            int r = idx / 12, v = idx - r * 12;
            int row = m0 + r;
            if (row < M)
                *(uint4*)(kvqs + (size_t)row * LDROW + dstoff + v * 8) =
                    *(const uint4*)(&smem[r * SLD + v * 8]);
        }
    }
}

// ---------------------------------------------------------------------------
// CSR construction — multi-block 3-phase scan (verified R14) + scatter.
// ---------------------------------------------------------------------------
__global__ __launch_bounds__(256) void k_scan_part(const int* __restrict__ deg,
                                                   int* __restrict__ bsum)
{
    __shared__ int red[256];
    int b = blockIdx.x, t = threadIdx.x;
    int v = (t < SC_NPB) ? deg[b * SC_NPB + t] : 0;
    red[t] = v;
    __syncthreads();
    for (int o = 128; o; o >>= 1) {
        if (t < o) red[t] += red[t + o];
        __syncthreads();
    }
    if (t == 0) bsum[b] = red[0];
}

__global__ __launch_bounds__(128) void k_scan_top(const int* __restrict__ bsum,
                                                  int* __restrict__ boff,
                                                  int* __restrict__ row_ptr)
{
    __shared__ int part[128];
    int t = threadIdx.x;
    int v = (t < SC_BLKS) ? bsum[t] : 0;
    part[t] = v;
    __syncthreads();
    for (int o = 1; o < 128; o <<= 1) {
        int x = (t >= o) ? part[t - o] : 0;
        __syncthreads();
        part[t] += x;
        __syncthreads();
    }
    if (t < SC_BLKS) boff[t] = part[t] - v;   // exclusive
    if (t == SC_BLKS - 1) row_ptr[N_NODES] = part[t];
}

__global__ __launch_bounds__(256) void k_scan_down(const int* __restrict__ deg,
                                                   const int* __restrict__ boff,
                                                   int* __restrict__ row_ptr,
                                                   int* __restrict__ cursor)
{
    __shared__ int part[256];
    int b = blockIdx.x, t = threadIdx.x;
    int idx = b * SC_NPB + t;
    int v = (t < SC_NPB) ? deg[idx] : 0;
    part[t] = v;
    __syncthreads();
    for (int o = 1; o < 256; o <<= 1) {
        int x = (t >= o) ? part[t - o] : 0;
        __syncthreads();
        part[t] += x;
        __syncthreads();
    }
    if (t < SC_NPB) {
        int r = boff[b] + part[t] - v;   // exclusive within block + offset
        row_ptr[idx] = r;
        cursor[idx]  = r;
    }
}

__global__ void k_scatter(const int* __restrict__ esrc, const int* __restrict__ edst,
                          int* __restrict__ cursor, int* __restrict__ csrc)
{
    int e = blockIdx.x * blockDim.x + threadIdx.x;
    if (e < N_EDGES) {
        int pos = atomicAdd(&cursor[edst[e]], 1);
        csrc[pos] = esrc[e];
    }
}

// ---------------------------------------------------------------------------
// Fused per-destination-node attention. fp8 K (pass 1) + fp8 V (pass 2).
// ONE WAVE (64 threads) PER NODE — verified best (R2/R11-R14).
// ---------------------------------------------------------------------------
__global__ __launch_bounds__(64) void node_attn(
    const ushort_t* __restrict__ kvqs, const uchar_t* __restrict__ kvf8,
    const int* __restrict__ row_ptr, const int* __restrict__ csrc,
    ushort_t* __restrict__ hb)
{
    const int n    = blockIdx.x;
    const int lane = threadIdx.x;          // 0..63

    __shared__ float QA[HD];               // Q as f32; reused as 'arr' in epilogue
    __shared__ float wbuf[CHUNK * NH];
    __shared__ int   srcs[CHUNK];
    __shared__ float mh[NH], lh[NH], scl[NH], linv[NH];

    const int beg = row_ptr[n], end = row_ptr[n + 1];
    const ushort_t* qk = kvqs + (size_t)n * LDROW;

    // Q stage: 72 uint4 (8 bf16 each) -> 576 floats. lanes 0..63 + 0..7.
    {
        uint4 v = *(const uint4*)(qk + lane * 8);
        unsigned int uu[4] = {v.x, v.y, v.z, v.w};
        #pragma unroll
        for (int j = 0; j < 4; j++) {
            QA[lane * 8 + 2 * j]     = bflo(uu[j]);
            QA[lane * 8 + 2 * j + 1] = bfhi(uu[j]);
        }
        if (lane < 8) {
            uint4 v2 = *(const uint4*)(qk + (64 + lane) * 8);
            unsigned int uu2[4] = {v2.x, v2.y, v2.z, v2.w};
            #pragma unroll
            for (int j = 0; j < 4; j++) {
                QA[(64 + lane) * 8 + 2 * j]     = bflo(uu2[j]);
                QA[(64 + lane) * 8 + 2 * j + 1] = bfhi(uu2[j]);
            }
        }
    }
    if (lane < NH) { mh[lane] = -1e30f; lh[lane] = 0.f; }

    // pass-1 lane mapping: sub-edge slot + (head, quarter)
    const int sub = lane >> 5;             // 0/1: which of 2 edges per iter
    const int h32 = lane & 31;
    const int g   = h32 >> 2;              // 0..7 (6,7 idle in pass 1)
    const int gg  = (g < 6) ? g : 0;
    const int qr  = h32 & 3;
    // pass-2 lane mapping: 48 lanes own 12 dims each, head-aligned
    const int hh  = lane >> 3;             // 0..7 (6,7 idle in pass 2)
    const int j8  = lane & 7;
    const uchar_t* vb = kvf8 + 576 + ((hh < 6) ? hh : 0) * HIDDEN + j8 * 12;

    float acc[12];
    #pragma unroll
    for (int d = 0; d < 12; d++) acc[d] = 0.f;
    const float qa = 0.10206207261596577f; // 1/sqrt(96)

    __syncthreads();   // Q, m, l ready (single wave: degenerates to waitcnt)

    for (int cb = beg; cb < end; cb += CHUNK) {
        const int c = min(CHUNK, end - cb);
        __syncthreads();
        if (lane < c) srcs[lane] = csrc[cb + lane];
        __syncthreads();

        // ---- pass 1: logits, 2 edges per iteration, fp8 K ---------------
        #pragma unroll 2
        for (int eb = 0; eb < c; eb += 2) {
            int e = eb + sub;
            bool act = (e < c) && (g < 6);
            int src = srcs[(e < c) ? e : 0];
            const uchar_t* kp = kvf8 + (size_t)src * KVF8LD + gg * HIDDEN + qr * 24;
            uint2 a0 = *(const uint2*)(kp);
            uint2 a1 = *(const uint2*)(kp + 8);
            uint2 a2 = *(const uint2*)(kp + 16);
            const float* qb = &QA[gg * HIDDEN + qr * 24];
            unsigned int uu[6] = {a0.x, a0.y, a1.x, a1.y, a2.x, a2.y};
            float p = 0.f;
            #pragma unroll
            for (int k2 = 0; k2 < 6; k2++) {
                f32x2 lo = __builtin_amdgcn_cvt_pk_f32_fp8(uu[k2], false);
                f32x2 hi = __builtin_amdgcn_cvt_pk_f32_fp8(uu[k2], true);
                p += lo[0] * qb[4 * k2]     + lo[1] * qb[4 * k2 + 1]
                   + hi[0] * qb[4 * k2 + 2] + hi[1] * qb[4 * k2 + 3];
            }
            p += __shfl_xor(p, 1, 64);
            p += __shfl_xor(p, 2, 64);
            if (act && qr == 0) wbuf[e * NH + g] = p * qa;
        }
        __syncthreads();

        // ---- softmax: 3 iterations x 2 heads (32 lanes each) ------------
        #pragma unroll
        for (int s = 0; s < 3; s++) {
            int h = 2 * s + sub;
            float logit = (h32 < c) ? wbuf[h32 * NH + h] : -1e30f;
            float cm = logit;
            #pragma unroll
            for (int o = 16; o; o >>= 1) cm = fmaxf(cm, __shfl_xor(cm, o, 32));
            cm = fmaxf(cm, mh[h]);
            float wv = (h32 < c) ? __expf(logit - cm) : 0.f;
            if (h32 < c) wbuf[h32 * NH + h] = wv;
            float lp = wv;
            #pragma unroll
            for (int o = 16; o; o >>= 1) lp += __shfl_xor(lp, o, 32);
            if (h32 == 0) {
                float sc = __expf(mh[h] - cm);
                scl[h] = sc;
                lh[h] = lh[h] * sc + lp;
                mh[h] = cm;
            }
        }
        __syncthreads();

        // ---- pass 2: fp8 V aggregation, 48 lanes x 12 dims --------------
        if (lane < 48) {
            float sc = scl[hh];
            #pragma unroll
            for (int d = 0; d < 12; d++) acc[d] *= sc;
            int e = 0;
            for (; e + 2 <= c; e += 2) {
                int s0 = srcs[e], s1 = srcs[e + 1];
                const uchar_t* p0 = vb + (size_t)s0 * KVF8LD;
                const uchar_t* p1 = vb + (size_t)s1 * KVF8LD;
                unsigned int r0[3], r1[3];
                #pragma unroll
                for (int k = 0; k < 3; k++) {
                    r0[k] = *(const unsigned int*)(p0 + 4 * k);
                    r1[k] = *(const unsigned int*)(p1 + 4 * k);
                }
                float w0 = wbuf[e * NH + hh], w1 = wbuf[(e + 1) * NH + hh];
                #pragma unroll
                for (int k = 0; k < 3; k++) {
                    f32x2 lo0 = __builtin_amdgcn_cvt_pk_f32_fp8(r0[k], false);
                    f32x2 hi0 = __builtin_amdgcn_cvt_pk_f32_fp8(r0[k], true);
                    acc[4 * k]     += w0 * lo0[0];
                    acc[4 * k + 1] += w0 * lo0[1];
                    acc[4 * k + 2] += w0 * hi0[0];
                    acc[4 * k + 3] += w0 * hi0[1];
                    f32x2 lo1 = __builtin_amdgcn_cvt_pk_f32_fp8(r1[k], false);
                    f32x2 hi1 = __builtin_amdgcn_cvt_pk_f32_fp8(r1[k], true);
                    acc[4 * k]     += w1 * lo1[0];
                    acc[4 * k + 1] += w1 * lo1[1];
                    acc[4 * k + 2] += w1 * hi1[0];
                    acc[4 * k + 3] += w1 * hi1[1];
                }
            }
            if (e < c) {
                int s0 = srcs[e];
                const uchar_t* p0 = vb + (size_t)s0 * KVF8LD;
                float w0 = wbuf[e * NH + hh];
                #pragma unroll
                for (int k = 0; k < 3; k++) {
                    unsigned int r = *(const unsigned int*)(p0 + 4 * k);
                    f32x2 lo = __builtin_amdgcn_cvt_pk_f32_fp8(r, false);
                    f32x2 hi = __builtin_amdgcn_cvt_pk_f32_fp8(r, true);
                    acc[4 * k]     += w0 * lo[0];
                    acc[4 * k + 1] += w0 * lo[1];
                    acc[4 * k + 2] += w0 * hi[0];
                    acc[4 * k + 3] += w0 * hi[1];
                }
            }
        }
    }

    if (lane < NH) linv[lane] = (lh[lane] > 0.f) ? 1.0f / lh[lane] : 0.f;
    __syncthreads();
    if (lane < 48) {
        float li = linv[hh];
        #pragma unroll
        for (int d = 0; d < 12; d++)
            QA[hh * HIDDEN + j8 * 12 + d] = acc[d] * li;   // QA reused as 'arr'
    }
    __syncthreads();

    {
        int d = lane;
        float s = (QA[d] + QA[HIDDEN + d] + QA[2 * HIDDEN + d] +
                   QA[3 * HIDDEN + d] + QA[4 * HIDDEN + d] + QA[5 * HIDDEN + d])
                  * (1.0f / 6.0f);
        s += bfs(qk[576 + d]);
        s = fmaxf(s, 0.0f);
        hb[n * HIDDEN + d] = f2bf(s);
        if (lane < 32) {
            int d2 = 64 + lane;
            float s2 = (QA[d2] + QA[HIDDEN + d2] + QA[2 * HIDDEN + d2] +
                        QA[3 * HIDDEN + d2] + QA[4 * HIDDEN + d2] + QA[5 * HIDDEN + d2])
                       * (1.0f / 6.0f);
            s2 += bfs(qk[576 + d2]);
            s2 = fmaxf(s2, 0.0f);
            hb[n * HIDDEN + d2] = f2bf(s2);
        }
    }
}

// ---------------------------------------------------------------------------
// Head with fused mean-pool. R15: vectorized pool (uint4 = 8 bf16 per load,
// 10 node-slices x 12 dim-chunks, LDS partial reduce) + parallel gnorm
// (64-lane shuffle reduce) replacing the serial t==0 loop.
// ---------------------------------------------------------------------------
__global__ __launch_bounds__(128) void k_head(
    const ushort_t* __restrict__ hb, const int* __restrict__ gbound,
    const float* __restrict__ fc1w, const float* __restrict__ fc1b,
    const float* __restrict__ fc2w, const float* __restrict__ fc2b,
    const float* __restrict__ arcw, float* __restrict__ out)
{
    int g = blockIdx.x, t = threadIdx.x;
    __shared__ float pool[10][HIDDEN];     // per-slice partial sums
    __shared__ float v0[HIDDEN], v1[HIDDEN], v2[HIDDEN];
    __shared__ float gnorm;
    const int s0 = gbound[g], s1 = gbound[g + 1];
    float cnt = fmaxf((float)(s1 - s0), 1.0f);

    // vectorized mean-pool: 120 active threads = 10 slices x 12 dim-chunks
    {
        const int ts = t / 12;             // node slice 0..9 (t<120)
        const int tc = t - ts * 12;        // dim chunk 0..11 (8 dims each)
        if (ts < 10) {
            float a[8] = {0.f};
            for (int n = s0 + ts; n < s1; n += 10) {
                uint4 v = *(const uint4*)(hb + (size_t)n * HIDDEN + tc * 8);
                unsigned int uu[4] = {v.x, v.y, v.z, v.w};
                #pragma unroll
                for (int j = 0; j < 4; j++) {
                    a[2 * j]     += bflo(uu[j]);
                    a[2 * j + 1] += bfhi(uu[j]);
                }
            }
            #pragma unroll
            for (int j = 0; j < 8; j++) pool[ts][tc * 8 + j] = a[j];
        }
    }
    __syncthreads();
    if (t < HIDDEN) {
        float s = 0.f;
        #pragma unroll
        for (int sl = 0; sl < 10; sl++) s += pool[sl][t];
        v0[t] = s / cnt;
    }
    __syncthreads();
    if (t < HIDDEN) {
        float s = fc1b[t];
        for (int k = 0; k < HIDDEN; k++) s += v0[k] * fc1w[k * HIDDEN + t];
        v1[t] = fmaxf(s, 0.f);
    }
    __syncthreads();
    if (t < HIDDEN) {
        float s = fc2b[t];
        for (int k = 0; k < HIDDEN; k++) s += v1[k] * fc2w[k * HIDDEN + t];
        v2[t] = fmaxf(s, 0.f);
    }
    __syncthreads();
    // parallel gnorm: 64-lane shuffle reduce over v2^2
    if (t < 64) {
        float s = v2[t] * v2[t];
        if (t < 32) s += v2[64 + t] * v2[64 + t];
        #pragma unroll
        for (int o = 32; o; o >>= 1) s += __shfl_xor(s, o, 64);
        if (t == 0) gnorm = sqrtf(s) + 1e-12f;
    }
    __syncthreads();
    if (t < NCLS) {
        float dot = 0.f, wn = 0.f;
        const float* wr = arcw + (size_t)t * HIDDEN;
        for (int k = 0; k < HIDDEN; k++) {
            float w = wr[k];
            dot += w * v2[k];
            wn  += w * w;
        }
        out[g * NCLS + t] = 30.0f * dot / (gnorm * (sqrtf(wn) + 1e-12f));
    }
}

// ---------------------------------------------------------------------------
extern "C" void kernel_launch(void* const* d_in, const int* in_sizes, int n_in,
                              void* d_out, int out_size, void* d_ws, size_t ws_size,
                              hipStream_t stream)
{
    (void)in_sizes; (void)n_in; (void)out_size; (void)ws_size;

    const float* x     = (const float*)d_in[0];
    const int*   ei    = (const int*)d_in[1];
    const int*   batch = (const int*)d_in[2];
    const float* Wq1 = (const float*)d_in[3];  const float* bq1 = (const float*)d_in[4];
    const float* Wk1 = (const float*)d_in[5];  const float* bk1 = (const float*)d_in[6];
    const float* Wv1 = (const float*)d_in[7];  const float* bv1 = (const float*)d_in[8];
    const float* Ws1 = (const float*)d_in[9];  const float* bs1 = (const float*)d_in[10];
    const float* Wq_r = (const float*)d_in[11]; const float* bq_r = (const float*)d_in[12];
    const float* Wk_r = (const float*)d_in[13]; const float* bk_r = (const float*)d_in[14];
    const float* Wv_r = (const float*)d_in[15]; const float* bv_r = (const float*)d_in[16];
    const float* Ws_r = (const float*)d_in[17]; const float* bs_r = (const float*)d_in[18];
    const float* fc1w = (const float*)d_in[19]; const float* fc1b = (const float*)d_in[20];
    const float* fc2w = (const float*)d_in[21]; const float* fc2b = (const float*)d_in[22];
    const float* arcw = (const float*)d_in[23];
    float* out = (float*)d_out;

    const int* esrc = ei;
    const int* edst = ei + N_EDGES;

    char* base = (char*)d_ws;
    size_t off = 0;
    auto alloc = [&](size_t bytes) -> void* {
        off = (off + 255) & ~(size_t)255;
        void* p = base + off;
        off += bytes;
        return p;
    };
    ushort_t* kvqs = (ushort_t*)alloc((size_t)N_NODES * LDROW * 2);  // 28.2 MB
    uchar_t*  kvf8 = (uchar_t*)alloc((size_t)N_NODES * KVF8LD);      // 23.0 MB
    ushort_t* xb  = (ushort_t*)alloc((size_t)N_NODES * DIM_IN * 2);
    ushort_t* hb0 = (ushort_t*)alloc((size_t)N_NODES * HIDDEN * 2);
    ushort_t* hb1 = (ushort_t*)alloc((size_t)N_NODES * HIDDEN * 2);
    ushort_t* Wb0 = (ushort_t*)alloc((size_t)DIM_IN * NALL * 2);
    ushort_t* Wbr = (ushort_t*)alloc((size_t)4 * HIDDEN * NALL * 2);
    int*   deg     = (int*)alloc(N_NODES * 4);
    int*   row_ptr = (int*)alloc((N_NODES + 1) * 4);
    int*   cursor  = (int*)alloc(N_NODES * 4);
    int*   csrc    = (int*)alloc(N_EDGES * 4);
    int*   gbound  = (int*)alloc((NGRAPH + 1) * 4);
    int*   bsum    = (int*)alloc(SC_BLKS * 4);
    int*   boff    = (int*)alloc(SC_BLKS * 4);

    // prep: x cast | degree | graph boundaries (one launch) + weight cast
    hipMemsetAsync(deg, 0, N_NODES * 4, stream);
    k_prep<<<PREP_CVT_BLOCKS + PREP_DEG_BLOCKS + PREP_GB_BLOCKS, 256, 0, stream>>>(
        x, xb, edst, deg, batch, gbound);
    {
        dim3 gw((DIM_IN * NALL + 255) / 256, 5);
        k_cvt_wT_all<<<gw, 256, 0, stream>>>(Wq1, Wk1, Wv1, Ws1,
                                             Wq_r, Wk_r, Wv_r, Ws_r, Wb0, Wbr);
    }
    k_scan_part<<<SC_BLKS, 256, 0, stream>>>(deg, bsum);
    k_scan_top<<<1, 128, 0, stream>>>(bsum, boff, row_ptr);
    k_scan_down<<<SC_BLKS, 256, 0, stream>>>(deg, boff, row_ptr, cursor);
    k_scatter<<<(N_EDGES + 255) / 256, 256, 0, stream>>>(esrc, edst, cursor, csrc);

    const ushort_t* Ain = xb;
    ushort_t* hbcur = hb0;
    for (int L = 0; L < 5; L++) {
        const ushort_t* Wb = (L == 0) ? Wb0 : (Wbr + (size_t)(L - 1) * HIDDEN * NALL);
        const float *bq, *bk, *bv, *bs;
        if (L == 0) { bq = bq1; bk = bk1; bv = bv1; bs = bs1; }
        else {
            int i = L - 1;
            bq = bq_r + (size_t)i * HD; bk = bk_r + (size_t)i * HD;
            bv = bv_r + (size_t)i * HD; bs = bs_r + (size_t)i * HIDDEN;
        }
        if (L == 0)
            gemm_qkvs_mfma<DIM_IN><<<GEMM_GRID, 256, 0, stream>>>(Ain, N_NODES, Wb,
                                                                  bq, bk, bv, bs, kvqs, kvf8);
        else
            gemm_qkvs_mfma<HIDDEN><<<GEMM_GRID, 256, 0, stream>>>(Ain, N_NODES, Wb,
                                                                  bq, bk, bv, bs, kvqs, kvf8);
        node_attn<<<N_NODES, 64, 0, stream>>>(kvqs, kvf8, row_ptr, csrc, hbcur);
        Ain = hbcur;
        hbcur = (hbcur == hb0) ? hb1 : hb0;
    }

    k_head<<<NGRAPH, 128, 0, stream>>>(hbcur == hb0 ? hb1 : hb0, gbound,
                                       fc1w, fc1b, fc2w, fc2b, arcw, out);
}

// Round 16
// 446.226 us; speedup vs baseline: 1.2573x; 1.0079x over previous
//
#include <hip/hip_runtime.h>
#include <math.h>

#define N_NODES 20000
#define N_EDGES 160000
#define DIM_IN  128
#define HIDDEN  96
#define NH      6
#define HD      576      // NH*HIDDEN
#define LDROW   704      // bf16 row stride: Q(576)|S(96)|pad(32) = 11 lines
#define KVF8LD  1152     // fp8 row stride BYTES: K(576)|V(576) = 9 lines
#define NALL    1824     // concat QKVS weight cols
#define NGRAPH  512
#define NCLS    128
#define CHUNK   32       // edges per softmax chunk
#define SLD     104      // bf16 LDS stage row stride (ushorts)
#define BSTR    112      // fp8 LDS stage row stride (bytes, mult of 16)
#define GEMM_NB   19     // column blocks (1824/96)
#define GEMM_NMT  79     // 256-row tiles (ceil(20000/256))
#define GEMM_LIN  (GEMM_NB * GEMM_NMT)          // 1501
#define GEMM_NCH  ((GEMM_LIN + 7) / 8)          // 188 per XCD chunk
#define GEMM_GRID (GEMM_NCH * 8)                // 1504 (3 pad blocks)
#define SC_BLKS 80       // scan blocks
#define SC_NPB  250      // nodes per scan block (80*250 = 20000 exact)

typedef unsigned short ushort_t;
typedef unsigned char uchar_t;
typedef __attribute__((ext_vector_type(8))) short bf16x8;
typedef __attribute__((ext_vector_type(4))) float f32x4;
typedef __attribute__((ext_vector_type(2))) float f32x2;

static __device__ __forceinline__ ushort_t f2bf(float f) {
    unsigned int u = __float_as_uint(f);
    return (ushort_t)((u + 0x7fffu + ((u >> 16) & 1u)) >> 16);  // RNE
}
static __device__ __forceinline__ float bfs(ushort_t u) { return __uint_as_float((unsigned int)u << 16); }
static __device__ __forceinline__ float bflo(unsigned int u) { return __uint_as_float(u << 16); }
static __device__ __forceinline__ float bfhi(unsigned int u) { return __uint_as_float(u & 0xffff0000u); }

// pack 4 f32 -> 4 fp8 bytes in one dword, via two independent cvt_pk calls
static __device__ __forceinline__ unsigned int pk_fp8x4(float a, float b, float c, float d) {
    unsigned int lo = (unsigned int)__builtin_amdgcn_cvt_pk_fp8_f32(a, b, 0, false);
    unsigned int hi = (unsigned int)__builtin_amdgcn_cvt_pk_fp8_f32(c, d, 0, false);
    return (lo & 0xffffu) | (hi << 16);
}

// ---------------------------------------------------------------------------
// Fused prep: x->bf16 cast (VECTORIZED: 8 elems/thread, float4 in, uint4 out)
// | edge degree histogram | graph boundaries.
// ---------------------------------------------------------------------------
#define PREP_CVT_BLOCKS 1250    // 20000*128/(256*8)
#define PREP_DEG_BLOCKS 625     // 160000/256
#define PREP_GB_BLOCKS  3       // ceil((NGRAPH+1)/256)
__global__ void k_prep(const float* __restrict__ x, ushort_t* __restrict__ xb,
                       const int* __restrict__ edst, int* __restrict__ deg,
                       const int* __restrict__ batch, int* __restrict__ gbound)
{
    int b = blockIdx.x;
    if (b < PREP_CVT_BLOCKS) {
        int i = (b * 256 + threadIdx.x) * 8;   // exact: 1250*256*8 = 2,560,000
        float4 v0 = *(const float4*)(x + i);
        float4 v1 = *(const float4*)(x + i + 4);
        unsigned int d0 = (unsigned int)f2bf(v0.x) | ((unsigned int)f2bf(v0.y) << 16);
        unsigned int d1 = (unsigned int)f2bf(v0.z) | ((unsigned int)f2bf(v0.w) << 16);
        unsigned int d2 = (unsigned int)f2bf(v1.x) | ((unsigned int)f2bf(v1.y) << 16);
        unsigned int d3 = (unsigned int)f2bf(v1.z) | ((unsigned int)f2bf(v1.w) << 16);
        uint4 o; o.x = d0; o.y = d1; o.z = d2; o.w = d3;
        *(uint4*)(xb + i) = o;
    } else if (b < PREP_CVT_BLOCKS + PREP_DEG_BLOCKS) {
        int e = (b - PREP_CVT_BLOCKS) * 256 + threadIdx.x;
        if (e < N_EDGES) atomicAdd(&deg[edst[e]], 1);
    } else {
        int g = (b - PREP_CVT_BLOCKS - PREP_DEG_BLOCKS) * 256 + threadIdx.x;
        if (g <= NGRAPH) {
            int lo = 0, hi = N_NODES;
            while (lo < hi) {
                int mid = (lo + hi) >> 1;
                if (batch[mid] < g) lo = mid + 1; else hi = mid;
            }
            gbound[g] = lo;
        }
    }
}

// All 5 layers' transposed concat bf16 weights in one launch. grid.y = layer.
__global__ void k_cvt_wT_all(
    const float* __restrict__ Wq1, const float* __restrict__ Wk1,
    const float* __restrict__ Wv1, const float* __restrict__ Ws1,
    const float* __restrict__ Wq_r, const float* __restrict__ Wk_r,
    const float* __restrict__ Wv_r, const float* __restrict__ Ws_r,
    ushort_t* __restrict__ Wb0, ushort_t* __restrict__ Wbr)
{
    const int L = blockIdx.y;
    const int K = (L == 0) ? DIM_IN : HIDDEN;
    int i = blockIdx.x * blockDim.x + threadIdx.x;
    if (i >= K * NALL) return;
    const float *Wq, *Wk, *Wv, *Ws; ushort_t* dst;
    if (L == 0) { Wq = Wq1; Wk = Wk1; Wv = Wv1; Ws = Ws1; dst = Wb0; }
    else {
        int j = L - 1;
        Wq = Wq_r + (size_t)j * HIDDEN * HD; Wk = Wk_r + (size_t)j * HIDDEN * HD;
        Wv = Wv_r + (size_t)j * HIDDEN * HD; Ws = Ws_r + (size_t)j * HIDDEN * HIDDEN;
        dst = Wbr + (size_t)j * HIDDEN * NALL;
    }
    int n = i / K, k = i - n * K;
    float v;
    if (n < 576)       v = Wq[(size_t)k * HD + n];
    else if (n < 1152) v = Wk[(size_t)k * HD + (n - 576)];
    else if (n < 1728) v = Wv[(size_t)k * HD + (n - 1152)];
    else               v = Ws[(size_t)k * HIDDEN + (n - 1728)];
    dst[i] = f2bf(v);
}

// ---------------------------------------------------------------------------
// bf16 MFMA fused QKVS projection. Swapped-operand epilogue (verified R11)
// + XCD-chunked swizzle (verified R12) + 256-row tile (verified R13).
// ---------------------------------------------------------------------------
template<int KDIM>
__global__ __launch_bounds__(256) void gemm_qkvs_mfma(
    const ushort_t* __restrict__ A, int M,
    const ushort_t* __restrict__ WbT,
    const float* __restrict__ bq, const float* __restrict__ bk,
    const float* __restrict__ bv, const float* __restrict__ bs,
    ushort_t* __restrict__ kvqs, uchar_t* __restrict__ kvf8)
{
    // XCD-chunked swizzle (verified): blocks with equal (blockIdx&7) share
    // an XCD; contiguous lin ranges keep one mtile's rb-blocks on one XCD.
    const int lin = (blockIdx.x & 7) * GEMM_NCH + (blockIdx.x >> 3);
    if (lin >= GEMM_LIN) return;           // uniform per block (pad blocks)
    const int rb = lin % GEMM_NB;          // 0..18 column block
    const int m0 = (lin / GEMM_NB) * 256;  // row tile base (256 rows)

    constexpr int LDB = KDIM + 8;       // padded B stride
    constexpr int K8  = KDIM >> 3;
    __shared__ __align__(16) ushort_t smem[256 * SLD];   // 53.2 KB
    const int t    = threadIdx.x;
    const int lane = t & 63;
    const int wm   = t >> 6;            // wave 0..3 -> 64-row band
    const int quad = lane >> 4;
    const int l16  = lane & 15;
    const int n0   = rb * 96;

    // cooperative B stage: 96 cols x KDIM, contiguous uint4 copies
    for (int idx = t; idx < 96 * K8; idx += 256) {
        int c = idx / K8, kc = idx - c * K8;
        uint4 v = *(const uint4*)(WbT + (size_t)(n0 + c) * KDIM + kc * 8);
        *(uint4*)(&smem[c * LDB + kc * 8]) = v;
    }

    // direct-global A fragment pointers (row-clamped for OOB M)
    const ushort_t* Arow[4];
    #pragma unroll
    for (int i = 0; i < 4; i++) {
        int row = m0 + wm * 64 + i * 16 + l16;
        row = min(row, M - 1);
        Arow[i] = A + (size_t)row * KDIM + quad * 8;
    }
    __syncthreads();

    f32x4 acc[4][6] = {};
    #pragma unroll
    for (int ks = 0; ks < KDIM; ks += 32) {
        bf16x8 af[4], bfv[6];
        #pragma unroll
        for (int i = 0; i < 4; i++) af[i] = *(const bf16x8*)(Arow[i] + ks);
        #pragma unroll
        for (int j = 0; j < 6; j++)
            bfv[j] = *(const bf16x8*)(&smem[(j * 16 + l16) * LDB + ks + quad * 8]);
        // swapped operands: lane holds row m = m0+wm*64+i*16+l16,
        // cols n = j*16+quad*4+{0..3}
        #pragma unroll
        for (int i = 0; i < 4; i++)
            #pragma unroll
            for (int j = 0; j < 6; j++)
                acc[i][j] = __builtin_amdgcn_mfma_f32_16x16x32_bf16(bfv[j], af[i], acc[i][j], 0, 0, 0);
    }

    // region select (boundaries are multiples of 96)
    int region; const float* biasp;
    if (rb < 6)       { region = 0; biasp = bq; }
    else if (rb < 12) { region = 1; biasp = bk; }
    else if (rb < 18) { region = 2; biasp = bv; }
    else              { region = 3; biasp = bs; }
    const int colbase = (region == 3) ? 0 : (rb - region * 6) * 96;
    // per-lane 4-col bias (cols j*16 + quad*4 + r)
    float bb[6][4];
    #pragma unroll
    for (int j = 0; j < 6; j++)
        #pragma unroll
        for (int r = 0; r < 4; r++)
            bb[j][r] = biasp[colbase + j * 16 + quad * 4 + r];

    __syncthreads();   // done reading B from smem; safe to overwrite

    if (region == 1 || region == 2) {
        // ---- K/V: packed fp8 dword stage + cooperative 16B stores ------
        uchar_t* bstage = (uchar_t*)smem;
        #pragma unroll
        for (int i = 0; i < 4; i++) {
            int row = wm * 64 + i * 16 + l16;
            #pragma unroll
            for (int j = 0; j < 6; j++) {
                unsigned int pk = pk_fp8x4(acc[i][j][0] + bb[j][0],
                                           acc[i][j][1] + bb[j][1],
                                           acc[i][j][2] + bb[j][2],
                                           acc[i][j][3] + bb[j][3]);
                *(unsigned int*)(bstage + row * BSTR + j * 16 + quad * 4) = pk;
            }
        }
        __syncthreads();
        const int c0 = (rb - 6) * 96;   // 0..1056 spans K|V contiguously
        for (int idx = t; idx < 256 * 6; idx += 256) {
            int r = idx / 6, v4 = idx - r * 6;
            int row = m0 + r;
            if (row < M)
                *(uint4*)(kvf8 + (size_t)row * KVF8LD + c0 + v4 * 16) =
                    *(const uint4*)(bstage + r * BSTR + v4 * 16);
        }
    } else {
        // ---- Q/S: packed bf16 8B stage + cooperative 16B stores --------
        int dstoff = (region == 0) ? n0 : 576;
        #pragma unroll
        for (int i = 0; i < 4; i++) {
            int row = wm * 64 + i * 16 + l16;
            #pragma unroll
            for (int j = 0; j < 6; j++) {
                unsigned int d0 = (unsigned int)f2bf(acc[i][j][0] + bb[j][0])
                                | ((unsigned int)f2bf(acc[i][j][1] + bb[j][1]) << 16);
                unsigned int d1 = (unsigned int)f2bf(acc[i][j][2] + bb[j][2])
                                | ((unsigned int)f2bf(acc[i][j][3] + bb[j][3]) << 16);
                uint2 dd; dd.x = d0; dd.y = d1;
                *(uint2*)(&smem[row * SLD + j * 16 + quad * 4]) = dd;
            }
        }
        __syncthreads();
        for (int idx = t; idx < 256 * 12; idx += 256) {
            int r = idx / 12, v = idx - r * 12;
            int row = m0 + r;
            if (row < M)
                *(uint4*)(kvqs + (size_t)row * LDROW + dstoff + v * 8) =
                    *(const uint4*)(&smem[r * SLD + v * 8]);
        }
    }
}

// ---------------------------------------------------------------------------
// CSR construction — multi-block 3-phase scan (verified R14) + scatter.
// ---------------------------------------------------------------------------
__global__ __launch_bounds__(256) void k_scan_part(const int* __restrict__ deg,
                                                   int* __restrict__ bsum)
{
    __shared__ int red[256];
    int b = blockIdx.x, t = threadIdx.x;
    int v = (t < SC_NPB) ? deg[b * SC_NPB + t] : 0;
    red[t] = v;
    __syncthreads();
    for (int o = 128; o; o >>= 1) {
        if (t < o) red[t] += red[t + o];
        __syncthreads();
    }
    if (t == 0) bsum[b] = red[0];
}

__global__ __launch_bounds__(128) void k_scan_top(const int* __restrict__ bsum,
                                                  int* __restrict__ boff,
                                                  int* __restrict__ row_ptr)
{
    __shared__ int part[128];
    int t = threadIdx.x;
    int v = (t < SC_BLKS) ? bsum[t] : 0;
    part[t] = v;
    __syncthreads();
    for (int o = 1; o < 128; o <<= 1) {
        int x = (t >= o) ? part[t - o] : 0;
        __syncthreads();
        part[t] += x;
        __syncthreads();
    }
    if (t < SC_BLKS) boff[t] = part[t] - v;   // exclusive
    if (t == SC_BLKS - 1) row_ptr[N_NODES] = part[t];
}

__global__ __launch_bounds__(256) void k_scan_down(const int* __restrict__ deg,
                                                   const int* __restrict__ boff,
                                                   int* __restrict__ row_ptr,
                                                   int* __restrict__ cursor)
{
    __shared__ int part[256];
    int b = blockIdx.x, t = threadIdx.x;
    int idx = b * SC_NPB + t;
    int v = (t < SC_NPB) ? deg[idx] : 0;
    part[t] = v;
    __syncthreads();
    for (int o = 1; o < 256; o <<= 1) {
        int x = (t >= o) ? part[t - o] : 0;
        __syncthreads();
        part[t] += x;
        __syncthreads();
    }
    if (t < SC_NPB) {
        int r = boff[b] + part[t] - v;   // exclusive within block + offset
        row_ptr[idx] = r;
        cursor[idx]  = r;
    }
}

__global__ void k_scatter(const int* __restrict__ esrc, const int* __restrict__ edst,
                          int* __restrict__ cursor, int* __restrict__ csrc)
{
    int e = blockIdx.x * blockDim.x + threadIdx.x;
    if (e < N_EDGES) {
        int pos = atomicAdd(&cursor[edst[e]], 1);
        csrc[pos] = esrc[e];
    }
}

// ---------------------------------------------------------------------------
// Fused per-destination-node attention. fp8 K (pass 1) + fp8 V (pass 2).
// ONE WAVE (64 threads) PER NODE — verified best (R2/R11-R15).
// ---------------------------------------------------------------------------
__global__ __launch_bounds__(64) void node_attn(
    const ushort_t* __restrict__ kvqs, const uchar_t* __restrict__ kvf8,
    const int* __restrict__ row_ptr, const int* __restrict__ csrc,
    ushort_t* __restrict__ hb)
{
    const int n    = blockIdx.x;
    const int lane = threadIdx.x;          // 0..63

    __shared__ float QA[HD];               // Q as f32; reused as 'arr' in epilogue
    __shared__ float wbuf[CHUNK * NH];
    __shared__ int   srcs[CHUNK];
    __shared__ float mh[NH], lh[NH], scl[NH], linv[NH];

    const int beg = row_ptr[n], end = row_ptr[n + 1];
    const ushort_t* qk = kvqs + (size_t)n * LDROW;

    // Q stage: 72 uint4 (8 bf16 each) -> 576 floats. lanes 0..63 + 0..7.
    {
        uint4 v = *(const uint4*)(qk + lane * 8);
        unsigned int uu[4] = {v.x, v.y, v.z, v.w};
        #pragma unroll
        for (int j = 0; j < 4; j++) {
            QA[lane * 8 + 2 * j]     = bflo(uu[j]);
            QA[lane * 8 + 2 * j + 1] = bfhi(uu[j]);
        }
        if (lane < 8) {
            uint4 v2 = *(const uint4*)(qk + (64 + lane) * 8);
            unsigned int uu2[4] = {v2.x, v2.y, v2.z, v2.w};
            #pragma unroll
            for (int j = 0; j < 4; j++) {
                QA[(64 + lane) * 8 + 2 * j]     = bflo(uu2[j]);
                QA[(64 + lane) * 8 + 2 * j + 1] = bfhi(uu2[j]);
            }
        }
    }
    if (lane < NH) { mh[lane] = -1e30f; lh[lane] = 0.f; }

    // pass-1 lane mapping: sub-edge slot + (head, quarter)
    const int sub = lane >> 5;             // 0/1: which of 2 edges per iter
    const int h32 = lane & 31;
    const int g   = h32 >> 2;              // 0..7 (6,7 idle in pass 1)
    const int gg  = (g < 6) ? g : 0;
    const int qr  = h32 & 3;
    // pass-2 lane mapping: 48 lanes own 12 dims each, head-aligned
    const int hh  = lane >> 3;             // 0..7 (6,7 idle in pass 2)
    const int j8  = lane & 7;
    const uchar_t* vb = kvf8 + 576 + ((hh < 6) ? hh : 0) * HIDDEN + j8 * 12;

    float acc[12];
    #pragma unroll
    for (int d = 0; d < 12; d++) acc[d] = 0.f;
    const float qa = 0.10206207261596577f; // 1/sqrt(96)

    __syncthreads();   // Q, m, l ready (single wave: degenerates to waitcnt)

    for (int cb = beg; cb < end; cb += CHUNK) {
        const int c = min(CHUNK, end - cb);
        __syncthreads();
        if (lane < c) srcs[lane] = csrc[cb + lane];
        __syncthreads();

        // ---- pass 1: logits, 2 edges per iteration, fp8 K ---------------
        #pragma unroll 2
        for (int eb = 0; eb < c; eb += 2) {
            int e = eb + sub;
            bool act = (e < c) && (g < 6);
            int src = srcs[(e < c) ? e : 0];
            const uchar_t* kp = kvf8 + (size_t)src * KVF8LD + gg * HIDDEN + qr * 24;
            uint2 a0 = *(const uint2*)(kp);
            uint2 a1 = *(const uint2*)(kp + 8);
            uint2 a2 = *(const uint2*)(kp + 16);
            const float* qb = &QA[gg * HIDDEN + qr * 24];
            unsigned int uu[6] = {a0.x, a0.y, a1.x, a1.y, a2.x, a2.y};
            float p = 0.f;
            #pragma unroll
            for (int k2 = 0; k2 < 6; k2++) {
                f32x2 lo = __builtin_amdgcn_cvt_pk_f32_fp8(uu[k2], false);
                f32x2 hi = __builtin_amdgcn_cvt_pk_f32_fp8(uu[k2], true);
                p += lo[0] * qb[4 * k2]     + lo[1] * qb[4 * k2 + 1]
                   + hi[0] * qb[4 * k2 + 2] + hi[1] * qb[4 * k2 + 3];
            }
            p += __shfl_xor(p, 1, 64);
            p += __shfl_xor(p, 2, 64);
            if (act && qr == 0) wbuf[e * NH + g] = p * qa;
        }
        __syncthreads();

        // ---- softmax: 3 iterations x 2 heads (32 lanes each) ------------
        #pragma unroll
        for (int s = 0; s < 3; s++) {
            int h = 2 * s + sub;
            float logit = (h32 < c) ? wbuf[h32 * NH + h] : -1e30f;
            float cm = logit;
            #pragma unroll
            for (int o = 16; o; o >>= 1) cm = fmaxf(cm, __shfl_xor(cm, o, 32));
            cm = fmaxf(cm, mh[h]);
            float wv = (h32 < c) ? __expf(logit - cm) : 0.f;
            if (h32 < c) wbuf[h32 * NH + h] = wv;
            float lp = wv;
            #pragma unroll
            for (int o = 16; o; o >>= 1) lp += __shfl_xor(lp, o, 32);
            if (h32 == 0) {
                float sc = __expf(mh[h] - cm);
                scl[h] = sc;
                lh[h] = lh[h] * sc + lp;
                mh[h] = cm;
            }
        }
        __syncthreads();

        // ---- pass 2: fp8 V aggregation, 48 lanes x 12 dims --------------
        if (lane < 48) {
            float sc = scl[hh];
            #pragma unroll
            for (int d = 0; d < 12; d++) acc[d] *= sc;
            int e = 0;
            for (; e + 2 <= c; e += 2) {
                int s0 = srcs[e], s1 = srcs[e + 1];
                const uchar_t* p0 = vb + (size_t)s0 * KVF8LD;
                const uchar_t* p1 = vb + (size_t)s1 * KVF8LD;
                unsigned int r0[3], r1[3];
                #pragma unroll
                for (int k = 0; k < 3; k++) {
                    r0[k] = *(const unsigned int*)(p0 + 4 * k);
                    r1[k] = *(const unsigned int*)(p1 + 4 * k);
                }
                float w0 = wbuf[e * NH + hh], w1 = wbuf[(e + 1) * NH + hh];
                #pragma unroll
                for (int k = 0; k < 3; k++) {
                    f32x2 lo0 = __builtin_amdgcn_cvt_pk_f32_fp8(r0[k], false);
                    f32x2 hi0 = __builtin_amdgcn_cvt_pk_f32_fp8(r0[k], true);
                    acc[4 * k]     += w0 * lo0[0];
                    acc[4 * k + 1] += w0 * lo0[1];
                    acc[4 * k + 2] += w0 * hi0[0];
                    acc[4 * k + 3] += w0 * hi0[1];
                    f32x2 lo1 = __builtin_amdgcn_cvt_pk_f32_fp8(r1[k], false);
                    f32x2 hi1 = __builtin_amdgcn_cvt_pk_f32_fp8(r1[k], true);
                    acc[4 * k]     += w1 * lo1[0];
                    acc[4 * k + 1] += w1 * lo1[1];
                    acc[4 * k + 2] += w1 * hi1[0];
                    acc[4 * k + 3] += w1 * hi1[1];
                }
            }
            if (e < c) {
                int s0 = srcs[e];
                const uchar_t* p0 = vb + (size_t)s0 * KVF8LD;
                float w0 = wbuf[e * NH + hh];
                #pragma unroll
                for (int k = 0; k < 3; k++) {
                    unsigned int r = *(const unsigned int*)(p0 + 4 * k);
                    f32x2 lo = __builtin_amdgcn_cvt_pk_f32_fp8(r, false);
                    f32x2 hi = __builtin_amdgcn_cvt_pk_f32_fp8(r, true);
                    acc[4 * k]     += w0 * lo[0];
                    acc[4 * k + 1] += w0 * lo[1];
                    acc[4 * k + 2] += w0 * hi[0];
                    acc[4 * k + 3] += w0 * hi[1];
                }
            }
        }
    }

    if (lane < NH) linv[lane] = (lh[lane] > 0.f) ? 1.0f / lh[lane] : 0.f;
    __syncthreads();
    if (lane < 48) {
        float li = linv[hh];
        #pragma unroll
        for (int d = 0; d < 12; d++)
            QA[hh * HIDDEN + j8 * 12 + d] = acc[d] * li;   // QA reused as 'arr'
    }
    __syncthreads();

    {
        int d = lane;
        float s = (QA[d] + QA[HIDDEN + d] + QA[2 * HIDDEN + d] +
                   QA[3 * HIDDEN + d] + QA[4 * HIDDEN + d] + QA[5 * HIDDEN + d])
                  * (1.0f / 6.0f);
        s += bfs(qk[576 + d]);
        s = fmaxf(s, 0.0f);
        hb[n * HIDDEN + d] = f2bf(s);
        if (lane < 32) {
            int d2 = 64 + lane;
            float s2 = (QA[d2] + QA[HIDDEN + d2] + QA[2 * HIDDEN + d2] +
                        QA[3 * HIDDEN + d2] + QA[4 * HIDDEN + d2] + QA[5 * HIDDEN + d2])
                       * (1.0f / 6.0f);
            s2 += bfs(qk[576 + d2]);
            s2 = fmaxf(s2, 0.0f);
            hb[n * HIDDEN + d2] = f2bf(s2);
        }
    }
}

// ---------------------------------------------------------------------------
// Head with fused mean-pool (verified R15: vectorized pool + parallel gnorm).
// ---------------------------------------------------------------------------
__global__ __launch_bounds__(128) void k_head(
    const ushort_t* __restrict__ hb, const int* __restrict__ gbound,
    const float* __restrict__ fc1w, const float* __restrict__ fc1b,
    const float* __restrict__ fc2w, const float* __restrict__ fc2b,
    const float* __restrict__ arcw, float* __restrict__ out)
{
    int g = blockIdx.x, t = threadIdx.x;
    __shared__ float pool[10][HIDDEN];     // per-slice partial sums
    __shared__ float v0[HIDDEN], v1[HIDDEN], v2[HIDDEN];
    __shared__ float gnorm;
    const int s0 = gbound[g], s1 = gbound[g + 1];
    float cnt = fmaxf((float)(s1 - s0), 1.0f);

    // vectorized mean-pool: 120 active threads = 10 slices x 12 dim-chunks
    {
        const int ts = t / 12;             // node slice 0..9 (t<120)
        const int tc = t - ts * 12;        // dim chunk 0..11 (8 dims each)
        if (ts < 10) {
            float a[8] = {0.f};
            for (int n = s0 + ts; n < s1; n += 10) {
                uint4 v = *(const uint4*)(hb + (size_t)n * HIDDEN + tc * 8);
                unsigned int uu[4] = {v.x, v.y, v.z, v.w};
                #pragma unroll
                for (int j = 0; j < 4; j++) {
                    a[2 * j]     += bflo(uu[j]);
                    a[2 * j + 1] += bfhi(uu[j]);
                }
            }
            #pragma unroll
            for (int j = 0; j < 8; j++) pool[ts][tc * 8 + j] = a[j];
        }
    }
    __syncthreads();
    if (t < HIDDEN) {
        float s = 0.f;
        #pragma unroll
        for (int sl = 0; sl < 10; sl++) s += pool[sl][t];
        v0[t] = s / cnt;
    }
    __syncthreads();
    if (t < HIDDEN) {
        float s = fc1b[t];
        for (int k = 0; k < HIDDEN; k++) s += v0[k] * fc1w[k * HIDDEN + t];
        v1[t] = fmaxf(s, 0.f);
    }
    __syncthreads();
    if (t < HIDDEN) {
        float s = fc2b[t];
        for (int k = 0; k < HIDDEN; k++) s += v1[k] * fc2w[k * HIDDEN + t];
        v2[t] = fmaxf(s, 0.f);
    }
    __syncthreads();
    // parallel gnorm: 64-lane shuffle reduce over v2^2
    if (t < 64) {
        float s = v2[t] * v2[t];
        if (t < 32) s += v2[64 + t] * v2[64 + t];
        #pragma unroll
        for (int o = 32; o; o >>= 1) s += __shfl_xor(s, o, 64);
        if (t == 0) gnorm = sqrtf(s) + 1e-12f;
    }
    __syncthreads();
    if (t < NCLS) {
        float dot = 0.f, wn = 0.f;
        const float* wr = arcw + (size_t)t * HIDDEN;
        for (int k = 0; k < HIDDEN; k++) {
            float w = wr[k];
            dot += w * v2[k];
            wn  += w * w;
        }
        out[g * NCLS + t] = 30.0f * dot / (gnorm * (sqrtf(wn) + 1e-12f));
    }
}

// ---------------------------------------------------------------------------
extern "C" void kernel_launch(void* const* d_in, const int* in_sizes, int n_in,
                              void* d_out, int out_size, void* d_ws, size_t ws_size,
                              hipStream_t stream)
{
    (void)in_sizes; (void)n_in; (void)out_size; (void)ws_size;

    const float* x     = (const float*)d_in[0];
    const int*   ei    = (const int*)d_in[1];
    const int*   batch = (const int*)d_in[2];
    const float* Wq1 = (const float*)d_in[3];  const float* bq1 = (const float*)d_in[4];
    const float* Wk1 = (const float*)d_in[5];  const float* bk1 = (const float*)d_in[6];
    const float* Wv1 = (const float*)d_in[7];  const float* bv1 = (const float*)d_in[8];
    const float* Ws1 = (const float*)d_in[9];  const float* bs1 = (const float*)d_in[10];
    const float* Wq_r = (const float*)d_in[11]; const float* bq_r = (const float*)d_in[12];
    const float* Wk_r = (const float*)d_in[13]; const float* bk_r = (const float*)d_in[14];
    const float* Wv_r = (const float*)d_in[15]; const float* bv_r = (const float*)d_in[16];
    const float* Ws_r = (const float*)d_in[17]; const float* bs_r = (const float*)d_in[18];
    const float* fc1w = (const float*)d_in[19]; const float* fc1b = (const float*)d_in[20];
    const float* fc2w = (const float*)d_in[21]; const float* fc2b = (const float*)d_in[22];
    const float* arcw = (const float*)d_in[23];
    float* out = (float*)d_out;

    const int* esrc = ei;
    const int* edst = ei + N_EDGES;

    char* base = (char*)d_ws;
    size_t off = 0;
    auto alloc = [&](size_t bytes) -> void* {
        off = (off + 255) & ~(size_t)255;
        void* p = base + off;
        off += bytes;
        return p;
    };
    ushort_t* kvqs = (ushort_t*)alloc((size_t)N_NODES * LDROW * 2);  // 28.2 MB
    uchar_t*  kvf8 = (uchar_t*)alloc((size_t)N_NODES * KVF8LD);      // 23.0 MB
    ushort_t* xb  = (ushort_t*)alloc((size_t)N_NODES * DIM_IN * 2);
    ushort_t* hb0 = (ushort_t*)alloc((size_t)N_NODES * HIDDEN * 2);
    ushort_t* hb1 = (ushort_t*)alloc((size_t)N_NODES * HIDDEN * 2);
    ushort_t* Wb0 = (ushort_t*)alloc((size_t)DIM_IN * NALL * 2);
    ushort_t* Wbr = (ushort_t*)alloc((size_t)4 * HIDDEN * NALL * 2);
    int*   deg     = (int*)alloc(N_NODES * 4);
    int*   row_ptr = (int*)alloc((N_NODES + 1) * 4);
    int*   cursor  = (int*)alloc(N_NODES * 4);
    int*   csrc    = (int*)alloc(N_EDGES * 4);
    int*   gbound  = (int*)alloc((NGRAPH + 1) * 4);
    int*   bsum    = (int*)alloc(SC_BLKS * 4);
    int*   boff    = (int*)alloc(SC_BLKS * 4);

    // prep: x cast | degree | graph boundaries (one launch) + weight cast
    hipMemsetAsync(deg, 0, N_NODES * 4, stream);
    k_prep<<<PREP_CVT_BLOCKS + PREP_DEG_BLOCKS + PREP_GB_BLOCKS, 256, 0, stream>>>(
        x, xb, edst, deg, batch, gbound);
    {
        dim3 gw((DIM_IN * NALL + 255) / 256, 5);
        k_cvt_wT_all<<<gw, 256, 0, stream>>>(Wq1, Wk1, Wv1, Ws1,
                                             Wq_r, Wk_r, Wv_r, Ws_r, Wb0, Wbr);
    }
    k_scan_part<<<SC_BLKS, 256, 0, stream>>>(deg, bsum);
    k_scan_top<<<1, 128, 0, stream>>>(bsum, boff, row_ptr);
    k_scan_down<<<SC_BLKS, 256, 0, stream>>>(deg, boff, row_ptr, cursor);
    k_scatter<<<(N_EDGES + 255) / 256, 256, 0, stream>>>(esrc, edst, cursor, csrc);

    const ushort_t* Ain = xb;
    ushort_t* hbcur = hb0;
    for (int L = 0; L < 5; L++) {
        const ushort_t* Wb = (L == 0) ? Wb0 : (Wbr + (size_t)(L - 1) * HIDDEN * NALL);
        const float *bq, *bk, *bv, *bs;
        if (L == 0) { bq = bq1; bk = bk1; bv = bv1; bs = bs1; }
        else {
            int i = L - 1;
            bq = bq_r + (size_t)i * HD; bk = bk_r + (size_t)i * HD;
            bv = bv_r + (size_t)i * HD; bs = bs_r + (size_t)i * HIDDEN;
        }
        if (L == 0)
            gemm_qkvs_mfma<DIM_IN><<<GEMM_GRID, 256, 0, stream>>>(Ain, N_NODES, Wb,
                                                                  bq, bk, bv, bs, kvqs, kvf8);
        else
            gemm_qkvs_mfma<HIDDEN><<<GEMM_GRID, 256, 0, stream>>>(Ain, N_NODES, Wb,
                                                                  bq, bk, bv, bs, kvqs, kvf8);
        node_attn<<<N_NODES, 64, 0, stream>>>(kvqs, kvf8, row_ptr, csrc, hbcur);
        Ain = hbcur;
        hbcur = (hbcur == hb0) ? hb1 : hb0;
    }

    k_head<<<NGRAPH, 128, 0, stream>>>(hbcur == hb0 ? hb1 : hb0, gbound,
                                       fc1w, fc1b, fc2w, fc2b, arcw, out);
}